// Round 12
// baseline (3042.267 us; speedup 1.0000x reference)
//
#include <hip/hip_runtime.h>
#include <stdint.h>

#define DET_THRESH 0.015f

// Packed fp32 FMA: 2 IEEE fp32 FMAs per VALU slot (v_pk_fma_f32, VOP3P).
// The scalar v_fma path tops out at 78.6 TF; packed reaches the 157.3 TF
// spec ceiling. All operands are VGPR pairs (weights come from LDS via
// wave-uniform ds_read_b64 broadcast, so no SGPR/VGPR ambiguity).
#define PKFMA(A2, W2, AV2) \
  asm("v_pk_fma_f32 %0, %1, %2, %0" : "+v"(A2) : "v"(W2), "v"(AV2))

// =====================================================================
// Weight pre-transpose: w[co][ci][tap] -> wT[ci*9+tap][co]  (per layer)
// =====================================================================
struct TP {
  const float* src[8];
  float* dst[8];
  int cin[8];
  int cout[8];
};

__global__ __launch_bounds__(256) void k_wT(TP tp) {
  int l = blockIdx.y;
  int n = tp.cin[l] * tp.cout[l] * 9;
  int k = blockIdx.x * 256 + threadIdx.x;
  if (k >= n) return;
  int ci9 = tp.cin[l] * 9;
  int co = k / ci9;
  int r = k - co * ci9;             // r = ci*9 + tap
  tp.dst[l][(size_t)r * tp.cout[l] + co] = tp.src[l][k];
}

// =====================================================================
// 2-rows-per-thread 3x3 conv (+bias+relu), optional fused 2x2 maxpool.
// Tile: TW cols x 2*RG rows x 16 co. Thread: rows {2r,2r+1} x 1 col x
// 16 co as 8 float2 pairs, v_pk_fma_f32 inner loop. Weights staged in
// LDS per 4-ci chunk, read as uniform ds_read_b64 broadcasts.
// =====================================================================
template <int TW, bool POOL>
__global__ __launch_bounds__(256) void k_conv2r(
    const float* __restrict__ in, const float* __restrict__ wT, const float* __restrict__ bias,
    float* __restrict__ out, int CIN, int COUT, int H, int W, int tilesX)
{
  constexpr int RG = (TW == 32) ? 8 : 6;
  constexpr int TH = RG * 2;
  constexpr int SR = TH + 2;
  constexpr int SC = TW + 2;
  constexpr int LC = TW + 4;
  constexpr int TOTAL = 4 * SR * SC;
  __shared__ float ain[4][SR][LC];
  __shared__ float2 wl2[288];        // [ci4][tap9][co16] as 8 pairs

  int tile = blockIdx.x;
  int tx = tile % tilesX, ty = tile / tilesX;
  int x0 = tx * TW, y0 = ty * TH;
  int cob = blockIdx.y * 16;
  int n = blockIdx.z;

  int tid = threadIdx.x;
  int r, c;
  if (TW == 32) { r = tid >> 5; c = tid & 31; }
  else          { r = tid / TW; c = tid - r * TW; }
  bool live = (TW * RG >= 256) || (tid < TW * RG);
  int rE = live ? r : 0;

  bool full = (y0 >= 1) && (y0 + TH + 1 <= H) && (x0 >= 1) && (x0 + TW + 1 <= W);
  size_t imgBase = (size_t)n * CIN * H * W;

  float2 accA[8], accB[8];
#pragma unroll
  for (int j = 0; j < 8; j++) {
    accA[j] = make_float2(0.f, 0.f);
    accB[j] = make_float2(0.f, 0.f);
  }

  int nch = CIN >> 2;
  for (int cc = 0; cc < nch; ++cc) {
    __syncthreads();
    // stage activations
    if (full) {
      const float* src = in + imgBase + (size_t)(cc * 4) * H * W + (y0 - 1) * W + (x0 - 1);
      for (int m = tid; m < TOTAL; m += 256) {
        int ci = m / (SR * SC);
        int rem = m - ci * (SR * SC);
        int rr = rem / SC;
        int col = rem - rr * SC;
        ain[ci][rr][col] = src[(size_t)ci * H * W + rr * W + col];
      }
    } else {
      for (int m = tid; m < TOTAL; m += 256) {
        int ci = m / (SR * SC);
        int rem = m - ci * (SR * SC);
        int rr = rem / SC;
        int col = rem - rr * SC;
        int gy = y0 - 1 + rr, gx = x0 - 1 + col;
        float v = 0.f;
        if (gy >= 0 && gy < H && gx >= 0 && gx < W)
          v = in[imgBase + ((size_t)(cc * 4 + ci) * H + gy) * W + gx];
        ain[ci][rr][col] = v;
      }
    }
    // stage weights [ci][tap][co16]
    {
      float* wlf = (float*)wl2;
      for (int m = tid; m < 576; m += 256) {
        int ci = m / 144;
        int rem = m - ci * 144;
        int tap = rem >> 4, co = rem & 15;
        wlf[m] = wT[(size_t)((cc * 4 + ci) * 9 + tap) * COUT + cob + co];
      }
    }
    __syncthreads();
#pragma unroll
    for (int ci = 0; ci < 4; ++ci) {
      float2 win2[4][3];
#pragma unroll
      for (int dy = 0; dy < 4; dy++) {
        float v0 = ain[ci][2 * rE + dy][c];
        float v1 = ain[ci][2 * rE + dy][c + 1];
        float v2 = ain[ci][2 * rE + dy][c + 2];
        win2[dy][0] = make_float2(v0, v0);
        win2[dy][1] = make_float2(v1, v1);
        win2[dy][2] = make_float2(v2, v2);
      }
#pragma unroll
      for (int tap = 0; tap < 9; tap++) {
        const float2* w2 = &wl2[ci * 72 + tap * 8];
        float2 a0d = win2[tap / 3][tap % 3];
        float2 a1d = win2[tap / 3 + 1][tap % 3];
#pragma unroll
        for (int p = 0; p < 8; p++) {
          float2 wv = w2[p];
          PKFMA(accA[p], wv, a0d);
          PKFMA(accB[p], wv, a1d);
        }
      }
    }
  }

  float bvv[16];
  {
    const float4* bp = (const float4*)(bias + cob);
    *(float4*)&bvv[0] = bp[0]; *(float4*)&bvv[4] = bp[1];
    *(float4*)&bvv[8] = bp[2]; *(float4*)&bvv[12] = bp[3];
  }
  const float* accAf = (const float*)accA;
  const float* accBf = (const float*)accB;
  int x = x0 + c;
  if (!POOL) {
    int yA = y0 + 2 * r, yB = yA + 1;
    bool okA = live && (yA < H) && (x < W);
    bool okB = live && (yB < H) && (x < W);
#pragma unroll
    for (int j = 0; j < 16; j++) {
      if (okA) out[(((size_t)n * COUT + cob + j) * H + yA) * W + x] = fmaxf(accAf[j] + bvv[j], 0.f);
      if (okB) out[(((size_t)n * COUT + cob + j) * H + yB) * W + x] = fmaxf(accBf[j] + bvv[j], 0.f);
    }
  } else {
    int Hp = H >> 1, Wp = W >> 1;
    int py = (y0 >> 1) + r, pxp = x >> 1;
    bool ok = live && ((c & 1) == 0) && (py < Hp) && (pxp < Wp);
#pragma unroll
    for (int j = 0; j < 16; j++) {
      float v0 = fmaxf(accAf[j] + bvv[j], 0.f);
      float v1 = fmaxf(accBf[j] + bvv[j], 0.f);
      float h = fmaxf(v0, v1);                      // vertical pair in-thread
      float hv = fmaxf(h, __shfl_xor(h, 1, 64));    // horizontal pair
      if (ok)
        out[(((size_t)n * COUT + cob + j) * Hp + py) * Wp + pxp] = hv;
    }
  }
}

// =====================================================================
// Single-row conv for the 30x40 layers (exact row fit at TH=6), packed.
// =====================================================================
template <int TW, int TH>
__global__ __launch_bounds__(256) void k_conv(
    const float* __restrict__ in, const float* __restrict__ wT, const float* __restrict__ bias,
    float* __restrict__ out, int CIN, int COUT, int H, int W, int tilesX)
{
  constexpr int SR = TH + 2;
  constexpr int SC = TW + 2;
  constexpr int LC = TW + 4;
  constexpr int TOTAL = 4 * SR * SC;
  __shared__ float ain[4][SR][LC];
  __shared__ float2 wl2[288];

  int tile = blockIdx.x;
  int tx = tile % tilesX, ty = tile / tilesX;
  int x0 = tx * TW, y0 = ty * TH;
  int cob = blockIdx.y * 16;
  int n = blockIdx.z;

  int tid = threadIdx.x;
  int r, c;
  if (TW == 32) { r = tid >> 5; c = tid & 31; }
  else          { r = tid / TW; c = tid - r * TW; }
  bool live = (TW * TH >= 256) || (tid < TW * TH);
  int rE = live ? r : 0;

  bool full = (y0 >= 1) && (y0 + TH + 1 <= H) && (x0 >= 1) && (x0 + TW + 1 <= W);
  size_t imgBase = (size_t)n * CIN * H * W;

  float2 acc[8];
#pragma unroll
  for (int j = 0; j < 8; j++) acc[j] = make_float2(0.f, 0.f);

  int nch = CIN >> 2;
  for (int cc = 0; cc < nch; ++cc) {
    __syncthreads();
    if (full) {
      const float* src = in + imgBase + (size_t)(cc * 4) * H * W + (y0 - 1) * W + (x0 - 1);
      for (int m = tid; m < TOTAL; m += 256) {
        int ci = m / (SR * SC);
        int rem = m - ci * (SR * SC);
        int rr = rem / SC;
        int col = rem - rr * SC;
        ain[ci][rr][col] = src[(size_t)ci * H * W + rr * W + col];
      }
    } else {
      for (int m = tid; m < TOTAL; m += 256) {
        int ci = m / (SR * SC);
        int rem = m - ci * (SR * SC);
        int rr = rem / SC;
        int col = rem - rr * SC;
        int gy = y0 - 1 + rr, gx = x0 - 1 + col;
        float v = 0.f;
        if (gy >= 0 && gy < H && gx >= 0 && gx < W)
          v = in[imgBase + ((size_t)(cc * 4 + ci) * H + gy) * W + gx];
        ain[ci][rr][col] = v;
      }
    }
    {
      float* wlf = (float*)wl2;
      for (int m = tid; m < 576; m += 256) {
        int ci = m / 144;
        int rem = m - ci * 144;
        int tap = rem >> 4, co = rem & 15;
        wlf[m] = wT[(size_t)((cc * 4 + ci) * 9 + tap) * COUT + cob + co];
      }
    }
    __syncthreads();
#pragma unroll
    for (int ci = 0; ci < 4; ++ci) {
      float2 win2[3][3];
#pragma unroll
      for (int dy = 0; dy < 3; dy++) {
        float v0 = ain[ci][rE + dy][c];
        float v1 = ain[ci][rE + dy][c + 1];
        float v2 = ain[ci][rE + dy][c + 2];
        win2[dy][0] = make_float2(v0, v0);
        win2[dy][1] = make_float2(v1, v1);
        win2[dy][2] = make_float2(v2, v2);
      }
#pragma unroll
      for (int tap = 0; tap < 9; tap++) {
        const float2* w2 = &wl2[ci * 72 + tap * 8];
        float2 ad = win2[tap / 3][tap % 3];
#pragma unroll
        for (int p = 0; p < 8; p++) {
          float2 wv = w2[p];
          PKFMA(acc[p], wv, ad);
        }
      }
    }
  }

  float bvv[16];
  {
    const float4* bp = (const float4*)(bias + cob);
    *(float4*)&bvv[0] = bp[0]; *(float4*)&bvv[4] = bp[1];
    *(float4*)&bvv[8] = bp[2]; *(float4*)&bvv[12] = bp[3];
  }
  const float* accf = (const float*)acc;
  int x = x0 + c;
  int y = y0 + r;
  if (live && y < H && x < W) {
#pragma unroll
    for (int j = 0; j < 16; j++)
      out[(((size_t)n * COUT + cob + j) * H + y) * W + x] = fmaxf(accf[j] + bvv[j], 0.f);
  }
}

// =====================================================================
// Fused conv0(1->64)+relu -> conv1(64->64)+relu -> 2x2 maxpool.
// 32x16 tile, 2 rows/thread, packed conv1; conv0 recompute stays scalar.
// =====================================================================
__global__ __launch_bounds__(256) void k_f01(
    const float* __restrict__ x, const float* __restrict__ w0g, const float* __restrict__ b0g,
    const float* __restrict__ wT1, const float* __restrict__ b1g, float* __restrict__ out)
{
  const int H = 240, W = 320;
  __shared__ float in_raw[20][36];
  __shared__ float a0[4][18][36];
  __shared__ float w0l[576];
  __shared__ float b0l[64];
  __shared__ float2 wl2[288];

  int tile = blockIdx.x;              // tilesX=10, tilesY=15
  int tx = tile % 10, ty = tile / 10;
  int x0 = tx * 32, y0 = ty * 16;
  int cob = blockIdx.y * 16;          // 0..3
  int n = blockIdx.z;

  int tid = threadIdx.x;
  int r = tid >> 5;                   // rows 2r, 2r+1
  int c = tid & 31;

  bool fullT = (y0 >= 1) && (y0 + 17 <= H) && (x0 >= 1) && (x0 + 33 <= W);

  for (int k = tid; k < 576; k += 256) w0l[k] = w0g[k];
  if (tid < 64) b0l[tid] = b0g[tid];
  for (int m = tid; m < 720; m += 256) {
    int rr = m / 36, col = m - rr * 36;
    int gy = y0 - 2 + rr, gx = x0 - 2 + col;
    in_raw[rr][col] = (gy >= 0 && gy < H && gx >= 0 && gx < W)
                          ? x[(size_t)n * (H * W) + gy * W + gx] : 0.f;
  }

  float2 accA[8], accB[8];
#pragma unroll
  for (int j = 0; j < 8; j++) {
    accA[j] = make_float2(0.f, 0.f);
    accB[j] = make_float2(0.f, 0.f);
  }

  for (int cc = 0; cc < 16; ++cc) {
    __syncthreads();                  // in_raw/w0l ready; a0/wl2 free
    // conv0 chunk -> a0 (zero OUTSIDE image: conv1 'SAME' zero-padding)
    if (fullT) {
      for (int m = tid; m < 2448; m += 256) {
        int ch = m / 612;
        int rem = m - ch * 612;
        int rr = rem / 34;
        int col = rem - rr * 34;
        const float* wp = &w0l[(cc * 4 + ch) * 9];
        float s = b0l[cc * 4 + ch];
#pragma unroll
        for (int dy = 0; dy < 3; dy++)
#pragma unroll
          for (int dx = 0; dx < 3; dx++)
            s = fmaf(in_raw[rr + dy][col + dx], wp[dy * 3 + dx], s);
        a0[ch][rr][col] = fmaxf(s, 0.f);
      }
    } else {
      for (int m = tid; m < 2448; m += 256) {
        int ch = m / 612;
        int rem = m - ch * 612;
        int rr = rem / 34;
        int col = rem - rr * 34;
        int gy = y0 - 1 + rr, gx = x0 - 1 + col;
        float v = 0.f;
        if (gy >= 0 && gy < H && gx >= 0 && gx < W) {
          const float* wp = &w0l[(cc * 4 + ch) * 9];
          float s = b0l[cc * 4 + ch];
#pragma unroll
          for (int dy = 0; dy < 3; dy++)
#pragma unroll
            for (int dx = 0; dx < 3; dx++)
              s = fmaf(in_raw[rr + dy][col + dx], wp[dy * 3 + dx], s);
          v = fmaxf(s, 0.f);
        }
        a0[ch][rr][col] = v;
      }
    }
    // stage conv1 weights
    {
      float* wlf = (float*)wl2;
      for (int m = tid; m < 576; m += 256) {
        int ci = m / 144;
        int rem = m - ci * 144;
        int tap = rem >> 4, co = rem & 15;
        wlf[m] = wT1[(size_t)((cc * 4 + ci) * 9 + tap) * 64 + cob + co];
      }
    }
    __syncthreads();
#pragma unroll
    for (int ci = 0; ci < 4; ++ci) {
      float2 win2[4][3];
#pragma unroll
      for (int dy = 0; dy < 4; dy++) {
        float v0 = a0[ci][2 * r + dy][c];
        float v1 = a0[ci][2 * r + dy][c + 1];
        float v2 = a0[ci][2 * r + dy][c + 2];
        win2[dy][0] = make_float2(v0, v0);
        win2[dy][1] = make_float2(v1, v1);
        win2[dy][2] = make_float2(v2, v2);
      }
#pragma unroll
      for (int tap = 0; tap < 9; tap++) {
        const float2* w2 = &wl2[ci * 72 + tap * 8];
        float2 a0d = win2[tap / 3][tap % 3];
        float2 a1d = win2[tap / 3 + 1][tap % 3];
#pragma unroll
        for (int p = 0; p < 8; p++) {
          float2 wv = w2[p];
          PKFMA(accA[p], wv, a0d);
          PKFMA(accB[p], wv, a1d);
        }
      }
    }
  }

  // bias + relu + 2x2 maxpool (vertical in-thread, horizontal shfl) + store
  float bvv[16];
  {
    const float4* bp = (const float4*)(b1g + cob);
    *(float4*)&bvv[0] = bp[0]; *(float4*)&bvv[4] = bp[1];
    *(float4*)&bvv[8] = bp[2]; *(float4*)&bvv[12] = bp[3];
  }
  const float* accAf = (const float*)accA;
  const float* accBf = (const float*)accB;
  int Hp = 120, Wp = 160;
  int py = ty * 8 + r, pxp = (x0 + c) >> 1;
  bool ok = ((c & 1) == 0);
#pragma unroll
  for (int j = 0; j < 16; j++) {
    float v0 = fmaxf(accAf[j] + bvv[j], 0.f);
    float v1 = fmaxf(accBf[j] + bvv[j], 0.f);
    float h = fmaxf(v0, v1);
    float hv = fmaxf(h, __shfl_xor(h, 1, 64));
    if (ok)
      out[(((size_t)n * 64 + cob + j) * Hp + py) * Wp + pxp] = hv;
  }
}

// =====================================================================
// Head: conv9 (1x1, 256->65) + bias + softmax(65) + dustbin drop + shuffle.
// Packed inner loop. Also zeroes the prob_nms/pred output region.
// =====================================================================
__global__ __launch_bounds__(256) void k_head(
    const float* __restrict__ act, const float* __restrict__ w9, const float* __restrict__ b9,
    float* __restrict__ prob, float* __restrict__ zbase)
{
  __shared__ float wl[256 * 68];
  int n = blockIdx.y;
  int tid = threadIdx.x;

  // zero onms+opred (2*614400 floats) across all 80 blocks
  {
    float4* z = (float4*)zbase;
    int gid = (blockIdx.y * gridDim.x + blockIdx.x) * 256 + tid;
    for (int k = gid; k < 307200; k += 20480)
      z[k] = make_float4(0.f, 0.f, 0.f, 0.f);
  }

  for (int k = tid; k < 65 * 256; k += 256) {
    int co = k / 256, ci = k % 256;
    wl[ci * 68 + co] = w9[k];
  }
  for (int ci = tid; ci < 256; ci += 256) {
    wl[ci * 68 + 65] = 0.f; wl[ci * 68 + 66] = 0.f; wl[ci * 68 + 67] = 0.f;
  }
  __syncthreads();
  int px = blockIdx.x * 128 + (tid >> 1);
  int half = tid & 1;
  bool live = (px < 1200);
  int cbase = half * 34;
  int nreal = half ? 31 : 34;    // real co count (incl. dustbin 64 on odd)

  float2 acc2[17];
#pragma unroll
  for (int i = 0; i < 17; i++) acc2[i] = make_float2(0.f, 0.f);

  if (live) {
    for (int ci = 0; ci < 256; ++ci) {
      float a = act[((size_t)n * 256 + ci) * 1200 + px];
      float2 ad = make_float2(a, a);
      const float2* wp = (const float2*)&wl[ci * 68 + cbase];
#pragma unroll
      for (int g = 0; g < 17; g++) {
        float2 wv = wp[g];
        PKFMA(acc2[g], wv, ad);
      }
    }
  }
  float* accv = (float*)acc2;
  for (int i = 0; i < 34; i++)
    if (i < nreal) accv[i] += b9[cbase + i];
  float m = -1e30f;
  for (int i = 0; i < 34; i++)
    if (i < nreal) m = fmaxf(m, accv[i]);
  m = fmaxf(m, __shfl_xor(m, 1, 64));
  float s = 0.f;
  for (int i = 0; i < 34; i++)
    if (i < nreal) { accv[i] = __expf(accv[i] - m); s += accv[i]; }
  s += __shfl_xor(s, 1, 64);
  float inv = 1.f / s;

  if (live) {
    int hc = px / 40, wc = px % 40;
    float* pb = prob + (size_t)n * 76800;
    int nw = half ? 30 : 34;     // write only co < 64
    for (int i = 0; i < nw; i++) {
      int co = cbase + i;
      pb[(hc * 8 + (co >> 3)) * 320 + wc * 8 + (co & 7)] = accv[i] * inv;
    }
  }
}

// =====================================================================
// Exact reference NMS per image (16 per-wave radix histograms).
// =====================================================================
#define MAXC 1024
__global__ __launch_bounds__(1024) void k_nms(
    const float* __restrict__ prob, float* __restrict__ onms, float* __restrict__ opred)
{
  __shared__ unsigned sup[MAXC * 32];
  __shared__ unsigned long long skey[MAXC];
  __shared__ unsigned syx[MAXC];
  __shared__ unsigned hist[256];
  __shared__ unsigned vword[32];
  __shared__ unsigned sh_prefix, sh_K, sh_cG, sh_pG, sh_pE;

  int n = blockIdx.x;
  int tid = threadIdx.x;
  const float* p = prob + (size_t)n * 76800;
  float* on = onms + (size_t)n * 76800;
  float* op = opred + (size_t)n * 76800;

  if (tid == 0) { sh_prefix = 0u; sh_K = MAXC; sh_cG = 0u; sh_pG = 0u; sh_pE = 0u; }

  unsigned* h16 = sup;   // 16 waves x 256 bins (sup unused until later)
  int wv = tid >> 6;
  for (int round = 0; round < 4; ++round) {
    for (int k = tid; k < 4096; k += 1024) h16[k] = 0u;
    __syncthreads();
    unsigned prefix = sh_prefix;
    int shift = 24 - 8 * round;
    unsigned maskHi = (round == 0) ? 0u : (0xFFFFFFFFu << (shift + 8));
    for (int k = tid; k < 76800; k += 1024) {
      unsigned b = __float_as_uint(p[k]);
      if ((b & maskHi) == prefix) atomicAdd(&h16[wv * 256 + ((b >> shift) & 255)], 1u);
    }
    __syncthreads();
    if (tid < 256) {
      unsigned s = 0u;
#pragma unroll
      for (int w = 0; w < 16; w++) s += h16[w * 256 + tid];
      hist[tid] = s;
    }
    __syncthreads();
    if (tid == 0) {
      unsigned K = sh_K, cum = 0u;
      int bin = 255;
      for (; bin >= 0; --bin) {
        unsigned cgt = hist[bin];
        if (cum + cgt >= K) break;
        cum += cgt;
      }
      sh_prefix = prefix | ((unsigned)bin << shift);
      sh_K = K - cum;
      sh_cG += cum;
    }
    __syncthreads();
  }
  unsigned T = sh_prefix;
  unsigned Kfill = sh_K;
  unsigned Cgt = sh_cG;

  unsigned* eq = sup;
  __syncthreads();
  for (int k = tid; k < 76800; k += 1024) {
    unsigned b = __float_as_uint(p[k]);
    if (b > T) {
      unsigned pos = atomicAdd(&sh_pG, 1u);
      skey[pos] = ((unsigned long long)b << 32) | (unsigned)(~(unsigned)k);
    } else if (b == T) {
      unsigned pos = atomicAdd(&sh_pE, 1u);
      if (pos < 2048u) eq[pos] = (unsigned)k;
    }
  }
  __syncthreads();
  unsigned cE = sh_pE;
  for (int k = tid; k < 2048; k += 1024)
    if ((unsigned)k >= cE) eq[k] = 0xFFFFFFFFu;
  __syncthreads();
  for (int k = 2; k <= 2048; k <<= 1) {
    for (int j = k >> 1; j > 0; j >>= 1) {
      int t = tid;
      int i = ((t & ~(j - 1)) << 1) | (t & (j - 1));
      int l = i | j;
      bool up = ((i & k) == 0);
      unsigned a = eq[i], b2 = eq[l];
      if (up ? (a > b2) : (a < b2)) { eq[i] = b2; eq[l] = a; }
      __syncthreads();
    }
  }
  for (int m2 = tid; m2 < (int)Kfill; m2 += 1024)
    skey[Cgt + m2] = ((unsigned long long)T << 32) | (unsigned)(~eq[m2]);
  __syncthreads();

  for (int k = 2; k <= MAXC; k <<= 1) {
    for (int j = k >> 1; j > 0; j >>= 1) {
      int i = tid;
      int l = i ^ j;
      if (l > i) {
        unsigned long long a = skey[i], b2 = skey[l];
        bool up = ((i & k) == 0);
        if (up ? (a < b2) : (a > b2)) { skey[i] = b2; skey[l] = a; }
      }
      __syncthreads();
    }
  }

  if (tid < 32) vword[tid] = 0u;
  __syncthreads();
  {
    unsigned long long key = skey[tid];
    unsigned vb = (unsigned)(key >> 32);
    float val = __uint_as_float(vb);
    unsigned id = ~(unsigned)key;
    unsigned y = id / 320u, xx = id - 320u * y;
    syx[tid] = (y << 16) | xx;
    if (val > DET_THRESH) atomicOr(&vword[tid >> 5], 1u << (tid & 31));
  }
  __syncthreads();

  {
    unsigned myyx = syx[tid];
    int ty = (int)(myyx >> 16), tx = (int)(myyx & 0xFFFFu);
    for (int w = 0; w < 32; ++w) {
      unsigned bits = 0u;
#pragma unroll 8
      for (int b2 = 0; b2 < 32; ++b2) {
        int j = w * 32 + b2;
        if (j > tid) {
          unsigned o = syx[j];
          int dy = ty - (int)(o >> 16); dy = dy < 0 ? -dy : dy;
          int dx = tx - (int)(o & 0xFFFFu); dx = dx < 0 ? -dx : dx;
          if (((dy | dx) < 4) && (dy + dx) <= 4) bits |= 1u << b2;
        }
      }
      sup[tid * 32 + w] = bits;
    }
  }
  __syncthreads();

  if (tid < 64) {
    int lw = tid;
    unsigned keepw = (lw < 32) ? vword[lw] : 0u;
    for (int i = 0; i < MAXC; ++i) {
      unsigned kword = __shfl(keepw, i >> 5, 64);
      if ((kword >> (i & 31)) & 1u) {
        if (lw < 32) keepw &= ~sup[i * 32 + lw];
      }
    }
    unsigned pc = (lw < 32) ? (unsigned)__builtin_popcount(keepw) : 0u;
    unsigned incl = pc;
    for (int d = 1; d < 32; d <<= 1) {
      unsigned t2 = __shfl_up(incl, d, 64);
      if (lw >= d) incl += t2;
    }
    unsigned excl = incl - pc;
    if (lw < 32) {
      int quota = 300 - (int)excl;
      if (quota <= 0) keepw = 0u;
      else if ((int)pc > quota) {
        while (__builtin_popcount(keepw) > quota)
          keepw &= ~(1u << (31 - __builtin_clz(keepw)));
      }
      unsigned kw = keepw;
      while (kw) {
        int b2 = __builtin_ffs((int)kw) - 1;
        kw &= kw - 1u;
        int i = lw * 32 + b2;
        unsigned long long key = skey[i];
        float v = __uint_as_float((unsigned)(key >> 32));
        unsigned id = ~(unsigned)key;
        on[id] = v;
        op[id] = v;
      }
    }
  }
}

// =====================================================================
extern "C" void kernel_launch(void* const* d_in, const int* in_sizes, int n_in,
                              void* d_out, int out_size, void* d_ws, size_t ws_size,
                              hipStream_t stream) {
  const float* x = (const float*)d_in[0];
  const float* w[10];
  const float* b[10];
  for (int i = 0; i < 10; ++i) {
    w[i] = (const float*)d_in[1 + 2 * i];
    b[i] = (const float*)d_in[2 + 2 * i];
  }
  float* A = (float*)d_ws;
  float* B = A + 9830400;        // 64*120*160*8
  float* prob  = (float*)d_out;
  float* onms  = prob + 614400;  // 8*240*320
  float* opred = onms + 614400;

  // Transposed weights live in the onms/opred region (dead until k_head
  // zeroes it; k_nms then scatters). Total 921600 floats <= 1228800.
  float* wT1 = onms;
  float* wT2 = wT1 + 36864;
  float* wT3 = wT2 + 36864;
  float* wT4 = wT3 + 36864;
  float* wT5 = wT4 + 73728;
  float* wT6 = wT5 + 147456;
  float* wT7 = wT6 + 147456;
  float* wT8 = wT7 + 147456;

  TP tp;
  tp.src[0] = w[1]; tp.dst[0] = wT1; tp.cin[0] = 64;  tp.cout[0] = 64;
  tp.src[1] = w[2]; tp.dst[1] = wT2; tp.cin[1] = 64;  tp.cout[1] = 64;
  tp.src[2] = w[3]; tp.dst[2] = wT3; tp.cin[2] = 64;  tp.cout[2] = 64;
  tp.src[3] = w[4]; tp.dst[3] = wT4; tp.cin[3] = 64;  tp.cout[3] = 128;
  tp.src[4] = w[5]; tp.dst[4] = wT5; tp.cin[4] = 128; tp.cout[4] = 128;
  tp.src[5] = w[6]; tp.dst[5] = wT6; tp.cin[5] = 128; tp.cout[5] = 128;
  tp.src[6] = w[7]; tp.dst[6] = wT7; tp.cin[6] = 128; tp.cout[6] = 128;
  tp.src[7] = w[8]; tp.dst[7] = wT8; tp.cin[7] = 128; tp.cout[7] = 256;
  k_wT<<<dim3(1152, 8), 256, 0, stream>>>(tp);

  // conv0+conv1+pool -> A (8,64,120,160). 32x16 tiles, 10x15.
  k_f01<<<dim3(150, 4, 8), 256, 0, stream>>>(x, w[0], b[0], wT1, b[1], A);
  // conv2 -> B (8,64,120,160). 32x16 tiles, 5x8.
  k_conv2r<32, false><<<dim3(40, 4, 8), 256, 0, stream>>>(A, wT2, b[2], B, 64, 64, 120, 160, 5);
  // conv3+pool -> A (8,64,60,80)
  k_conv2r<32, true ><<<dim3(40, 4, 8), 256, 0, stream>>>(B, wT3, b[3], A, 64, 64, 120, 160, 5);
  // conv4 -> B (8,128,60,80). 40x12 tiles, 2x5 (exact).
  k_conv2r<40, false><<<dim3(10, 8, 8), 256, 0, stream>>>(A, wT4, b[4], B, 64, 128, 60, 80, 2);
  // conv5+pool -> A (8,128,30,40)
  k_conv2r<40, true ><<<dim3(10, 8, 8), 256, 0, stream>>>(B, wT5, b[5], A, 128, 128, 60, 80, 2);
  // conv6 -> B (8,128,30,40). 40x6 tiles, 1x5 (exact).
  k_conv<40, 6><<<dim3(5, 8, 8), 256, 0, stream>>>(A, wT6, b[6], B, 128, 128, 30, 40, 1);
  // conv7 -> A
  k_conv<40, 6><<<dim3(5, 8, 8), 256, 0, stream>>>(B, wT7, b[7], A, 128, 128, 30, 40, 1);
  // conv8 -> B (8,256,30,40)
  k_conv<40, 6><<<dim3(5, 16, 8), 256, 0, stream>>>(A, wT8, b[8], B, 128, 256, 30, 40, 1);
  // convPb + softmax + shuffle -> prob; also zeroes onms/opred.
  k_head<<<dim3(10, 8), 256, 0, stream>>>(B, w[9], b[9], prob, onms);
  // NMS + top-300 -> prob_nms, pred
  k_nms<<<dim3(8), 1024, 0, stream>>>(prob, onms, opred);
}

// Round 13
// 2835.650 us; speedup vs baseline: 1.0729x; 1.0729x over previous
//
#include <hip/hip_runtime.h>
#include <stdint.h>

#define DET_THRESH 0.015f

// 32 FMAs of weight quads q0..q7 against activation AV (scalar v_fma --
// the fp32 pipe is 128 FMA-lanes/CU/cyc; v_pk_fma_f32 takes 2 slots for
// 2 FMAs, so packed math gains nothing (r12: 700->1126us regression)).
#define FMA32(ACC, AV) do { \
  ACC[0]  = fmaf(AV, q0.x, ACC[0]);  ACC[1]  = fmaf(AV, q0.y, ACC[1]);  \
  ACC[2]  = fmaf(AV, q0.z, ACC[2]);  ACC[3]  = fmaf(AV, q0.w, ACC[3]);  \
  ACC[4]  = fmaf(AV, q1.x, ACC[4]);  ACC[5]  = fmaf(AV, q1.y, ACC[5]);  \
  ACC[6]  = fmaf(AV, q1.z, ACC[6]);  ACC[7]  = fmaf(AV, q1.w, ACC[7]);  \
  ACC[8]  = fmaf(AV, q2.x, ACC[8]);  ACC[9]  = fmaf(AV, q2.y, ACC[9]);  \
  ACC[10] = fmaf(AV, q2.z, ACC[10]); ACC[11] = fmaf(AV, q2.w, ACC[11]); \
  ACC[12] = fmaf(AV, q3.x, ACC[12]); ACC[13] = fmaf(AV, q3.y, ACC[13]); \
  ACC[14] = fmaf(AV, q3.z, ACC[14]); ACC[15] = fmaf(AV, q3.w, ACC[15]); \
  ACC[16] = fmaf(AV, q4.x, ACC[16]); ACC[17] = fmaf(AV, q4.y, ACC[17]); \
  ACC[18] = fmaf(AV, q4.z, ACC[18]); ACC[19] = fmaf(AV, q4.w, ACC[19]); \
  ACC[20] = fmaf(AV, q5.x, ACC[20]); ACC[21] = fmaf(AV, q5.y, ACC[21]); \
  ACC[22] = fmaf(AV, q5.z, ACC[22]); ACC[23] = fmaf(AV, q5.w, ACC[23]); \
  ACC[24] = fmaf(AV, q6.x, ACC[24]); ACC[25] = fmaf(AV, q6.y, ACC[25]); \
  ACC[26] = fmaf(AV, q6.z, ACC[26]); ACC[27] = fmaf(AV, q6.w, ACC[27]); \
  ACC[28] = fmaf(AV, q7.x, ACC[28]); ACC[29] = fmaf(AV, q7.y, ACC[29]); \
  ACC[30] = fmaf(AV, q7.z, ACC[30]); ACC[31] = fmaf(AV, q7.w, ACC[31]); } while (0)

// =====================================================================
// Weight pre-transpose: w[co][ci][tap] -> wT[ci*9+tap][co]  (per layer)
// =====================================================================
struct TP {
  const float* src[8];
  float* dst[8];
  int cin[8];
  int cout[8];
};

__global__ __launch_bounds__(256) void k_wT(TP tp) {
  int l = blockIdx.y;
  int n = tp.cin[l] * tp.cout[l] * 9;
  int k = blockIdx.x * 256 + threadIdx.x;
  if (k >= n) return;
  int ci9 = tp.cin[l] * 9;
  int co = k / ci9;
  int r = k - co * ci9;             // r = ci*9 + tap
  tp.dst[l][(size_t)r * tp.cout[l] + co] = tp.src[l][k];
}

// =====================================================================
// 3x3 conv (+bias+relu), optional fused 2x2 maxpool.
// Tile: TW cols x TH rows x 32 co. Thread: 1 row x 1 col x 32 co.
// acc32+win9+addr ~ 55 VGPR: fits the 64-reg 8-wave budget, so no AGPR
// parking (r7 evidence). 32 co/thread halves LDS window reads, staging,
// and s_load cadence PER FMA vs the 16-co version -- the LDS pipe (one
// unit per CU, 4 SIMDs) was ~70% loaded by scalar b32 window reads.
// POOL only valid for TW=32 (row pair = lane^32, col pair = lane^1).
// =====================================================================
template <int TW, int TH, bool POOL>
__global__ __launch_bounds__(256) void k_conv32(
    const float* __restrict__ in, const float* __restrict__ wT, const float* __restrict__ bias,
    float* __restrict__ out, int CIN, int COUT, int H, int W, int tilesX)
{
  constexpr int SR = TH + 2;
  constexpr int SC = TW + 2;
  constexpr int LC = TW + 4;
  constexpr int TOTAL = 4 * SR * SC;
  __shared__ float ain[4][SR][LC];

  int tile = blockIdx.x;
  int tx = tile % tilesX, ty = tile / tilesX;
  int x0 = tx * TW, y0 = ty * TH;
  int cob = blockIdx.y * 32;
  int n = blockIdx.z;

  int tid = threadIdx.x;
  int r, c;
  if (TW == 32) { r = tid >> 5; c = tid & 31; }
  else          { r = tid / TW; c = tid - r * TW; }
  bool live = (TW * TH >= 256) || (tid < TW * TH);
  int rE = live ? r : 0;

  bool full = (y0 >= 1) && (y0 + TH + 1 <= H) && (x0 >= 1) && (x0 + TW + 1 <= W);
  size_t imgBase = (size_t)n * CIN * H * W;

  float acc[32];
#pragma unroll
  for (int j = 0; j < 32; j++) acc[j] = 0.f;

  int nch = CIN >> 2;
  for (int cc = 0; cc < nch; ++cc) {
    __syncthreads();
    if (full) {
      const float* src = in + imgBase + (size_t)(cc * 4) * H * W + (y0 - 1) * W + (x0 - 1);
      for (int m = tid; m < TOTAL; m += 256) {
        int ci = m / (SR * SC);
        int rem = m - ci * (SR * SC);
        int rr = rem / SC;
        int col = rem - rr * SC;
        ain[ci][rr][col] = src[(size_t)ci * H * W + rr * W + col];
      }
    } else {
      for (int m = tid; m < TOTAL; m += 256) {
        int ci = m / (SR * SC);
        int rem = m - ci * (SR * SC);
        int rr = rem / SC;
        int col = rem - rr * SC;
        int gy = y0 - 1 + rr, gx = x0 - 1 + col;
        float v = 0.f;
        if (gy >= 0 && gy < H && gx >= 0 && gx < W)
          v = in[imgBase + ((size_t)(cc * 4 + ci) * H + gy) * W + gx];
        ain[ci][rr][col] = v;
      }
    }
    __syncthreads();
#pragma unroll
    for (int ci = 0; ci < 4; ++ci) {
      float win[3][3];
#pragma unroll
      for (int dy = 0; dy < 3; dy++) {
        win[dy][0] = ain[ci][rE + dy][c];
        win[dy][1] = ain[ci][rE + dy][c + 1];
        win[dy][2] = ain[ci][rE + dy][c + 2];
      }
      const float* wp = wT + (size_t)((cc * 4 + ci) * 9) * COUT + cob;
#pragma unroll
      for (int tap = 0; tap < 9; tap++) {
        float4 q0 = *(const float4*)(wp + tap * COUT);
        float4 q1 = *(const float4*)(wp + tap * COUT + 4);
        float4 q2 = *(const float4*)(wp + tap * COUT + 8);
        float4 q3 = *(const float4*)(wp + tap * COUT + 12);
        float4 q4 = *(const float4*)(wp + tap * COUT + 16);
        float4 q5 = *(const float4*)(wp + tap * COUT + 20);
        float4 q6 = *(const float4*)(wp + tap * COUT + 24);
        float4 q7 = *(const float4*)(wp + tap * COUT + 28);
        float av = win[tap / 3][tap % 3];
        FMA32(acc, av);
      }
    }
  }

  float bvv[32];
  {
    const float4* bp = (const float4*)(bias + cob);
#pragma unroll
    for (int g = 0; g < 8; g++) *(float4*)&bvv[4 * g] = bp[g];
  }
  int x = x0 + c;
  int y = y0 + r;
  if (!POOL) {
    if (live && y < H && x < W) {
#pragma unroll
      for (int j = 0; j < 32; j++)
        out[(((size_t)n * COUT + cob + j) * H + y) * W + x] = fmaxf(acc[j] + bvv[j], 0.f);
    }
  } else {
    // TW==32 only: vertical pair lane^32, horizontal pair lane^1
    int Hp = H >> 1, Wp = W >> 1;
    int py = y >> 1, pxp = x >> 1;
    bool ok = ((r & 1) == 0) && ((c & 1) == 0) && (py < Hp) && (pxp < Wp);
#pragma unroll
    for (int j = 0; j < 32; j++) {
      float h = fmaxf(acc[j] + bvv[j], 0.f);
      float hv = fmaxf(h, __shfl_xor(h, 32, 64));   // row pair
      float hh = fmaxf(hv, __shfl_xor(hv, 1, 64));  // col pair
      if (ok)
        out[(((size_t)n * COUT + cob + j) * Hp + py) * Wp + pxp] = hh;
    }
  }
}

// =====================================================================
// Fused conv0(1->64)+relu -> conv1(64->64)+relu -> 2x2 maxpool.
// 32x8 tile, 1 row x 32 co; conv0 recomputed per 4-ch chunk into LDS
// (redundancy now 2x: two co-blocks instead of four).
// =====================================================================
__global__ __launch_bounds__(256) void k_f01(
    const float* __restrict__ x, const float* __restrict__ w0g, const float* __restrict__ b0g,
    const float* __restrict__ wT1, const float* __restrict__ b1g, float* __restrict__ out)
{
  const int H = 240, W = 320;
  __shared__ float in_raw[12][36];
  __shared__ float a0[4][10][36];
  __shared__ float w0l[576];
  __shared__ float b0l[64];

  int tile = blockIdx.x;              // tilesX=10, tilesY=30
  int tx = tile % 10, ty = tile / 10;
  int x0 = tx * 32, y0 = ty * 8;
  int cob = blockIdx.y * 32;          // 0..1
  int n = blockIdx.z;

  int tid = threadIdx.x;
  int r = tid >> 5;
  int c = tid & 31;

  bool fullT = (y0 >= 1) && (y0 + 9 <= H) && (x0 >= 1) && (x0 + 33 <= W);

  for (int k = tid; k < 576; k += 256) w0l[k] = w0g[k];
  if (tid < 64) b0l[tid] = b0g[tid];
  for (int m = tid; m < 432; m += 256) {
    int rr = m / 36, col = m - rr * 36;
    int gy = y0 - 2 + rr, gx = x0 - 2 + col;
    in_raw[rr][col] = (gy >= 0 && gy < H && gx >= 0 && gx < W)
                          ? x[(size_t)n * (H * W) + gy * W + gx] : 0.f;
  }

  float acc[32];
#pragma unroll
  for (int j = 0; j < 32; j++) acc[j] = 0.f;

  for (int cc = 0; cc < 16; ++cc) {
    __syncthreads();                  // in_raw/w0l ready; a0 free
    // conv0 chunk -> a0 (zero OUTSIDE image: conv1 'SAME' zero-padding)
    if (fullT) {
      for (int m = tid; m < 1360; m += 256) {
        int ch = m / 340;
        int rem = m - ch * 340;
        int rr = rem / 34;
        int col = rem - rr * 34;
        const float* wp = &w0l[(cc * 4 + ch) * 9];
        float s = b0l[cc * 4 + ch];
#pragma unroll
        for (int dy = 0; dy < 3; dy++)
#pragma unroll
          for (int dx = 0; dx < 3; dx++)
            s = fmaf(in_raw[rr + dy][col + dx], wp[dy * 3 + dx], s);
        a0[ch][rr][col] = fmaxf(s, 0.f);
      }
    } else {
      for (int m = tid; m < 1360; m += 256) {
        int ch = m / 340;
        int rem = m - ch * 340;
        int rr = rem / 34;
        int col = rem - rr * 34;
        int gy = y0 - 1 + rr, gx = x0 - 1 + col;
        float v = 0.f;
        if (gy >= 0 && gy < H && gx >= 0 && gx < W) {
          const float* wp = &w0l[(cc * 4 + ch) * 9];
          float s = b0l[cc * 4 + ch];
#pragma unroll
          for (int dy = 0; dy < 3; dy++)
#pragma unroll
            for (int dx = 0; dx < 3; dx++)
              s = fmaf(in_raw[rr + dy][col + dx], wp[dy * 3 + dx], s);
          v = fmaxf(s, 0.f);
        }
        a0[ch][rr][col] = v;
      }
    }
    __syncthreads();
#pragma unroll
    for (int ci = 0; ci < 4; ++ci) {
      float win[3][3];
#pragma unroll
      for (int dy = 0; dy < 3; dy++) {
        win[dy][0] = a0[ci][r + dy][c];
        win[dy][1] = a0[ci][r + dy][c + 1];
        win[dy][2] = a0[ci][r + dy][c + 2];
      }
      const float* wp = wT1 + (size_t)((cc * 4 + ci) * 9) * 64 + cob;
#pragma unroll
      for (int tap = 0; tap < 9; tap++) {
        float4 q0 = *(const float4*)(wp + tap * 64);
        float4 q1 = *(const float4*)(wp + tap * 64 + 4);
        float4 q2 = *(const float4*)(wp + tap * 64 + 8);
        float4 q3 = *(const float4*)(wp + tap * 64 + 12);
        float4 q4 = *(const float4*)(wp + tap * 64 + 16);
        float4 q5 = *(const float4*)(wp + tap * 64 + 20);
        float4 q6 = *(const float4*)(wp + tap * 64 + 24);
        float4 q7 = *(const float4*)(wp + tap * 64 + 28);
        float av = win[tap / 3][tap % 3];
        FMA32(acc, av);
      }
    }
  }

  // bias + relu + 2x2 maxpool (row pair lane^32, col pair lane^1) + store
  float bvv[32];
  {
    const float4* bp = (const float4*)(b1g + cob);
#pragma unroll
    for (int g = 0; g < 8; g++) *(float4*)&bvv[4 * g] = bp[g];
  }
  int Hp = 120, Wp = 160;
  int py = (y0 + r) >> 1, pxp = (x0 + c) >> 1;
  bool ok = ((r & 1) == 0) && ((c & 1) == 0);
#pragma unroll
  for (int j = 0; j < 32; j++) {
    float h = fmaxf(acc[j] + bvv[j], 0.f);
    float hv = fmaxf(h, __shfl_xor(h, 32, 64));
    float hh = fmaxf(hv, __shfl_xor(hv, 1, 64));
    if (ok)
      out[(((size_t)n * 64 + cob + j) * Hp + py) * Wp + pxp] = hh;
  }
}

// =====================================================================
// Head: conv9 (1x1, 256->65) + bias + softmax(65) + dustbin drop + shuffle.
// 2-lane teams. Also zeroes the prob_nms/pred output region.
// =====================================================================
__global__ __launch_bounds__(256) void k_head(
    const float* __restrict__ act, const float* __restrict__ w9, const float* __restrict__ b9,
    float* __restrict__ prob, float* __restrict__ zbase)
{
  __shared__ float wl[256 * 68];
  int n = blockIdx.y;
  int tid = threadIdx.x;

  // zero onms+opred (2*614400 floats) across all 80 blocks
  {
    float4* z = (float4*)zbase;
    int gid = (blockIdx.y * gridDim.x + blockIdx.x) * 256 + tid;
    for (int k = gid; k < 307200; k += 20480)
      z[k] = make_float4(0.f, 0.f, 0.f, 0.f);
  }

  for (int k = tid; k < 65 * 256; k += 256) {
    int co = k / 256, ci = k % 256;
    wl[ci * 68 + co] = w9[k];
  }
  for (int ci = tid; ci < 256; ci += 256) {
    wl[ci * 68 + 65] = 0.f; wl[ci * 68 + 66] = 0.f; wl[ci * 68 + 67] = 0.f;
  }
  __syncthreads();
  int px = blockIdx.x * 128 + (tid >> 1);
  int half = tid & 1;
  bool live = (px < 1200);
  int cbase = half * 34;
  int nreal = half ? 31 : 34;    // real co count (incl. dustbin 64 on odd)

  float accv[34];
#pragma unroll
  for (int i = 0; i < 34; i++) accv[i] = 0.f;

  if (live) {
    for (int ci = 0; ci < 256; ++ci) {
      float a = act[((size_t)n * 256 + ci) * 1200 + px];
      const float2* wp = (const float2*)&wl[ci * 68 + cbase];
#pragma unroll
      for (int g = 0; g < 17; g++) {
        float2 wv = wp[g];
        accv[g * 2 + 0] = fmaf(a, wv.x, accv[g * 2 + 0]);
        accv[g * 2 + 1] = fmaf(a, wv.y, accv[g * 2 + 1]);
      }
    }
  }
  for (int i = 0; i < 34; i++)
    if (i < nreal) accv[i] += b9[cbase + i];
  float m = -1e30f;
  for (int i = 0; i < 34; i++)
    if (i < nreal) m = fmaxf(m, accv[i]);
  m = fmaxf(m, __shfl_xor(m, 1, 64));
  float s = 0.f;
  for (int i = 0; i < 34; i++)
    if (i < nreal) { accv[i] = __expf(accv[i] - m); s += accv[i]; }
  s += __shfl_xor(s, 1, 64);
  float inv = 1.f / s;

  if (live) {
    int hc = px / 40, wc = px % 40;
    float* pb = prob + (size_t)n * 76800;
    int nw = half ? 30 : 34;     // write only co < 64
    for (int i = 0; i < nw; i++) {
      int co = cbase + i;
      pb[(hc * 8 + (co >> 3)) * 320 + wc * 8 + (co & 7)] = accv[i] * inv;
    }
  }
}

// =====================================================================
// Exact reference NMS per image (16 per-wave radix histograms).
// =====================================================================
#define MAXC 1024
__global__ __launch_bounds__(1024) void k_nms(
    const float* __restrict__ prob, float* __restrict__ onms, float* __restrict__ opred)
{
  __shared__ unsigned sup[MAXC * 32];
  __shared__ unsigned long long skey[MAXC];
  __shared__ unsigned syx[MAXC];
  __shared__ unsigned hist[256];
  __shared__ unsigned vword[32];
  __shared__ unsigned sh_prefix, sh_K, sh_cG, sh_pG, sh_pE;

  int n = blockIdx.x;
  int tid = threadIdx.x;
  const float* p = prob + (size_t)n * 76800;
  float* on = onms + (size_t)n * 76800;
  float* op = opred + (size_t)n * 76800;

  if (tid == 0) { sh_prefix = 0u; sh_K = MAXC; sh_cG = 0u; sh_pG = 0u; sh_pE = 0u; }

  unsigned* h16 = sup;   // 16 waves x 256 bins (sup unused until later)
  int wv = tid >> 6;
  for (int round = 0; round < 4; ++round) {
    for (int k = tid; k < 4096; k += 1024) h16[k] = 0u;
    __syncthreads();
    unsigned prefix = sh_prefix;
    int shift = 24 - 8 * round;
    unsigned maskHi = (round == 0) ? 0u : (0xFFFFFFFFu << (shift + 8));
    for (int k = tid; k < 76800; k += 1024) {
      unsigned b = __float_as_uint(p[k]);
      if ((b & maskHi) == prefix) atomicAdd(&h16[wv * 256 + ((b >> shift) & 255)], 1u);
    }
    __syncthreads();
    if (tid < 256) {
      unsigned s = 0u;
#pragma unroll
      for (int w = 0; w < 16; w++) s += h16[w * 256 + tid];
      hist[tid] = s;
    }
    __syncthreads();
    if (tid == 0) {
      unsigned K = sh_K, cum = 0u;
      int bin = 255;
      for (; bin >= 0; --bin) {
        unsigned cgt = hist[bin];
        if (cum + cgt >= K) break;
        cum += cgt;
      }
      sh_prefix = prefix | ((unsigned)bin << shift);
      sh_K = K - cum;
      sh_cG += cum;
    }
    __syncthreads();
  }
  unsigned T = sh_prefix;
  unsigned Kfill = sh_K;
  unsigned Cgt = sh_cG;

  unsigned* eq = sup;
  __syncthreads();
  for (int k = tid; k < 76800; k += 1024) {
    unsigned b = __float_as_uint(p[k]);
    if (b > T) {
      unsigned pos = atomicAdd(&sh_pG, 1u);
      skey[pos] = ((unsigned long long)b << 32) | (unsigned)(~(unsigned)k);
    } else if (b == T) {
      unsigned pos = atomicAdd(&sh_pE, 1u);
      if (pos < 2048u) eq[pos] = (unsigned)k;
    }
  }
  __syncthreads();
  unsigned cE = sh_pE;
  for (int k = tid; k < 2048; k += 1024)
    if ((unsigned)k >= cE) eq[k] = 0xFFFFFFFFu;
  __syncthreads();
  for (int k = 2; k <= 2048; k <<= 1) {
    for (int j = k >> 1; j > 0; j >>= 1) {
      int t = tid;
      int i = ((t & ~(j - 1)) << 1) | (t & (j - 1));
      int l = i | j;
      bool up = ((i & k) == 0);
      unsigned a = eq[i], b2 = eq[l];
      if (up ? (a > b2) : (a < b2)) { eq[i] = b2; eq[l] = a; }
      __syncthreads();
    }
  }
  for (int m2 = tid; m2 < (int)Kfill; m2 += 1024)
    skey[Cgt + m2] = ((unsigned long long)T << 32) | (unsigned)(~eq[m2]);
  __syncthreads();

  for (int k = 2; k <= MAXC; k <<= 1) {
    for (int j = k >> 1; j > 0; j >>= 1) {
      int i = tid;
      int l = i ^ j;
      if (l > i) {
        unsigned long long a = skey[i], b2 = skey[l];
        bool up = ((i & k) == 0);
        if (up ? (a < b2) : (a > b2)) { skey[i] = b2; skey[l] = a; }
      }
      __syncthreads();
    }
  }

  if (tid < 32) vword[tid] = 0u;
  __syncthreads();
  {
    unsigned long long key = skey[tid];
    unsigned vb = (unsigned)(key >> 32);
    float val = __uint_as_float(vb);
    unsigned id = ~(unsigned)key;
    unsigned y = id / 320u, xx = id - 320u * y;
    syx[tid] = (y << 16) | xx;
    if (val > DET_THRESH) atomicOr(&vword[tid >> 5], 1u << (tid & 31));
  }
  __syncthreads();

  {
    unsigned myyx = syx[tid];
    int ty = (int)(myyx >> 16), tx = (int)(myyx & 0xFFFFu);
    for (int w = 0; w < 32; ++w) {
      unsigned bits = 0u;
#pragma unroll 8
      for (int b2 = 0; b2 < 32; ++b2) {
        int j = w * 32 + b2;
        if (j > tid) {
          unsigned o = syx[j];
          int dy = ty - (int)(o >> 16); dy = dy < 0 ? -dy : dy;
          int dx = tx - (int)(o & 0xFFFFu); dx = dx < 0 ? -dx : dx;
          if (((dy | dx) < 4) && (dy + dx) <= 4) bits |= 1u << b2;
        }
      }
      sup[tid * 32 + w] = bits;
    }
  }
  __syncthreads();

  if (tid < 64) {
    int lw = tid;
    unsigned keepw = (lw < 32) ? vword[lw] : 0u;
    for (int i = 0; i < MAXC; ++i) {
      unsigned kword = __shfl(keepw, i >> 5, 64);
      if ((kword >> (i & 31)) & 1u) {
        if (lw < 32) keepw &= ~sup[i * 32 + lw];
      }
    }
    unsigned pc = (lw < 32) ? (unsigned)__builtin_popcount(keepw) : 0u;
    unsigned incl = pc;
    for (int d = 1; d < 32; d <<= 1) {
      unsigned t2 = __shfl_up(incl, d, 64);
      if (lw >= d) incl += t2;
    }
    unsigned excl = incl - pc;
    if (lw < 32) {
      int quota = 300 - (int)excl;
      if (quota <= 0) keepw = 0u;
      else if ((int)pc > quota) {
        while (__builtin_popcount(keepw) > quota)
          keepw &= ~(1u << (31 - __builtin_clz(keepw)));
      }
      unsigned kw = keepw;
      while (kw) {
        int b2 = __builtin_ffs((int)kw) - 1;
        kw &= kw - 1u;
        int i = lw * 32 + b2;
        unsigned long long key = skey[i];
        float v = __uint_as_float((unsigned)(key >> 32));
        unsigned id = ~(unsigned)key;
        on[id] = v;
        op[id] = v;
      }
    }
  }
}

// =====================================================================
extern "C" void kernel_launch(void* const* d_in, const int* in_sizes, int n_in,
                              void* d_out, int out_size, void* d_ws, size_t ws_size,
                              hipStream_t stream) {
  const float* x = (const float*)d_in[0];
  const float* w[10];
  const float* b[10];
  for (int i = 0; i < 10; ++i) {
    w[i] = (const float*)d_in[1 + 2 * i];
    b[i] = (const float*)d_in[2 + 2 * i];
  }
  float* A = (float*)d_ws;
  float* B = A + 9830400;        // 64*120*160*8
  float* prob  = (float*)d_out;
  float* onms  = prob + 614400;  // 8*240*320
  float* opred = onms + 614400;

  // Transposed weights live in the onms/opred region (dead until k_head
  // zeroes it; k_nms then scatters). Total 921600 floats <= 1228800.
  float* wT1 = onms;
  float* wT2 = wT1 + 36864;
  float* wT3 = wT2 + 36864;
  float* wT4 = wT3 + 36864;
  float* wT5 = wT4 + 73728;
  float* wT6 = wT5 + 147456;
  float* wT7 = wT6 + 147456;
  float* wT8 = wT7 + 147456;

  TP tp;
  tp.src[0] = w[1]; tp.dst[0] = wT1; tp.cin[0] = 64;  tp.cout[0] = 64;
  tp.src[1] = w[2]; tp.dst[1] = wT2; tp.cin[1] = 64;  tp.cout[1] = 64;
  tp.src[2] = w[3]; tp.dst[2] = wT3; tp.cin[2] = 64;  tp.cout[2] = 64;
  tp.src[3] = w[4]; tp.dst[3] = wT4; tp.cin[3] = 64;  tp.cout[3] = 128;
  tp.src[4] = w[5]; tp.dst[4] = wT5; tp.cin[4] = 128; tp.cout[4] = 128;
  tp.src[5] = w[6]; tp.dst[5] = wT6; tp.cin[5] = 128; tp.cout[5] = 128;
  tp.src[6] = w[7]; tp.dst[6] = wT7; tp.cin[6] = 128; tp.cout[6] = 128;
  tp.src[7] = w[8]; tp.dst[7] = wT8; tp.cin[7] = 128; tp.cout[7] = 256;
  k_wT<<<dim3(1152, 8), 256, 0, stream>>>(tp);

  // conv0+conv1+pool -> A (8,64,120,160). 32x8 tiles 10x30, 2 co-blocks.
  k_f01<<<dim3(300, 2, 8), 256, 0, stream>>>(x, w[0], b[0], wT1, b[1], A);
  // conv2 -> B (8,64,120,160). 32x8 tiles 5x15, 2 co-blocks.
  k_conv32<32, 8, false><<<dim3(75, 2, 8), 256, 0, stream>>>(A, wT2, b[2], B, 64, 64, 120, 160, 5);
  // conv3+pool -> A (8,64,60,80)
  k_conv32<32, 8, true ><<<dim3(75, 2, 8), 256, 0, stream>>>(B, wT3, b[3], A, 64, 64, 120, 160, 5);
  // conv4 -> B (8,128,60,80). 40x6 tiles 2x10, 4 co-blocks.
  k_conv32<40, 6, false><<<dim3(20, 4, 8), 256, 0, stream>>>(A, wT4, b[4], B, 64, 128, 60, 80, 2);
  // conv5+pool -> A (8,128,30,40). 32x8 tiles 3x8 (edge-masked), 4 co-blocks.
  k_conv32<32, 8, true ><<<dim3(24, 4, 8), 256, 0, stream>>>(B, wT5, b[5], A, 128, 128, 60, 80, 3);
  // conv6 -> B (8,128,30,40). 40x6 tiles 1x5, 4 co-blocks.
  k_conv32<40, 6, false><<<dim3(5, 4, 8), 256, 0, stream>>>(A, wT6, b[6], B, 128, 128, 30, 40, 1);
  // conv7 -> A
  k_conv32<40, 6, false><<<dim3(5, 4, 8), 256, 0, stream>>>(B, wT7, b[7], A, 128, 128, 30, 40, 1);
  // conv8 -> B (8,256,30,40). 8 co-blocks.
  k_conv32<40, 6, false><<<dim3(5, 8, 8), 256, 0, stream>>>(A, wT8, b[8], B, 128, 256, 30, 40, 1);
  // convPb + softmax + shuffle -> prob; also zeroes onms/opred.
  k_head<<<dim3(10, 8), 256, 0, stream>>>(B, w[9], b[9], prob, onms);
  // NMS + top-300 -> prob_nms, pred
  k_nms<<<dim3(8), 1024, 0, stream>>>(prob, onms, opred);
}

// Round 14
// 2153.808 us; speedup vs baseline: 1.4125x; 1.3166x over previous
//
#include <hip/hip_runtime.h>
#include <stdint.h>

#define DET_THRESH 0.015f

// 16-FMA and 32-FMA bundles (scalar v_fma: fp32 pipe is 128 lanes/CU/cyc;
// packed v_pk_fma_f32 takes 2 slots for 2 FMAs -- no gain, r12 measured).
#define FMA16(ACC, AV) do { \
  ACC[0]  = fmaf(AV, q0.x, ACC[0]);  ACC[1]  = fmaf(AV, q0.y, ACC[1]);  \
  ACC[2]  = fmaf(AV, q0.z, ACC[2]);  ACC[3]  = fmaf(AV, q0.w, ACC[3]);  \
  ACC[4]  = fmaf(AV, q1.x, ACC[4]);  ACC[5]  = fmaf(AV, q1.y, ACC[5]);  \
  ACC[6]  = fmaf(AV, q1.z, ACC[6]);  ACC[7]  = fmaf(AV, q1.w, ACC[7]);  \
  ACC[8]  = fmaf(AV, q2.x, ACC[8]);  ACC[9]  = fmaf(AV, q2.y, ACC[9]);  \
  ACC[10] = fmaf(AV, q2.z, ACC[10]); ACC[11] = fmaf(AV, q2.w, ACC[11]); \
  ACC[12] = fmaf(AV, q3.x, ACC[12]); ACC[13] = fmaf(AV, q3.y, ACC[13]); \
  ACC[14] = fmaf(AV, q3.z, ACC[14]); ACC[15] = fmaf(AV, q3.w, ACC[15]); } while (0)

#define FMA32(ACC, AV) do { \
  FMA16(ACC, AV); \
  ACC[16] = fmaf(AV, q4.x, ACC[16]); ACC[17] = fmaf(AV, q4.y, ACC[17]); \
  ACC[18] = fmaf(AV, q4.z, ACC[18]); ACC[19] = fmaf(AV, q4.w, ACC[19]); \
  ACC[20] = fmaf(AV, q5.x, ACC[20]); ACC[21] = fmaf(AV, q5.y, ACC[21]); \
  ACC[22] = fmaf(AV, q5.z, ACC[22]); ACC[23] = fmaf(AV, q5.w, ACC[23]); \
  ACC[24] = fmaf(AV, q6.x, ACC[24]); ACC[25] = fmaf(AV, q6.y, ACC[25]); \
  ACC[26] = fmaf(AV, q6.z, ACC[26]); ACC[27] = fmaf(AV, q6.w, ACC[27]); \
  ACC[28] = fmaf(AV, q7.x, ACC[28]); ACC[29] = fmaf(AV, q7.y, ACC[29]); \
  ACC[30] = fmaf(AV, q7.z, ACC[30]); ACC[31] = fmaf(AV, q7.w, ACC[31]); } while (0)

// =====================================================================
// Weight pre-transpose: w[co][ci][tap] -> wT[ci*9+tap][co]  (per layer)
// =====================================================================
struct TP {
  const float* src[8];
  float* dst[8];
  int cin[8];
  int cout[8];
};

__global__ __launch_bounds__(256) void k_wT(TP tp) {
  int l = blockIdx.y;
  int n = tp.cin[l] * tp.cout[l] * 9;
  int k = blockIdx.x * 256 + threadIdx.x;
  if (k >= n) return;
  int ci9 = tp.cin[l] * 9;
  int co = k / ci9;
  int r = k - co * ci9;             // r = ci*9 + tap
  tp.dst[l][(size_t)r * tp.cout[l] + co] = tp.src[l][k];
}

// =====================================================================
// Generic 3x3 conv, 16 co/thread (r10's proven-best geometry for the
// pure conv layers -- the 32-co variant regressed them by ~670us total:
// halved block counts + VGPR 36 < the ~45 needed, partial AGPR parking).
// Tile: TW cols x TH rows x 16 co.
// =====================================================================
template <int TW, int TH, bool POOL>
__global__ __launch_bounds__(256) void k_conv(
    const float* __restrict__ in, const float* __restrict__ wT, const float* __restrict__ bias,
    float* __restrict__ out, int CIN, int COUT, int H, int W, int tilesX)
{
  constexpr int SR = TH + 2;
  constexpr int SC = TW + 2;
  constexpr int LC = TW + 4;
  constexpr int TOTAL = 4 * SR * SC;
  __shared__ float ain[4][SR][LC];

  int tile = blockIdx.x;
  int tx = tile % tilesX, ty = tile / tilesX;
  int x0 = tx * TW, y0 = ty * TH;
  int cob = blockIdx.y * 16;
  int n = blockIdx.z;

  int tid = threadIdx.x;
  int r, c;
  if (TW == 32) { r = tid >> 5; c = tid & 31; }
  else          { r = tid / TW; c = tid - r * TW; }
  bool live = (TW * TH >= 256) || (tid < TW * TH);
  int rE = live ? r : 0;

  bool full = (y0 >= 1) && (y0 + TH + 1 <= H) && (x0 >= 1) && (x0 + TW + 1 <= W);
  size_t imgBase = (size_t)n * CIN * H * W;

  float acc[16];
#pragma unroll
  for (int j = 0; j < 16; j++) acc[j] = 0.f;

  int nch = CIN >> 2;
  for (int cc = 0; cc < nch; ++cc) {
    __syncthreads();
    if (full) {
      const float* src = in + imgBase + (size_t)(cc * 4) * H * W + (y0 - 1) * W + (x0 - 1);
      for (int m = tid; m < TOTAL; m += 256) {
        int ci = m / (SR * SC);
        int rem = m - ci * (SR * SC);
        int rr = rem / SC;
        int col = rem - rr * SC;
        ain[ci][rr][col] = src[(size_t)ci * H * W + rr * W + col];
      }
    } else {
      for (int m = tid; m < TOTAL; m += 256) {
        int ci = m / (SR * SC);
        int rem = m - ci * (SR * SC);
        int rr = rem / SC;
        int col = rem - rr * SC;
        int gy = y0 - 1 + rr, gx = x0 - 1 + col;
        float v = 0.f;
        if (gy >= 0 && gy < H && gx >= 0 && gx < W)
          v = in[imgBase + ((size_t)(cc * 4 + ci) * H + gy) * W + gx];
        ain[ci][rr][col] = v;
      }
    }
    __syncthreads();
#pragma unroll
    for (int ci = 0; ci < 4; ++ci) {
      float win[3][3];
#pragma unroll
      for (int dy = 0; dy < 3; dy++) {
        win[dy][0] = ain[ci][rE + dy][c];
        win[dy][1] = ain[ci][rE + dy][c + 1];
        win[dy][2] = ain[ci][rE + dy][c + 2];
      }
      const float* wp = wT + (size_t)((cc * 4 + ci) * 9) * COUT + cob;
#pragma unroll
      for (int tap = 0; tap < 9; tap++) {
        float4 q0 = *(const float4*)(wp + tap * COUT);
        float4 q1 = *(const float4*)(wp + tap * COUT + 4);
        float4 q2 = *(const float4*)(wp + tap * COUT + 8);
        float4 q3 = *(const float4*)(wp + tap * COUT + 12);
        float av = win[tap / 3][tap % 3];
        FMA16(acc, av);
      }
    }
  }

  float bvv[16];
  {
    const float4* bp = (const float4*)(bias + cob);
    *(float4*)&bvv[0] = bp[0]; *(float4*)&bvv[4] = bp[1];
    *(float4*)&bvv[8] = bp[2]; *(float4*)&bvv[12] = bp[3];
  }
  int x = x0 + c;
  int y = y0 + r;
  if (!POOL) {
    if (live && y < H && x < W) {
#pragma unroll
      for (int j = 0; j < 16; j++)
        out[(((size_t)n * COUT + cob + j) * H + y) * W + x] = fmaxf(acc[j] + bvv[j], 0.f);
    }
  } else {
    // TW==32 only
    int Hp = H >> 1, Wp = W >> 1;
    int py = y >> 1, pxp = x >> 1;
    bool ok = ((r & 1) == 0) && ((c & 1) == 0) && (py < Hp) && (pxp < Wp);
#pragma unroll
    for (int j = 0; j < 16; j++) {
      float h = fmaxf(acc[j] + bvv[j], 0.f);
      float hc = fmaxf(h, __shfl_xor(h, 1, 64));    // col pair
      float hv = fmaxf(hc, __shfl_xor(hc, 32, 64)); // row pair
      if (ok)
        out[(((size_t)n * COUT + cob + j) * Hp + py) * Wp + pxp] = hv;
    }
  }
}

// =====================================================================
// Fused conv0(1->64)+relu -> conv1(64->64)+relu -> 2x2 maxpool.
// 32x8 tile, 1 row x 32 co (r13: 586us = ~77 TF, near the 78.6 TF
// scalar-FMA ceiling; the 2-co-block split halves conv0 recompute).
// =====================================================================
__global__ __launch_bounds__(256) void k_f01(
    const float* __restrict__ x, const float* __restrict__ w0g, const float* __restrict__ b0g,
    const float* __restrict__ wT1, const float* __restrict__ b1g, float* __restrict__ out)
{
  const int H = 240, W = 320;
  __shared__ float in_raw[12][36];
  __shared__ float a0[4][10][36];
  __shared__ float w0l[576];
  __shared__ float b0l[64];

  int tile = blockIdx.x;              // tilesX=10, tilesY=30
  int tx = tile % 10, ty = tile / 10;
  int x0 = tx * 32, y0 = ty * 8;
  int cob = blockIdx.y * 32;          // 0..1
  int n = blockIdx.z;

  int tid = threadIdx.x;
  int r = tid >> 5;
  int c = tid & 31;

  bool fullT = (y0 >= 1) && (y0 + 9 <= H) && (x0 >= 1) && (x0 + 33 <= W);

  for (int k = tid; k < 576; k += 256) w0l[k] = w0g[k];
  if (tid < 64) b0l[tid] = b0g[tid];
  for (int m = tid; m < 432; m += 256) {
    int rr = m / 36, col = m - rr * 36;
    int gy = y0 - 2 + rr, gx = x0 - 2 + col;
    in_raw[rr][col] = (gy >= 0 && gy < H && gx >= 0 && gx < W)
                          ? x[(size_t)n * (H * W) + gy * W + gx] : 0.f;
  }

  float acc[32];
#pragma unroll
  for (int j = 0; j < 32; j++) acc[j] = 0.f;

  for (int cc = 0; cc < 16; ++cc) {
    __syncthreads();                  // in_raw/w0l ready; a0 free
    // conv0 chunk -> a0 (zero OUTSIDE image: conv1 'SAME' zero-padding)
    if (fullT) {
      for (int m = tid; m < 1360; m += 256) {
        int ch = m / 340;
        int rem = m - ch * 340;
        int rr = rem / 34;
        int col = rem - rr * 34;
        const float* wp = &w0l[(cc * 4 + ch) * 9];
        float s = b0l[cc * 4 + ch];
#pragma unroll
        for (int dy = 0; dy < 3; dy++)
#pragma unroll
          for (int dx = 0; dx < 3; dx++)
            s = fmaf(in_raw[rr + dy][col + dx], wp[dy * 3 + dx], s);
        a0[ch][rr][col] = fmaxf(s, 0.f);
      }
    } else {
      for (int m = tid; m < 1360; m += 256) {
        int ch = m / 340;
        int rem = m - ch * 340;
        int rr = rem / 34;
        int col = rem - rr * 34;
        int gy = y0 - 1 + rr, gx = x0 - 1 + col;
        float v = 0.f;
        if (gy >= 0 && gy < H && gx >= 0 && gx < W) {
          const float* wp = &w0l[(cc * 4 + ch) * 9];
          float s = b0l[cc * 4 + ch];
#pragma unroll
          for (int dy = 0; dy < 3; dy++)
#pragma unroll
            for (int dx = 0; dx < 3; dx++)
              s = fmaf(in_raw[rr + dy][col + dx], wp[dy * 3 + dx], s);
          v = fmaxf(s, 0.f);
        }
        a0[ch][rr][col] = v;
      }
    }
    __syncthreads();
#pragma unroll
    for (int ci = 0; ci < 4; ++ci) {
      float win[3][3];
#pragma unroll
      for (int dy = 0; dy < 3; dy++) {
        win[dy][0] = a0[ci][r + dy][c];
        win[dy][1] = a0[ci][r + dy][c + 1];
        win[dy][2] = a0[ci][r + dy][c + 2];
      }
      const float* wp = wT1 + (size_t)((cc * 4 + ci) * 9) * 64 + cob;
#pragma unroll
      for (int tap = 0; tap < 9; tap++) {
        float4 q0 = *(const float4*)(wp + tap * 64);
        float4 q1 = *(const float4*)(wp + tap * 64 + 4);
        float4 q2 = *(const float4*)(wp + tap * 64 + 8);
        float4 q3 = *(const float4*)(wp + tap * 64 + 12);
        float4 q4 = *(const float4*)(wp + tap * 64 + 16);
        float4 q5 = *(const float4*)(wp + tap * 64 + 20);
        float4 q6 = *(const float4*)(wp + tap * 64 + 24);
        float4 q7 = *(const float4*)(wp + tap * 64 + 28);
        float av = win[tap / 3][tap % 3];
        FMA32(acc, av);
      }
    }
  }

  // bias + relu + 2x2 maxpool (row pair lane^32, col pair lane^1) + store
  float bvv[32];
  {
    const float4* bp = (const float4*)(b1g + cob);
#pragma unroll
    for (int g = 0; g < 8; g++) *(float4*)&bvv[4 * g] = bp[g];
  }
  int Hp = 120, Wp = 160;
  int py = (y0 + r) >> 1, pxp = (x0 + c) >> 1;
  bool ok = ((r & 1) == 0) && ((c & 1) == 0);
#pragma unroll
  for (int j = 0; j < 32; j++) {
    float h = fmaxf(acc[j] + bvv[j], 0.f);
    float hv = fmaxf(h, __shfl_xor(h, 32, 64));
    float hh = fmaxf(hv, __shfl_xor(hv, 1, 64));
    if (ok)
      out[(((size_t)n * 64 + cob + j) * Hp + py) * Wp + pxp] = hh;
  }
}

// =====================================================================
// Head: conv9 (1x1, 256->65) + bias + softmax(65) + dustbin drop + shuffle.
// 2-lane teams. Also zeroes the prob_nms/pred output region.
// =====================================================================
__global__ __launch_bounds__(256) void k_head(
    const float* __restrict__ act, const float* __restrict__ w9, const float* __restrict__ b9,
    float* __restrict__ prob, float* __restrict__ zbase)
{
  __shared__ float wl[256 * 68];
  int n = blockIdx.y;
  int tid = threadIdx.x;

  // zero onms+opred (2*614400 floats) across all 80 blocks
  {
    float4* z = (float4*)zbase;
    int gid = (blockIdx.y * gridDim.x + blockIdx.x) * 256 + tid;
    for (int k = gid; k < 307200; k += 20480)
      z[k] = make_float4(0.f, 0.f, 0.f, 0.f);
  }

  for (int k = tid; k < 65 * 256; k += 256) {
    int co = k / 256, ci = k % 256;
    wl[ci * 68 + co] = w9[k];
  }
  for (int ci = tid; ci < 256; ci += 256) {
    wl[ci * 68 + 65] = 0.f; wl[ci * 68 + 66] = 0.f; wl[ci * 68 + 67] = 0.f;
  }
  __syncthreads();
  int px = blockIdx.x * 128 + (tid >> 1);
  int half = tid & 1;
  bool live = (px < 1200);
  int cbase = half * 34;
  int nreal = half ? 31 : 34;    // real co count (incl. dustbin 64 on odd)

  float accv[34];
#pragma unroll
  for (int i = 0; i < 34; i++) accv[i] = 0.f;

  if (live) {
    for (int ci = 0; ci < 256; ++ci) {
      float a = act[((size_t)n * 256 + ci) * 1200 + px];
      const float2* wp = (const float2*)&wl[ci * 68 + cbase];
#pragma unroll
      for (int g = 0; g < 17; g++) {
        float2 wv = wp[g];
        accv[g * 2 + 0] = fmaf(a, wv.x, accv[g * 2 + 0]);
        accv[g * 2 + 1] = fmaf(a, wv.y, accv[g * 2 + 1]);
      }
    }
  }
  for (int i = 0; i < 34; i++)
    if (i < nreal) accv[i] += b9[cbase + i];
  float m = -1e30f;
  for (int i = 0; i < 34; i++)
    if (i < nreal) m = fmaxf(m, accv[i]);
  m = fmaxf(m, __shfl_xor(m, 1, 64));
  float s = 0.f;
  for (int i = 0; i < 34; i++)
    if (i < nreal) { accv[i] = __expf(accv[i] - m); s += accv[i]; }
  s += __shfl_xor(s, 1, 64);
  float inv = 1.f / s;

  if (live) {
    int hc = px / 40, wc = px % 40;
    float* pb = prob + (size_t)n * 76800;
    int nw = half ? 30 : 34;     // write only co < 64
    for (int i = 0; i < nw; i++) {
      int co = cbase + i;
      pb[(hc * 8 + (co >> 3)) * 320 + wc * 8 + (co & 7)] = accv[i] * inv;
    }
  }
}

// =====================================================================
// Exact reference NMS per image (16 per-wave radix histograms).
// =====================================================================
#define MAXC 1024
__global__ __launch_bounds__(1024) void k_nms(
    const float* __restrict__ prob, float* __restrict__ onms, float* __restrict__ opred)
{
  __shared__ unsigned sup[MAXC * 32];
  __shared__ unsigned long long skey[MAXC];
  __shared__ unsigned syx[MAXC];
  __shared__ unsigned hist[256];
  __shared__ unsigned vword[32];
  __shared__ unsigned sh_prefix, sh_K, sh_cG, sh_pG, sh_pE;

  int n = blockIdx.x;
  int tid = threadIdx.x;
  const float* p = prob + (size_t)n * 76800;
  float* on = onms + (size_t)n * 76800;
  float* op = opred + (size_t)n * 76800;

  if (tid == 0) { sh_prefix = 0u; sh_K = MAXC; sh_cG = 0u; sh_pG = 0u; sh_pE = 0u; }

  unsigned* h16 = sup;   // 16 waves x 256 bins (sup unused until later)
  int wv = tid >> 6;
  for (int round = 0; round < 4; ++round) {
    for (int k = tid; k < 4096; k += 1024) h16[k] = 0u;
    __syncthreads();
    unsigned prefix = sh_prefix;
    int shift = 24 - 8 * round;
    unsigned maskHi = (round == 0) ? 0u : (0xFFFFFFFFu << (shift + 8));
    for (int k = tid; k < 76800; k += 1024) {
      unsigned b = __float_as_uint(p[k]);
      if ((b & maskHi) == prefix) atomicAdd(&h16[wv * 256 + ((b >> shift) & 255)], 1u);
    }
    __syncthreads();
    if (tid < 256) {
      unsigned s = 0u;
#pragma unroll
      for (int w = 0; w < 16; w++) s += h16[w * 256 + tid];
      hist[tid] = s;
    }
    __syncthreads();
    if (tid == 0) {
      unsigned K = sh_K, cum = 0u;
      int bin = 255;
      for (; bin >= 0; --bin) {
        unsigned cgt = hist[bin];
        if (cum + cgt >= K) break;
        cum += cgt;
      }
      sh_prefix = prefix | ((unsigned)bin << shift);
      sh_K = K - cum;
      sh_cG += cum;
    }
    __syncthreads();
  }
  unsigned T = sh_prefix;
  unsigned Kfill = sh_K;
  unsigned Cgt = sh_cG;

  unsigned* eq = sup;
  __syncthreads();
  for (int k = tid; k < 76800; k += 1024) {
    unsigned b = __float_as_uint(p[k]);
    if (b > T) {
      unsigned pos = atomicAdd(&sh_pG, 1u);
      skey[pos] = ((unsigned long long)b << 32) | (unsigned)(~(unsigned)k);
    } else if (b == T) {
      unsigned pos = atomicAdd(&sh_pE, 1u);
      if (pos < 2048u) eq[pos] = (unsigned)k;
    }
  }
  __syncthreads();
  unsigned cE = sh_pE;
  for (int k = tid; k < 2048; k += 1024)
    if ((unsigned)k >= cE) eq[k] = 0xFFFFFFFFu;
  __syncthreads();
  for (int k = 2; k <= 2048; k <<= 1) {
    for (int j = k >> 1; j > 0; j >>= 1) {
      int t = tid;
      int i = ((t & ~(j - 1)) << 1) | (t & (j - 1));
      int l = i | j;
      bool up = ((i & k) == 0);
      unsigned a = eq[i], b2 = eq[l];
      if (up ? (a > b2) : (a < b2)) { eq[i] = b2; eq[l] = a; }
      __syncthreads();
    }
  }
  for (int m2 = tid; m2 < (int)Kfill; m2 += 1024)
    skey[Cgt + m2] = ((unsigned long long)T << 32) | (unsigned)(~eq[m2]);
  __syncthreads();

  for (int k = 2; k <= MAXC; k <<= 1) {
    for (int j = k >> 1; j > 0; j >>= 1) {
      int i = tid;
      int l = i ^ j;
      if (l > i) {
        unsigned long long a = skey[i], b2 = skey[l];
        bool up = ((i & k) == 0);
        if (up ? (a < b2) : (a > b2)) { skey[i] = b2; skey[l] = a; }
      }
      __syncthreads();
    }
  }

  if (tid < 32) vword[tid] = 0u;
  __syncthreads();
  {
    unsigned long long key = skey[tid];
    unsigned vb = (unsigned)(key >> 32);
    float val = __uint_as_float(vb);
    unsigned id = ~(unsigned)key;
    unsigned y = id / 320u, xx = id - 320u * y;
    syx[tid] = (y << 16) | xx;
    if (val > DET_THRESH) atomicOr(&vword[tid >> 5], 1u << (tid & 31));
  }
  __syncthreads();

  {
    unsigned myyx = syx[tid];
    int ty = (int)(myyx >> 16), tx = (int)(myyx & 0xFFFFu);
    for (int w = 0; w < 32; ++w) {
      unsigned bits = 0u;
#pragma unroll 8
      for (int b2 = 0; b2 < 32; ++b2) {
        int j = w * 32 + b2;
        if (j > tid) {
          unsigned o = syx[j];
          int dy = ty - (int)(o >> 16); dy = dy < 0 ? -dy : dy;
          int dx = tx - (int)(o & 0xFFFFu); dx = dx < 0 ? -dx : dx;
          if (((dy | dx) < 4) && (dy + dx) <= 4) bits |= 1u << b2;
        }
      }
      sup[tid * 32 + w] = bits;
    }
  }
  __syncthreads();

  if (tid < 64) {
    int lw = tid;
    unsigned keepw = (lw < 32) ? vword[lw] : 0u;
    for (int i = 0; i < MAXC; ++i) {
      unsigned kword = __shfl(keepw, i >> 5, 64);
      if ((kword >> (i & 31)) & 1u) {
        if (lw < 32) keepw &= ~sup[i * 32 + lw];
      }
    }
    unsigned pc = (lw < 32) ? (unsigned)__builtin_popcount(keepw) : 0u;
    unsigned incl = pc;
    for (int d = 1; d < 32; d <<= 1) {
      unsigned t2 = __shfl_up(incl, d, 64);
      if (lw >= d) incl += t2;
    }
    unsigned excl = incl - pc;
    if (lw < 32) {
      int quota = 300 - (int)excl;
      if (quota <= 0) keepw = 0u;
      else if ((int)pc > quota) {
        while (__builtin_popcount(keepw) > quota)
          keepw &= ~(1u << (31 - __builtin_clz(keepw)));
      }
      unsigned kw = keepw;
      while (kw) {
        int b2 = __builtin_ffs((int)kw) - 1;
        kw &= kw - 1u;
        int i = lw * 32 + b2;
        unsigned long long key = skey[i];
        float v = __uint_as_float((unsigned)(key >> 32));
        unsigned id = ~(unsigned)key;
        on[id] = v;
        op[id] = v;
      }
    }
  }
}

// =====================================================================
extern "C" void kernel_launch(void* const* d_in, const int* in_sizes, int n_in,
                              void* d_out, int out_size, void* d_ws, size_t ws_size,
                              hipStream_t stream) {
  const float* x = (const float*)d_in[0];
  const float* w[10];
  const float* b[10];
  for (int i = 0; i < 10; ++i) {
    w[i] = (const float*)d_in[1 + 2 * i];
    b[i] = (const float*)d_in[2 + 2 * i];
  }
  float* A = (float*)d_ws;
  float* B = A + 9830400;        // 64*120*160*8
  float* prob  = (float*)d_out;
  float* onms  = prob + 614400;  // 8*240*320
  float* opred = onms + 614400;

  // Transposed weights live in the onms/opred region (dead until k_head
  // zeroes it; k_nms then scatters). Total 921600 floats <= 1228800.
  float* wT1 = onms;
  float* wT2 = wT1 + 36864;
  float* wT3 = wT2 + 36864;
  float* wT4 = wT3 + 36864;
  float* wT5 = wT4 + 73728;
  float* wT6 = wT5 + 147456;
  float* wT7 = wT6 + 147456;
  float* wT8 = wT7 + 147456;

  TP tp;
  tp.src[0] = w[1]; tp.dst[0] = wT1; tp.cin[0] = 64;  tp.cout[0] = 64;
  tp.src[1] = w[2]; tp.dst[1] = wT2; tp.cin[1] = 64;  tp.cout[1] = 64;
  tp.src[2] = w[3]; tp.dst[2] = wT3; tp.cin[2] = 64;  tp.cout[2] = 64;
  tp.src[3] = w[4]; tp.dst[3] = wT4; tp.cin[3] = 64;  tp.cout[3] = 128;
  tp.src[4] = w[5]; tp.dst[4] = wT5; tp.cin[4] = 128; tp.cout[4] = 128;
  tp.src[5] = w[6]; tp.dst[5] = wT6; tp.cin[5] = 128; tp.cout[5] = 128;
  tp.src[6] = w[7]; tp.dst[6] = wT7; tp.cin[6] = 128; tp.cout[6] = 128;
  tp.src[7] = w[8]; tp.dst[7] = wT8; tp.cin[7] = 128; tp.cout[7] = 256;
  k_wT<<<dim3(1152, 8), 256, 0, stream>>>(tp);

  // conv0+conv1+pool -> A (8,64,120,160). 32x8 tiles 10x30, 2 co-blocks (32co).
  k_f01<<<dim3(300, 2, 8), 256, 0, stream>>>(x, w[0], b[0], wT1, b[1], A);
  // conv2 -> B (8,64,120,160). 32x8x16co, (75,4,8).
  k_conv<32, 8, false><<<dim3(75, 4, 8), 256, 0, stream>>>(A, wT2, b[2], B, 64, 64, 120, 160, 5);
  // conv3+pool -> A (8,64,60,80)
  k_conv<32, 8, true ><<<dim3(75, 4, 8), 256, 0, stream>>>(B, wT3, b[3], A, 64, 64, 120, 160, 5);
  // conv4 -> B (8,128,60,80). 40x6x16co, (20,8,8).
  k_conv<40, 6, false><<<dim3(20, 8, 8), 256, 0, stream>>>(A, wT4, b[4], B, 64, 128, 60, 80, 2);
  // conv5+pool -> A (8,128,30,40). 32x8x16co, (24,8,8).
  k_conv<32, 8, true ><<<dim3(24, 8, 8), 256, 0, stream>>>(B, wT5, b[5], A, 128, 128, 60, 80, 3);
  // conv6 -> B (8,128,30,40). 40x6x16co, (5,8,8).
  k_conv<40, 6, false><<<dim3(5, 8, 8), 256, 0, stream>>>(A, wT6, b[6], B, 128, 128, 30, 40, 1);
  // conv7 -> A
  k_conv<40, 6, false><<<dim3(5, 8, 8), 256, 0, stream>>>(B, wT7, b[7], A, 128, 128, 30, 40, 1);
  // conv8 -> B (8,256,30,40). (5,16,8).
  k_conv<40, 6, false><<<dim3(5, 16, 8), 256, 0, stream>>>(A, wT8, b[8], B, 128, 256, 30, 40, 1);
  // convPb + softmax + shuffle -> prob; also zeroes onms/opred.
  k_head<<<dim3(10, 8), 256, 0, stream>>>(B, w[9], b[9], prob, onms);
  // NMS + top-300 -> prob_nms, pred
  k_nms<<<dim3(8), 1024, 0, stream>>>(prob, onms, opred);
}

// Round 15
// 1844.999 us; speedup vs baseline: 1.6489x; 1.1674x over previous
//
#include <hip/hip_runtime.h>
#include <stdint.h>

#define DET_THRESH 0.015f

#define FMA16(ACC, AV) do { \
  ACC[0]  = fmaf(AV, q0.x, ACC[0]);  ACC[1]  = fmaf(AV, q0.y, ACC[1]);  \
  ACC[2]  = fmaf(AV, q0.z, ACC[2]);  ACC[3]  = fmaf(AV, q0.w, ACC[3]);  \
  ACC[4]  = fmaf(AV, q1.x, ACC[4]);  ACC[5]  = fmaf(AV, q1.y, ACC[5]);  \
  ACC[6]  = fmaf(AV, q1.z, ACC[6]);  ACC[7]  = fmaf(AV, q1.w, ACC[7]);  \
  ACC[8]  = fmaf(AV, q2.x, ACC[8]);  ACC[9]  = fmaf(AV, q2.y, ACC[9]);  \
  ACC[10] = fmaf(AV, q2.z, ACC[10]); ACC[11] = fmaf(AV, q2.w, ACC[11]); \
  ACC[12] = fmaf(AV, q3.x, ACC[12]); ACC[13] = fmaf(AV, q3.y, ACC[13]); \
  ACC[14] = fmaf(AV, q3.z, ACC[14]); ACC[15] = fmaf(AV, q3.w, ACC[15]); } while (0)

#define FMA32(ACC, AV) do { \
  FMA16(ACC, AV); \
  ACC[16] = fmaf(AV, q4.x, ACC[16]); ACC[17] = fmaf(AV, q4.y, ACC[17]); \
  ACC[18] = fmaf(AV, q4.z, ACC[18]); ACC[19] = fmaf(AV, q4.w, ACC[19]); \
  ACC[20] = fmaf(AV, q5.x, ACC[20]); ACC[21] = fmaf(AV, q5.y, ACC[21]); \
  ACC[22] = fmaf(AV, q5.z, ACC[22]); ACC[23] = fmaf(AV, q5.w, ACC[23]); \
  ACC[24] = fmaf(AV, q6.x, ACC[24]); ACC[25] = fmaf(AV, q6.y, ACC[25]); \
  ACC[26] = fmaf(AV, q6.z, ACC[26]); ACC[27] = fmaf(AV, q6.w, ACC[27]); \
  ACC[28] = fmaf(AV, q7.x, ACC[28]); ACC[29] = fmaf(AV, q7.y, ACC[29]); \
  ACC[30] = fmaf(AV, q7.z, ACC[30]); ACC[31] = fmaf(AV, q7.w, ACC[31]); } while (0)

// =====================================================================
// Weight pre-transpose: w[co][ci][tap] -> wT[ci*9+tap][co]  (per layer)
// =====================================================================
struct TP {
  const float* src[8];
  float* dst[8];
  int cin[8];
  int cout[8];
};

__global__ __launch_bounds__(256) void k_wT(TP tp) {
  int l = blockIdx.y;
  int n = tp.cin[l] * tp.cout[l] * 9;
  int k = blockIdx.x * 256 + threadIdx.x;
  if (k >= n) return;
  int ci9 = tp.cin[l] * 9;
  int co = k / ci9;
  int r = k - co * ci9;             // r = ci*9 + tap
  tp.dst[l][(size_t)r * tp.cout[l] + co] = tp.src[l][k];
}

// =====================================================================
// Generic 3x3 conv, 16 co/thread (r10 geometry, proven best for the
// large pure-conv layers). Tile: TW cols x TH rows x 16 co.
// =====================================================================
template <int TW, int TH, bool POOL>
__global__ __launch_bounds__(256) void k_conv(
    const float* __restrict__ in, const float* __restrict__ wT, const float* __restrict__ bias,
    float* __restrict__ out, int CIN, int COUT, int H, int W, int tilesX)
{
  constexpr int SR = TH + 2;
  constexpr int SC = TW + 2;
  constexpr int LC = TW + 4;
  constexpr int TOTAL = 4 * SR * SC;
  __shared__ float ain[4][SR][LC];

  int tile = blockIdx.x;
  int tx = tile % tilesX, ty = tile / tilesX;
  int x0 = tx * TW, y0 = ty * TH;
  int cob = blockIdx.y * 16;
  int n = blockIdx.z;

  int tid = threadIdx.x;
  int r, c;
  if (TW == 32) { r = tid >> 5; c = tid & 31; }
  else          { r = tid / TW; c = tid - r * TW; }
  bool live = (TW * TH >= 256) || (tid < TW * TH);
  int rE = live ? r : 0;

  bool full = (y0 >= 1) && (y0 + TH + 1 <= H) && (x0 >= 1) && (x0 + TW + 1 <= W);
  size_t imgBase = (size_t)n * CIN * H * W;

  float acc[16];
#pragma unroll
  for (int j = 0; j < 16; j++) acc[j] = 0.f;

  int nch = CIN >> 2;
  for (int cc = 0; cc < nch; ++cc) {
    __syncthreads();
    if (full) {
      const float* src = in + imgBase + (size_t)(cc * 4) * H * W + (y0 - 1) * W + (x0 - 1);
      for (int m = tid; m < TOTAL; m += 256) {
        int ci = m / (SR * SC);
        int rem = m - ci * (SR * SC);
        int rr = rem / SC;
        int col = rem - rr * SC;
        ain[ci][rr][col] = src[(size_t)ci * H * W + rr * W + col];
      }
    } else {
      for (int m = tid; m < TOTAL; m += 256) {
        int ci = m / (SR * SC);
        int rem = m - ci * (SR * SC);
        int rr = rem / SC;
        int col = rem - rr * SC;
        int gy = y0 - 1 + rr, gx = x0 - 1 + col;
        float v = 0.f;
        if (gy >= 0 && gy < H && gx >= 0 && gx < W)
          v = in[imgBase + ((size_t)(cc * 4 + ci) * H + gy) * W + gx];
        ain[ci][rr][col] = v;
      }
    }
    __syncthreads();
#pragma unroll
    for (int ci = 0; ci < 4; ++ci) {
      float win[3][3];
#pragma unroll
      for (int dy = 0; dy < 3; dy++) {
        win[dy][0] = ain[ci][rE + dy][c];
        win[dy][1] = ain[ci][rE + dy][c + 1];
        win[dy][2] = ain[ci][rE + dy][c + 2];
      }
      const float* wp = wT + (size_t)((cc * 4 + ci) * 9) * COUT + cob;
#pragma unroll
      for (int tap = 0; tap < 9; tap++) {
        float4 q0 = *(const float4*)(wp + tap * COUT);
        float4 q1 = *(const float4*)(wp + tap * COUT + 4);
        float4 q2 = *(const float4*)(wp + tap * COUT + 8);
        float4 q3 = *(const float4*)(wp + tap * COUT + 12);
        float av = win[tap / 3][tap % 3];
        FMA16(acc, av);
      }
    }
  }

  float bvv[16];
  {
    const float4* bp = (const float4*)(bias + cob);
    *(float4*)&bvv[0] = bp[0]; *(float4*)&bvv[4] = bp[1];
    *(float4*)&bvv[8] = bp[2]; *(float4*)&bvv[12] = bp[3];
  }
  int x = x0 + c;
  int y = y0 + r;
  if (!POOL) {
    if (live && y < H && x < W) {
#pragma unroll
      for (int j = 0; j < 16; j++)
        out[(((size_t)n * COUT + cob + j) * H + y) * W + x] = fmaxf(acc[j] + bvv[j], 0.f);
    }
  } else {
    // TW==32 only
    int Hp = H >> 1, Wp = W >> 1;
    int py = y >> 1, pxp = x >> 1;
    bool ok = ((r & 1) == 0) && ((c & 1) == 0) && (py < Hp) && (pxp < Wp);
#pragma unroll
    for (int j = 0; j < 16; j++) {
      float h = fmaxf(acc[j] + bvv[j], 0.f);
      float hc = fmaxf(h, __shfl_xor(h, 1, 64));    // col pair
      float hv = fmaxf(hc, __shfl_xor(hc, 32, 64)); // row pair
      if (ok)
        out[(((size_t)n * COUT + cob + j) * Hp + py) * Wp + pxp] = hv;
    }
  }
}

// =====================================================================
// ci-split partial conv for the 30x40 layers (CIN=128). Each block does
// a 32-ci slice (split = blockIdx.z & 3) -> 4x the blocks of the fused
// version (conv6/7 were at 1.25 waves/SIMD -- pure latency exposure).
// Partial sums (no bias/relu) go to per-split slabs; k_fuse reduces.
// Tile 40x6, 16 co/thread.
// =====================================================================
__global__ __launch_bounds__(256) void k_convp(
    const float* __restrict__ in, const float* __restrict__ wT,
    float* __restrict__ pout, int COUT)
{
  const int H = 30, W = 40;
  constexpr int SR = 8, SC = 42, LC = 44;
  constexpr int TOTAL = 4 * SR * SC;   // 1344
  __shared__ float ain[4][SR][LC];

  int y0 = blockIdx.x * 6;             // 0..4
  int cob = blockIdx.y * 16;
  int z = blockIdx.z;
  int n = z >> 2, split = z & 3;

  int tid = threadIdx.x;
  int r = tid / 40, c = tid - r * 40;
  bool live = tid < 240;
  int rE = live ? r : 0;

  size_t imgBase = (size_t)n * 128 * 1200;

  float acc[16];
#pragma unroll
  for (int j = 0; j < 16; j++) acc[j] = 0.f;

  int cc0 = split * 8;
  for (int cc = cc0; cc < cc0 + 8; ++cc) {
    __syncthreads();
    for (int m = tid; m < TOTAL; m += 256) {
      int ci = m / (SR * SC);
      int rem = m - ci * (SR * SC);
      int rr = rem / SC;
      int col = rem - rr * SC;
      int gy = y0 - 1 + rr, gx = col - 1;
      float v = 0.f;
      if (gy >= 0 && gy < H && gx >= 0 && gx < W)
        v = in[imgBase + ((size_t)(cc * 4 + ci) * H + gy) * W + gx];
      ain[ci][rr][col] = v;
    }
    __syncthreads();
#pragma unroll
    for (int ci = 0; ci < 4; ++ci) {
      float win[3][3];
#pragma unroll
      for (int dy = 0; dy < 3; dy++) {
        win[dy][0] = ain[ci][rE + dy][c];
        win[dy][1] = ain[ci][rE + dy][c + 1];
        win[dy][2] = ain[ci][rE + dy][c + 2];
      }
      const float* wp = wT + (size_t)((cc * 4 + ci) * 9) * COUT + cob;
#pragma unroll
      for (int tap = 0; tap < 9; tap++) {
        float4 q0 = *(const float4*)(wp + tap * COUT);
        float4 q1 = *(const float4*)(wp + tap * COUT + 4);
        float4 q2 = *(const float4*)(wp + tap * COUT + 8);
        float4 q3 = *(const float4*)(wp + tap * COUT + 12);
        float av = win[tap / 3][tap % 3];
        FMA16(acc, av);
      }
    }
  }

  int y = y0 + r;
  if (live && y < H) {
    float* po = pout + (size_t)split * (8 * (size_t)COUT * 1200)
              + ((size_t)n * COUT + cob) * 1200 + y * 40 + c;
#pragma unroll
    for (int j = 0; j < 16; j++)
      po[(size_t)j * 1200] = acc[j];
  }
}

// sum 4 partial slabs + bias + relu
__global__ __launch_bounds__(256) void k_fuse(
    const float* __restrict__ pin, const float* __restrict__ bias,
    float* __restrict__ out, int COUT)
{
  int idx = blockIdx.x * 256 + threadIdx.x;
  int total = 8 * COUT * 1200;
  if (idx >= total) return;
  int co = (idx / 1200) % COUT;
  size_t slab = (size_t)8 * COUT * 1200;
  float s = pin[idx] + pin[idx + slab] + pin[idx + 2 * slab] + pin[idx + 3 * slab] + bias[co];
  out[idx] = fmaxf(s, 0.f);
}

// =====================================================================
// Fused conv0(1->64)+relu -> conv1(64->64)+relu -> 2x2 maxpool.
// 32x8 tile, 1 row x 32 co (r13/r14: 584us = 98% of scalar-FMA issue).
// =====================================================================
__global__ __launch_bounds__(256) void k_f01(
    const float* __restrict__ x, const float* __restrict__ w0g, const float* __restrict__ b0g,
    const float* __restrict__ wT1, const float* __restrict__ b1g, float* __restrict__ out)
{
  const int H = 240, W = 320;
  __shared__ float in_raw[12][36];
  __shared__ float a0[4][10][36];
  __shared__ float w0l[576];
  __shared__ float b0l[64];

  int tile = blockIdx.x;              // tilesX=10, tilesY=30
  int tx = tile % 10, ty = tile / 10;
  int x0 = tx * 32, y0 = ty * 8;
  int cob = blockIdx.y * 32;          // 0..1
  int n = blockIdx.z;

  int tid = threadIdx.x;
  int r = tid >> 5;
  int c = tid & 31;

  bool fullT = (y0 >= 1) && (y0 + 9 <= H) && (x0 >= 1) && (x0 + 33 <= W);

  for (int k = tid; k < 576; k += 256) w0l[k] = w0g[k];
  if (tid < 64) b0l[tid] = b0g[tid];
  for (int m = tid; m < 432; m += 256) {
    int rr = m / 36, col = m - rr * 36;
    int gy = y0 - 2 + rr, gx = x0 - 2 + col;
    in_raw[rr][col] = (gy >= 0 && gy < H && gx >= 0 && gx < W)
                          ? x[(size_t)n * (H * W) + gy * W + gx] : 0.f;
  }

  float acc[32];
#pragma unroll
  for (int j = 0; j < 32; j++) acc[j] = 0.f;

  for (int cc = 0; cc < 16; ++cc) {
    __syncthreads();                  // in_raw/w0l ready; a0 free
    if (fullT) {
      for (int m = tid; m < 1360; m += 256) {
        int ch = m / 340;
        int rem = m - ch * 340;
        int rr = rem / 34;
        int col = rem - rr * 34;
        const float* wp = &w0l[(cc * 4 + ch) * 9];
        float s = b0l[cc * 4 + ch];
#pragma unroll
        for (int dy = 0; dy < 3; dy++)
#pragma unroll
          for (int dx = 0; dx < 3; dx++)
            s = fmaf(in_raw[rr + dy][col + dx], wp[dy * 3 + dx], s);
        a0[ch][rr][col] = fmaxf(s, 0.f);
      }
    } else {
      for (int m = tid; m < 1360; m += 256) {
        int ch = m / 340;
        int rem = m - ch * 340;
        int rr = rem / 34;
        int col = rem - rr * 34;
        int gy = y0 - 1 + rr, gx = x0 - 1 + col;
        float v = 0.f;
        if (gy >= 0 && gy < H && gx >= 0 && gx < W) {
          const float* wp = &w0l[(cc * 4 + ch) * 9];
          float s = b0l[cc * 4 + ch];
#pragma unroll
          for (int dy = 0; dy < 3; dy++)
#pragma unroll
            for (int dx = 0; dx < 3; dx++)
              s = fmaf(in_raw[rr + dy][col + dx], wp[dy * 3 + dx], s);
          v = fmaxf(s, 0.f);
        }
        a0[ch][rr][col] = v;
      }
    }
    __syncthreads();
#pragma unroll
    for (int ci = 0; ci < 4; ++ci) {
      float win[3][3];
#pragma unroll
      for (int dy = 0; dy < 3; dy++) {
        win[dy][0] = a0[ci][r + dy][c];
        win[dy][1] = a0[ci][r + dy][c + 1];
        win[dy][2] = a0[ci][r + dy][c + 2];
      }
      const float* wp = wT1 + (size_t)((cc * 4 + ci) * 9) * 64 + cob;
#pragma unroll
      for (int tap = 0; tap < 9; tap++) {
        float4 q0 = *(const float4*)(wp + tap * 64);
        float4 q1 = *(const float4*)(wp + tap * 64 + 4);
        float4 q2 = *(const float4*)(wp + tap * 64 + 8);
        float4 q3 = *(const float4*)(wp + tap * 64 + 12);
        float4 q4 = *(const float4*)(wp + tap * 64 + 16);
        float4 q5 = *(const float4*)(wp + tap * 64 + 20);
        float4 q6 = *(const float4*)(wp + tap * 64 + 24);
        float4 q7 = *(const float4*)(wp + tap * 64 + 28);
        float av = win[tap / 3][tap % 3];
        FMA32(acc, av);
      }
    }
  }

  float bvv[32];
  {
    const float4* bp = (const float4*)(b1g + cob);
#pragma unroll
    for (int g = 0; g < 8; g++) *(float4*)&bvv[4 * g] = bp[g];
  }
  int Hp = 120, Wp = 160;
  int py = (y0 + r) >> 1, pxp = (x0 + c) >> 1;
  bool ok = ((r & 1) == 0) && ((c & 1) == 0);
#pragma unroll
  for (int j = 0; j < 32; j++) {
    float h = fmaxf(acc[j] + bvv[j], 0.f);
    float hv = fmaxf(h, __shfl_xor(h, 32, 64));
    float hh = fmaxf(hv, __shfl_xor(hv, 1, 64));
    if (ok)
      out[(((size_t)n * 64 + cob + j) * Hp + py) * Wp + pxp] = hh;
  }
}

// =====================================================================
// Head: conv9 (1x1, 256->65) + bias + softmax(65) + dustbin drop + shuffle.
// 2-lane teams. Also zeroes the prob_nms/pred output region.
// =====================================================================
__global__ __launch_bounds__(256) void k_head(
    const float* __restrict__ act, const float* __restrict__ w9, const float* __restrict__ b9,
    float* __restrict__ prob, float* __restrict__ zbase)
{
  __shared__ float wl[256 * 68];
  int n = blockIdx.y;
  int tid = threadIdx.x;

  // zero onms+opred (2*614400 floats) across all 80 blocks
  {
    float4* z = (float4*)zbase;
    int gid = (blockIdx.y * gridDim.x + blockIdx.x) * 256 + tid;
    for (int k = gid; k < 307200; k += 20480)
      z[k] = make_float4(0.f, 0.f, 0.f, 0.f);
  }

  for (int k = tid; k < 65 * 256; k += 256) {
    int co = k / 256, ci = k % 256;
    wl[ci * 68 + co] = w9[k];
  }
  for (int ci = tid; ci < 256; ci += 256) {
    wl[ci * 68 + 65] = 0.f; wl[ci * 68 + 66] = 0.f; wl[ci * 68 + 67] = 0.f;
  }
  __syncthreads();
  int px = blockIdx.x * 128 + (tid >> 1);
  int half = tid & 1;
  bool live = (px < 1200);
  int cbase = half * 34;
  int nreal = half ? 31 : 34;    // real co count (incl. dustbin 64 on odd)

  float accv[34];
#pragma unroll
  for (int i = 0; i < 34; i++) accv[i] = 0.f;

  if (live) {
    for (int ci = 0; ci < 256; ++ci) {
      float a = act[((size_t)n * 256 + ci) * 1200 + px];
      const float2* wp = (const float2*)&wl[ci * 68 + cbase];
#pragma unroll
      for (int g = 0; g < 17; g++) {
        float2 wv = wp[g];
        accv[g * 2 + 0] = fmaf(a, wv.x, accv[g * 2 + 0]);
        accv[g * 2 + 1] = fmaf(a, wv.y, accv[g * 2 + 1]);
      }
    }
  }
  for (int i = 0; i < 34; i++)
    if (i < nreal) accv[i] += b9[cbase + i];
  float m = -1e30f;
  for (int i = 0; i < 34; i++)
    if (i < nreal) m = fmaxf(m, accv[i]);
  m = fmaxf(m, __shfl_xor(m, 1, 64));
  float s = 0.f;
  for (int i = 0; i < 34; i++)
    if (i < nreal) { accv[i] = __expf(accv[i] - m); s += accv[i]; }
  s += __shfl_xor(s, 1, 64);
  float inv = 1.f / s;

  if (live) {
    int hc = px / 40, wc = px % 40;
    float* pb = prob + (size_t)n * 76800;
    int nw = half ? 30 : 34;     // write only co < 64
    for (int i = 0; i < nw; i++) {
      int co = cbase + i;
      pb[(hc * 8 + (co >> 3)) * 320 + wc * 8 + (co & 7)] = accv[i] * inv;
    }
  }
}

// =====================================================================
// Exact reference NMS per image (16 per-wave radix histograms).
// =====================================================================
#define MAXC 1024
__global__ __launch_bounds__(1024) void k_nms(
    const float* __restrict__ prob, float* __restrict__ onms, float* __restrict__ opred)
{
  __shared__ unsigned sup[MAXC * 32];
  __shared__ unsigned long long skey[MAXC];
  __shared__ unsigned syx[MAXC];
  __shared__ unsigned hist[256];
  __shared__ unsigned vword[32];
  __shared__ unsigned sh_prefix, sh_K, sh_cG, sh_pG, sh_pE;

  int n = blockIdx.x;
  int tid = threadIdx.x;
  const float* p = prob + (size_t)n * 76800;
  float* on = onms + (size_t)n * 76800;
  float* op = opred + (size_t)n * 76800;

  if (tid == 0) { sh_prefix = 0u; sh_K = MAXC; sh_cG = 0u; sh_pG = 0u; sh_pE = 0u; }

  unsigned* h16 = sup;   // 16 waves x 256 bins (sup unused until later)
  int wv = tid >> 6;
  for (int round = 0; round < 4; ++round) {
    for (int k = tid; k < 4096; k += 1024) h16[k] = 0u;
    __syncthreads();
    unsigned prefix = sh_prefix;
    int shift = 24 - 8 * round;
    unsigned maskHi = (round == 0) ? 0u : (0xFFFFFFFFu << (shift + 8));
    for (int k = tid; k < 76800; k += 1024) {
      unsigned b = __float_as_uint(p[k]);
      if ((b & maskHi) == prefix) atomicAdd(&h16[wv * 256 + ((b >> shift) & 255)], 1u);
    }
    __syncthreads();
    if (tid < 256) {
      unsigned s = 0u;
#pragma unroll
      for (int w = 0; w < 16; w++) s += h16[w * 256 + tid];
      hist[tid] = s;
    }
    __syncthreads();
    if (tid == 0) {
      unsigned K = sh_K, cum = 0u;
      int bin = 255;
      for (; bin >= 0; --bin) {
        unsigned cgt = hist[bin];
        if (cum + cgt >= K) break;
        cum += cgt;
      }
      sh_prefix = prefix | ((unsigned)bin << shift);
      sh_K = K - cum;
      sh_cG += cum;
    }
    __syncthreads();
  }
  unsigned T = sh_prefix;
  unsigned Kfill = sh_K;
  unsigned Cgt = sh_cG;

  unsigned* eq = sup;
  __syncthreads();
  for (int k = tid; k < 76800; k += 1024) {
    unsigned b = __float_as_uint(p[k]);
    if (b > T) {
      unsigned pos = atomicAdd(&sh_pG, 1u);
      skey[pos] = ((unsigned long long)b << 32) | (unsigned)(~(unsigned)k);
    } else if (b == T) {
      unsigned pos = atomicAdd(&sh_pE, 1u);
      if (pos < 2048u) eq[pos] = (unsigned)k;
    }
  }
  __syncthreads();
  unsigned cE = sh_pE;
  for (int k = tid; k < 2048; k += 1024)
    if ((unsigned)k >= cE) eq[k] = 0xFFFFFFFFu;
  __syncthreads();
  for (int k = 2; k <= 2048; k <<= 1) {
    for (int j = k >> 1; j > 0; j >>= 1) {
      int t = tid;
      int i = ((t & ~(j - 1)) << 1) | (t & (j - 1));
      int l = i | j;
      bool up = ((i & k) == 0);
      unsigned a = eq[i], b2 = eq[l];
      if (up ? (a > b2) : (a < b2)) { eq[i] = b2; eq[l] = a; }
      __syncthreads();
    }
  }
  for (int m2 = tid; m2 < (int)Kfill; m2 += 1024)
    skey[Cgt + m2] = ((unsigned long long)T << 32) | (unsigned)(~eq[m2]);
  __syncthreads();

  for (int k = 2; k <= MAXC; k <<= 1) {
    for (int j = k >> 1; j > 0; j >>= 1) {
      int i = tid;
      int l = i ^ j;
      if (l > i) {
        unsigned long long a = skey[i], b2 = skey[l];
        bool up = ((i & k) == 0);
        if (up ? (a < b2) : (a > b2)) { skey[i] = b2; skey[l] = a; }
      }
      __syncthreads();
    }
  }

  if (tid < 32) vword[tid] = 0u;
  __syncthreads();
  {
    unsigned long long key = skey[tid];
    unsigned vb = (unsigned)(key >> 32);
    float val = __uint_as_float(vb);
    unsigned id = ~(unsigned)key;
    unsigned y = id / 320u, xx = id - 320u * y;
    syx[tid] = (y << 16) | xx;
    if (val > DET_THRESH) atomicOr(&vword[tid >> 5], 1u << (tid & 31));
  }
  __syncthreads();

  {
    unsigned myyx = syx[tid];
    int ty = (int)(myyx >> 16), tx = (int)(myyx & 0xFFFFu);
    for (int w = 0; w < 32; ++w) {
      unsigned bits = 0u;
#pragma unroll 8
      for (int b2 = 0; b2 < 32; ++b2) {
        int j = w * 32 + b2;
        if (j > tid) {
          unsigned o = syx[j];
          int dy = ty - (int)(o >> 16); dy = dy < 0 ? -dy : dy;
          int dx = tx - (int)(o & 0xFFFFu); dx = dx < 0 ? -dx : dx;
          if (((dy | dx) < 4) && (dy + dx) <= 4) bits |= 1u << b2;
        }
      }
      sup[tid * 32 + w] = bits;
    }
  }
  __syncthreads();

  if (tid < 64) {
    int lw = tid;
    unsigned keepw = (lw < 32) ? vword[lw] : 0u;
    for (int i = 0; i < MAXC; ++i) {
      unsigned kword = __shfl(keepw, i >> 5, 64);
      if ((kword >> (i & 31)) & 1u) {
        if (lw < 32) keepw &= ~sup[i * 32 + lw];
      }
    }
    unsigned pc = (lw < 32) ? (unsigned)__builtin_popcount(keepw) : 0u;
    unsigned incl = pc;
    for (int d = 1; d < 32; d <<= 1) {
      unsigned t2 = __shfl_up(incl, d, 64);
      if (lw >= d) incl += t2;
    }
    unsigned excl = incl - pc;
    if (lw < 32) {
      int quota = 300 - (int)excl;
      if (quota <= 0) keepw = 0u;
      else if ((int)pc > quota) {
        while (__builtin_popcount(keepw) > quota)
          keepw &= ~(1u << (31 - __builtin_clz(keepw)));
      }
      unsigned kw = keepw;
      while (kw) {
        int b2 = __builtin_ffs((int)kw) - 1;
        kw &= kw - 1u;
        int i = lw * 32 + b2;
        unsigned long long key = skey[i];
        float v = __uint_as_float((unsigned)(key >> 32));
        unsigned id = ~(unsigned)key;
        on[id] = v;
        op[id] = v;
      }
    }
  }
}

// =====================================================================
extern "C" void kernel_launch(void* const* d_in, const int* in_sizes, int n_in,
                              void* d_out, int out_size, void* d_ws, size_t ws_size,
                              hipStream_t stream) {
  const float* x = (const float*)d_in[0];
  const float* w[10];
  const float* b[10];
  for (int i = 0; i < 10; ++i) {
    w[i] = (const float*)d_in[1 + 2 * i];
    b[i] = (const float*)d_in[2 + 2 * i];
  }
  float* A = (float*)d_ws;
  float* B = A + 9830400;        // 64*120*160*8
  float* prob  = (float*)d_out;
  float* onms  = prob + 614400;  // 8*240*320
  float* opred = onms + 614400;

  // Transposed weights live in the onms/opred region (dead until k_head
  // zeroes it; k_nms then scatters). Total 921600 floats <= 1228800.
  float* wT1 = onms;
  float* wT2 = wT1 + 36864;
  float* wT3 = wT2 + 36864;
  float* wT4 = wT3 + 36864;
  float* wT5 = wT4 + 73728;
  float* wT6 = wT5 + 147456;
  float* wT7 = wT6 + 147456;
  float* wT8 = wT7 + 147456;

  TP tp;
  tp.src[0] = w[1]; tp.dst[0] = wT1; tp.cin[0] = 64;  tp.cout[0] = 64;
  tp.src[1] = w[2]; tp.dst[1] = wT2; tp.cin[1] = 64;  tp.cout[1] = 64;
  tp.src[2] = w[3]; tp.dst[2] = wT3; tp.cin[2] = 64;  tp.cout[2] = 64;
  tp.src[3] = w[4]; tp.dst[3] = wT4; tp.cin[3] = 64;  tp.cout[3] = 128;
  tp.src[4] = w[5]; tp.dst[4] = wT5; tp.cin[4] = 128; tp.cout[4] = 128;
  tp.src[5] = w[6]; tp.dst[5] = wT6; tp.cin[5] = 128; tp.cout[5] = 128;
  tp.src[6] = w[7]; tp.dst[6] = wT7; tp.cin[6] = 128; tp.cout[6] = 128;
  tp.src[7] = w[8]; tp.dst[7] = wT8; tp.cin[7] = 128; tp.cout[7] = 256;
  k_wT<<<dim3(1152, 8), 256, 0, stream>>>(tp);

  // conv0+conv1+pool -> A (8,64,120,160). 32x8 tiles 10x30, 2 co-blocks (32co).
  k_f01<<<dim3(300, 2, 8), 256, 0, stream>>>(x, w[0], b[0], wT1, b[1], A);
  // conv2 -> B (8,64,120,160). 32x8x16co.
  k_conv<32, 8, false><<<dim3(75, 4, 8), 256, 0, stream>>>(A, wT2, b[2], B, 64, 64, 120, 160, 5);
  // conv3+pool -> A (8,64,60,80)
  k_conv<32, 8, true ><<<dim3(75, 4, 8), 256, 0, stream>>>(B, wT3, b[3], A, 64, 64, 120, 160, 5);
  // conv4 -> B (8,128,60,80). 40x6x16co.
  k_conv<40, 6, false><<<dim3(20, 8, 8), 256, 0, stream>>>(A, wT4, b[4], B, 64, 128, 60, 80, 2);
  // conv5+pool -> A (8,128,30,40). 32x8x16co.
  k_conv<32, 8, true ><<<dim3(24, 8, 8), 256, 0, stream>>>(B, wT5, b[5], A, 128, 128, 60, 80, 3);

  // 30x40 layers: ci-split x4 (4x blocks; were 1.25 waves/SIMD).
  float* C6 = B + 4915200;  // conv6 output (1.2M floats)
  float* C7 = A + 4915200;  // conv7 output
  // conv6: A -> partials in B[0..4.9M]; fuse -> C6
  k_convp<<<dim3(5, 8, 32), 256, 0, stream>>>(A, wT6, B, 128);
  k_fuse<<<4800, 256, 0, stream>>>(B, b[6], C6, 128);
  // conv7: C6 -> partials in A[0..4.9M]; fuse -> C7
  k_convp<<<dim3(5, 8, 32), 256, 0, stream>>>(C6, wT7, A, 128);
  k_fuse<<<4800, 256, 0, stream>>>(A, b[7], C7, 128);
  // conv8: C7 -> partials fill B exactly (4 x 2.4576M); fuse -> A[0..2.4M]
  k_convp<<<dim3(5, 16, 32), 256, 0, stream>>>(C7, wT8, B, 256);
  k_fuse<<<9600, 256, 0, stream>>>(B, b[8], A, 256);

  // convPb + softmax + shuffle -> prob; also zeroes onms/opred.
  k_head<<<dim3(10, 8), 256, 0, stream>>>(A, w[9], b[9], prob, onms);
  // NMS + top-300 -> prob_nms, pred
  k_nms<<<dim3(8), 1024, 0, stream>>>(prob, onms, opred);
}

// Round 16
// 1835.269 us; speedup vs baseline: 1.6577x; 1.0053x over previous
//
#include <hip/hip_runtime.h>
#include <stdint.h>

#define DET_THRESH 0.015f

#define FMA16(ACC, AV) do { \
  ACC[0]  = fmaf(AV, q0.x, ACC[0]);  ACC[1]  = fmaf(AV, q0.y, ACC[1]);  \
  ACC[2]  = fmaf(AV, q0.z, ACC[2]);  ACC[3]  = fmaf(AV, q0.w, ACC[3]);  \
  ACC[4]  = fmaf(AV, q1.x, ACC[4]);  ACC[5]  = fmaf(AV, q1.y, ACC[5]);  \
  ACC[6]  = fmaf(AV, q1.z, ACC[6]);  ACC[7]  = fmaf(AV, q1.w, ACC[7]);  \
  ACC[8]  = fmaf(AV, q2.x, ACC[8]);  ACC[9]  = fmaf(AV, q2.y, ACC[9]);  \
  ACC[10] = fmaf(AV, q2.z, ACC[10]); ACC[11] = fmaf(AV, q2.w, ACC[11]); \
  ACC[12] = fmaf(AV, q3.x, ACC[12]); ACC[13] = fmaf(AV, q3.y, ACC[13]); \
  ACC[14] = fmaf(AV, q3.z, ACC[14]); ACC[15] = fmaf(AV, q3.w, ACC[15]); } while (0)

#define FMA32(ACC, AV) do { \
  FMA16(ACC, AV); \
  ACC[16] = fmaf(AV, q4.x, ACC[16]); ACC[17] = fmaf(AV, q4.y, ACC[17]); \
  ACC[18] = fmaf(AV, q4.z, ACC[18]); ACC[19] = fmaf(AV, q4.w, ACC[19]); \
  ACC[20] = fmaf(AV, q5.x, ACC[20]); ACC[21] = fmaf(AV, q5.y, ACC[21]); \
  ACC[22] = fmaf(AV, q5.z, ACC[22]); ACC[23] = fmaf(AV, q5.w, ACC[23]); \
  ACC[24] = fmaf(AV, q6.x, ACC[24]); ACC[25] = fmaf(AV, q6.y, ACC[25]); \
  ACC[26] = fmaf(AV, q6.z, ACC[26]); ACC[27] = fmaf(AV, q6.w, ACC[27]); \
  ACC[28] = fmaf(AV, q7.x, ACC[28]); ACC[29] = fmaf(AV, q7.y, ACC[29]); \
  ACC[30] = fmaf(AV, q7.z, ACC[30]); ACC[31] = fmaf(AV, q7.w, ACC[31]); } while (0)

// =====================================================================
// Weight pre-transpose: w[co][ci][tap] -> wT[ci*9+tap][co]  (per layer)
// =====================================================================
struct TP {
  const float* src[8];
  float* dst[8];
  int cin[8];
  int cout[8];
};

__global__ __launch_bounds__(256) void k_wT(TP tp) {
  int l = blockIdx.y;
  int n = tp.cin[l] * tp.cout[l] * 9;
  int k = blockIdx.x * 256 + threadIdx.x;
  if (k >= n) return;
  int ci9 = tp.cin[l] * 9;
  int co = k / ci9;
  int r = k - co * ci9;             // r = ci*9 + tap
  tp.dst[l][(size_t)r * tp.cout[l] + co] = tp.src[l][k];
}

// =====================================================================
// Generic 3x3 conv body, 16 co/thread (r10 geometry). Shared by the
// per-layer named kernels kc2..kc5 (distinct names -> per-layer rocprof).
// =====================================================================
template <int TW, int TH, bool POOL>
__device__ __forceinline__ void conv_body(
    const float* __restrict__ in, const float* __restrict__ wT, const float* __restrict__ bias,
    float* __restrict__ out, int CIN, int COUT, int H, int W, int tilesX)
{
  constexpr int SR = TH + 2;
  constexpr int SC = TW + 2;
  constexpr int LC = TW + 4;
  constexpr int TOTAL = 4 * SR * SC;
  __shared__ float ain[4][SR][LC];

  int tile = blockIdx.x;
  int tx = tile % tilesX, ty = tile / tilesX;
  int x0 = tx * TW, y0 = ty * TH;
  int cob = blockIdx.y * 16;
  int n = blockIdx.z;

  int tid = threadIdx.x;
  int r, c;
  if (TW == 32) { r = tid >> 5; c = tid & 31; }
  else          { r = tid / TW; c = tid - r * TW; }
  bool live = (TW * TH >= 256) || (tid < TW * TH);
  int rE = live ? r : 0;

  bool full = (y0 >= 1) && (y0 + TH + 1 <= H) && (x0 >= 1) && (x0 + TW + 1 <= W);
  size_t imgBase = (size_t)n * CIN * H * W;

  float acc[16];
#pragma unroll
  for (int j = 0; j < 16; j++) acc[j] = 0.f;

  int nch = CIN >> 2;
  for (int cc = 0; cc < nch; ++cc) {
    __syncthreads();
    if (full) {
      const float* src = in + imgBase + (size_t)(cc * 4) * H * W + (y0 - 1) * W + (x0 - 1);
      for (int m = tid; m < TOTAL; m += 256) {
        int ci = m / (SR * SC);
        int rem = m - ci * (SR * SC);
        int rr = rem / SC;
        int col = rem - rr * SC;
        ain[ci][rr][col] = src[(size_t)ci * H * W + rr * W + col];
      }
    } else {
      for (int m = tid; m < TOTAL; m += 256) {
        int ci = m / (SR * SC);
        int rem = m - ci * (SR * SC);
        int rr = rem / SC;
        int col = rem - rr * SC;
        int gy = y0 - 1 + rr, gx = x0 - 1 + col;
        float v = 0.f;
        if (gy >= 0 && gy < H && gx >= 0 && gx < W)
          v = in[imgBase + ((size_t)(cc * 4 + ci) * H + gy) * W + gx];
        ain[ci][rr][col] = v;
      }
    }
    __syncthreads();
#pragma unroll
    for (int ci = 0; ci < 4; ++ci) {
      float win[3][3];
#pragma unroll
      for (int dy = 0; dy < 3; dy++) {
        win[dy][0] = ain[ci][rE + dy][c];
        win[dy][1] = ain[ci][rE + dy][c + 1];
        win[dy][2] = ain[ci][rE + dy][c + 2];
      }
      const float* wp = wT + (size_t)((cc * 4 + ci) * 9) * COUT + cob;
#pragma unroll
      for (int tap = 0; tap < 9; tap++) {
        float4 q0 = *(const float4*)(wp + tap * COUT);
        float4 q1 = *(const float4*)(wp + tap * COUT + 4);
        float4 q2 = *(const float4*)(wp + tap * COUT + 8);
        float4 q3 = *(const float4*)(wp + tap * COUT + 12);
        float av = win[tap / 3][tap % 3];
        FMA16(acc, av);
      }
    }
  }

  float bvv[16];
  {
    const float4* bp = (const float4*)(bias + cob);
    *(float4*)&bvv[0] = bp[0]; *(float4*)&bvv[4] = bp[1];
    *(float4*)&bvv[8] = bp[2]; *(float4*)&bvv[12] = bp[3];
  }
  int x = x0 + c;
  int y = y0 + r;
  if (!POOL) {
    if (live && y < H && x < W) {
#pragma unroll
      for (int j = 0; j < 16; j++)
        out[(((size_t)n * COUT + cob + j) * H + y) * W + x] = fmaxf(acc[j] + bvv[j], 0.f);
    }
  } else {
    // TW==32 only
    int Hp = H >> 1, Wp = W >> 1;
    int py = y >> 1, pxp = x >> 1;
    bool ok = ((r & 1) == 0) && ((c & 1) == 0) && (py < Hp) && (pxp < Wp);
#pragma unroll
    for (int j = 0; j < 16; j++) {
      float h = fmaxf(acc[j] + bvv[j], 0.f);
      float hc = fmaxf(h, __shfl_xor(h, 1, 64));    // col pair
      float hv = fmaxf(hc, __shfl_xor(hc, 32, 64)); // row pair
      if (ok)
        out[(((size_t)n * COUT + cob + j) * Hp + py) * Wp + pxp] = hv;
    }
  }
}

__global__ __launch_bounds__(256) void kc2(const float* in, const float* wT, const float* bias,
                                           float* out, int CIN, int COUT, int H, int W, int tX)
{ conv_body<32, 8, false>(in, wT, bias, out, CIN, COUT, H, W, tX); }
__global__ __launch_bounds__(256) void kc3(const float* in, const float* wT, const float* bias,
                                           float* out, int CIN, int COUT, int H, int W, int tX)
{ conv_body<32, 8, true>(in, wT, bias, out, CIN, COUT, H, W, tX); }
__global__ __launch_bounds__(256) void kc4(const float* in, const float* wT, const float* bias,
                                           float* out, int CIN, int COUT, int H, int W, int tX)
{ conv_body<40, 6, false>(in, wT, bias, out, CIN, COUT, H, W, tX); }
__global__ __launch_bounds__(256) void kc5(const float* in, const float* wT, const float* bias,
                                           float* out, int CIN, int COUT, int H, int W, int tX)
{ conv_body<32, 8, true>(in, wT, bias, out, CIN, COUT, H, W, tX); }

// =====================================================================
// ci-split partial conv for the 30x40 layers (CIN=128). split = z&3.
// =====================================================================
__global__ __launch_bounds__(256) void k_convp(
    const float* __restrict__ in, const float* __restrict__ wT,
    float* __restrict__ pout, int COUT)
{
  const int H = 30, W = 40;
  constexpr int SR = 8, SC = 42, LC = 44;
  constexpr int TOTAL = 4 * SR * SC;   // 1344
  __shared__ float ain[4][SR][LC];

  int y0 = blockIdx.x * 6;             // 0..4
  int cob = blockIdx.y * 16;
  int z = blockIdx.z;
  int n = z >> 2, split = z & 3;

  int tid = threadIdx.x;
  int r = tid / 40, c = tid - r * 40;
  bool live = tid < 240;
  int rE = live ? r : 0;

  size_t imgBase = (size_t)n * 128 * 1200;

  float acc[16];
#pragma unroll
  for (int j = 0; j < 16; j++) acc[j] = 0.f;

  int cc0 = split * 8;
  for (int cc = cc0; cc < cc0 + 8; ++cc) {
    __syncthreads();
    for (int m = tid; m < TOTAL; m += 256) {
      int ci = m / (SR * SC);
      int rem = m - ci * (SR * SC);
      int rr = rem / SC;
      int col = rem - rr * SC;
      int gy = y0 - 1 + rr, gx = col - 1;
      float v = 0.f;
      if (gy >= 0 && gy < H && gx >= 0 && gx < W)
        v = in[imgBase + ((size_t)(cc * 4 + ci) * H + gy) * W + gx];
      ain[ci][rr][col] = v;
    }
    __syncthreads();
#pragma unroll
    for (int ci = 0; ci < 4; ++ci) {
      float win[3][3];
#pragma unroll
      for (int dy = 0; dy < 3; dy++) {
        win[dy][0] = ain[ci][rE + dy][c];
        win[dy][1] = ain[ci][rE + dy][c + 1];
        win[dy][2] = ain[ci][rE + dy][c + 2];
      }
      const float* wp = wT + (size_t)((cc * 4 + ci) * 9) * COUT + cob;
#pragma unroll
      for (int tap = 0; tap < 9; tap++) {
        float4 q0 = *(const float4*)(wp + tap * COUT);
        float4 q1 = *(const float4*)(wp + tap * COUT + 4);
        float4 q2 = *(const float4*)(wp + tap * COUT + 8);
        float4 q3 = *(const float4*)(wp + tap * COUT + 12);
        float av = win[tap / 3][tap % 3];
        FMA16(acc, av);
      }
    }
  }

  int y = y0 + r;
  if (live && y < H) {
    float* po = pout + (size_t)split * (8 * (size_t)COUT * 1200)
              + ((size_t)n * COUT + cob) * 1200 + y * 40 + c;
#pragma unroll
    for (int j = 0; j < 16; j++)
      po[(size_t)j * 1200] = acc[j];
  }
}

// sum 4 partial slabs + bias + relu (float4)
__global__ __launch_bounds__(256) void k_fuse(
    const float* __restrict__ pin, const float* __restrict__ bias,
    float* __restrict__ out, int COUT)
{
  int idx = blockIdx.x * 256 + threadIdx.x;       // float4 index
  int total4 = 2 * COUT * 1200;                   // (8*COUT*1200)/4
  if (idx >= total4) return;
  int co = ((idx * 4) / 1200) % COUT;
  size_t slab4 = (size_t)2 * COUT * 1200;
  const float4* p4 = (const float4*)pin;
  float4 a = p4[idx], b2 = p4[idx + slab4], c2 = p4[idx + 2 * slab4], d = p4[idx + 3 * slab4];
  float bb = bias[co];
  float4 o;
  o.x = fmaxf(a.x + b2.x + c2.x + d.x + bb, 0.f);
  o.y = fmaxf(a.y + b2.y + c2.y + d.y + bb, 0.f);
  o.z = fmaxf(a.z + b2.z + c2.z + d.z + bb, 0.f);
  o.w = fmaxf(a.w + b2.w + c2.w + d.w + bb, 0.f);
  ((float4*)out)[idx] = o;
}

// =====================================================================
// Fused conv0(1->64)+relu -> conv1(64->64)+relu -> 2x2 maxpool.
// 32x8 tile, 1 row x 32 co (584us = 98% of the scalar-FMA issue floor).
// =====================================================================
__global__ __launch_bounds__(256) void k_f01(
    const float* __restrict__ x, const float* __restrict__ w0g, const float* __restrict__ b0g,
    const float* __restrict__ wT1, const float* __restrict__ b1g, float* __restrict__ out)
{
  const int H = 240, W = 320;
  __shared__ float in_raw[12][36];
  __shared__ float a0[4][10][36];
  __shared__ float w0l[576];
  __shared__ float b0l[64];

  int tile = blockIdx.x;              // tilesX=10, tilesY=30
  int tx = tile % 10, ty = tile / 10;
  int x0 = tx * 32, y0 = ty * 8;
  int cob = blockIdx.y * 32;          // 0..1
  int n = blockIdx.z;

  int tid = threadIdx.x;
  int r = tid >> 5;
  int c = tid & 31;

  bool fullT = (y0 >= 1) && (y0 + 9 <= H) && (x0 >= 1) && (x0 + 33 <= W);

  for (int k = tid; k < 576; k += 256) w0l[k] = w0g[k];
  if (tid < 64) b0l[tid] = b0g[tid];
  for (int m = tid; m < 432; m += 256) {
    int rr = m / 36, col = m - rr * 36;
    int gy = y0 - 2 + rr, gx = x0 - 2 + col;
    in_raw[rr][col] = (gy >= 0 && gy < H && gx >= 0 && gx < W)
                          ? x[(size_t)n * (H * W) + gy * W + gx] : 0.f;
  }

  float acc[32];
#pragma unroll
  for (int j = 0; j < 32; j++) acc[j] = 0.f;

  for (int cc = 0; cc < 16; ++cc) {
    __syncthreads();                  // in_raw/w0l ready; a0 free
    if (fullT) {
      for (int m = tid; m < 1360; m += 256) {
        int ch = m / 340;
        int rem = m - ch * 340;
        int rr = rem / 34;
        int col = rem - rr * 34;
        const float* wp = &w0l[(cc * 4 + ch) * 9];
        float s = b0l[cc * 4 + ch];
#pragma unroll
        for (int dy = 0; dy < 3; dy++)
#pragma unroll
          for (int dx = 0; dx < 3; dx++)
            s = fmaf(in_raw[rr + dy][col + dx], wp[dy * 3 + dx], s);
        a0[ch][rr][col] = fmaxf(s, 0.f);
      }
    } else {
      for (int m = tid; m < 1360; m += 256) {
        int ch = m / 340;
        int rem = m - ch * 340;
        int rr = rem / 34;
        int col = rem - rr * 34;
        int gy = y0 - 1 + rr, gx = x0 - 1 + col;
        float v = 0.f;
        if (gy >= 0 && gy < H && gx >= 0 && gx < W) {
          const float* wp = &w0l[(cc * 4 + ch) * 9];
          float s = b0l[cc * 4 + ch];
#pragma unroll
          for (int dy = 0; dy < 3; dy++)
#pragma unroll
            for (int dx = 0; dx < 3; dx++)
              s = fmaf(in_raw[rr + dy][col + dx], wp[dy * 3 + dx], s);
          v = fmaxf(s, 0.f);
        }
        a0[ch][rr][col] = v;
      }
    }
    __syncthreads();
#pragma unroll
    for (int ci = 0; ci < 4; ++ci) {
      float win[3][3];
#pragma unroll
      for (int dy = 0; dy < 3; dy++) {
        win[dy][0] = a0[ci][r + dy][c];
        win[dy][1] = a0[ci][r + dy][c + 1];
        win[dy][2] = a0[ci][r + dy][c + 2];
      }
      const float* wp = wT1 + (size_t)((cc * 4 + ci) * 9) * 64 + cob;
#pragma unroll
      for (int tap = 0; tap < 9; tap++) {
        float4 q0 = *(const float4*)(wp + tap * 64);
        float4 q1 = *(const float4*)(wp + tap * 64 + 4);
        float4 q2 = *(const float4*)(wp + tap * 64 + 8);
        float4 q3 = *(const float4*)(wp + tap * 64 + 12);
        float4 q4 = *(const float4*)(wp + tap * 64 + 16);
        float4 q5 = *(const float4*)(wp + tap * 64 + 20);
        float4 q6 = *(const float4*)(wp + tap * 64 + 24);
        float4 q7 = *(const float4*)(wp + tap * 64 + 28);
        float av = win[tap / 3][tap % 3];
        FMA32(acc, av);
      }
    }
  }

  float bvv[32];
  {
    const float4* bp = (const float4*)(b1g + cob);
#pragma unroll
    for (int g = 0; g < 8; g++) *(float4*)&bvv[4 * g] = bp[g];
  }
  int Hp = 120, Wp = 160;
  int py = (y0 + r) >> 1, pxp = (x0 + c) >> 1;
  bool ok = ((r & 1) == 0) && ((c & 1) == 0);
#pragma unroll
  for (int j = 0; j < 32; j++) {
    float h = fmaxf(acc[j] + bvv[j], 0.f);
    float hv = fmaxf(h, __shfl_xor(h, 32, 64));
    float hh = fmaxf(hv, __shfl_xor(hv, 1, 64));
    if (ok)
      out[(((size_t)n * 64 + cob + j) * Hp + py) * Wp + pxp] = hh;
  }
}

// =====================================================================
// Head: conv9 (1x1, 256->65) + bias + softmax(65) + dustbin drop + shuffle.
// 2-lane teams. Also zeroes the prob_nms/pred output region.
// =====================================================================
__global__ __launch_bounds__(256) void k_head(
    const float* __restrict__ act, const float* __restrict__ w9, const float* __restrict__ b9,
    float* __restrict__ prob, float* __restrict__ zbase)
{
  __shared__ float wl[256 * 68];
  int n = blockIdx.y;
  int tid = threadIdx.x;

  // zero onms+opred (2*614400 floats) across all 80 blocks
  {
    float4* z = (float4*)zbase;
    int gid = (blockIdx.y * gridDim.x + blockIdx.x) * 256 + tid;
    for (int k = gid; k < 307200; k += 20480)
      z[k] = make_float4(0.f, 0.f, 0.f, 0.f);
  }

  for (int k = tid; k < 65 * 256; k += 256) {
    int co = k / 256, ci = k % 256;
    wl[ci * 68 + co] = w9[k];
  }
  for (int ci = tid; ci < 256; ci += 256) {
    wl[ci * 68 + 65] = 0.f; wl[ci * 68 + 66] = 0.f; wl[ci * 68 + 67] = 0.f;
  }
  __syncthreads();
  int px = blockIdx.x * 128 + (tid >> 1);
  int half = tid & 1;
  bool live = (px < 1200);
  int cbase = half * 34;
  int nreal = half ? 31 : 34;    // real co count (incl. dustbin 64 on odd)

  float accv[34];
#pragma unroll
  for (int i = 0; i < 34; i++) accv[i] = 0.f;

  if (live) {
    for (int ci = 0; ci < 256; ++ci) {
      float a = act[((size_t)n * 256 + ci) * 1200 + px];
      const float2* wp = (const float2*)&wl[ci * 68 + cbase];
#pragma unroll
      for (int g = 0; g < 17; g++) {
        float2 wv = wp[g];
        accv[g * 2 + 0] = fmaf(a, wv.x, accv[g * 2 + 0]);
        accv[g * 2 + 1] = fmaf(a, wv.y, accv[g * 2 + 1]);
      }
    }
  }
  for (int i = 0; i < 34; i++)
    if (i < nreal) accv[i] += b9[cbase + i];
  float m = -1e30f;
  for (int i = 0; i < 34; i++)
    if (i < nreal) m = fmaxf(m, accv[i]);
  m = fmaxf(m, __shfl_xor(m, 1, 64));
  float s = 0.f;
  for (int i = 0; i < 34; i++)
    if (i < nreal) { accv[i] = __expf(accv[i] - m); s += accv[i]; }
  s += __shfl_xor(s, 1, 64);
  float inv = 1.f / s;

  if (live) {
    int hc = px / 40, wc = px % 40;
    float* pb = prob + (size_t)n * 76800;
    int nw = half ? 30 : 34;     // write only co < 64
    for (int i = 0; i < nw; i++) {
      int co = cbase + i;
      pb[(hc * 8 + (co >> 3)) * 320 + wc * 8 + (co & 7)] = accv[i] * inv;
    }
  }
}

// =====================================================================
// Exact reference NMS per image (16 per-wave radix histograms; float4
// global reads -- with only 8 resident blocks the scalar 75-load loops
// were latency-exposed).
// =====================================================================
#define MAXC 1024
__global__ __launch_bounds__(1024) void k_nms(
    const float* __restrict__ prob, float* __restrict__ onms, float* __restrict__ opred)
{
  __shared__ unsigned sup[MAXC * 32];
  __shared__ unsigned long long skey[MAXC];
  __shared__ unsigned syx[MAXC];
  __shared__ unsigned hist[256];
  __shared__ unsigned vword[32];
  __shared__ unsigned sh_prefix, sh_K, sh_cG, sh_pG, sh_pE;

  int n = blockIdx.x;
  int tid = threadIdx.x;
  const float* p = prob + (size_t)n * 76800;
  const float4* p4 = (const float4*)p;
  float* on = onms + (size_t)n * 76800;
  float* op = opred + (size_t)n * 76800;

  if (tid == 0) { sh_prefix = 0u; sh_K = MAXC; sh_cG = 0u; sh_pG = 0u; sh_pE = 0u; }

  unsigned* h16 = sup;   // 16 waves x 256 bins (sup unused until later)
  int wv = tid >> 6;
  for (int round = 0; round < 4; ++round) {
    for (int k = tid; k < 4096; k += 1024) h16[k] = 0u;
    __syncthreads();
    unsigned prefix = sh_prefix;
    int shift = 24 - 8 * round;
    unsigned maskHi = (round == 0) ? 0u : (0xFFFFFFFFu << (shift + 8));
    for (int k = tid; k < 19200; k += 1024) {
      float4 v4 = p4[k];
      const float* vp = (const float*)&v4;
#pragma unroll
      for (int e = 0; e < 4; e++) {
        unsigned b = __float_as_uint(vp[e]);
        if ((b & maskHi) == prefix) atomicAdd(&h16[wv * 256 + ((b >> shift) & 255)], 1u);
      }
    }
    __syncthreads();
    if (tid < 256) {
      unsigned s = 0u;
#pragma unroll
      for (int w = 0; w < 16; w++) s += h16[w * 256 + tid];
      hist[tid] = s;
    }
    __syncthreads();
    if (tid == 0) {
      unsigned K = sh_K, cum = 0u;
      int bin = 255;
      for (; bin >= 0; --bin) {
        unsigned cgt = hist[bin];
        if (cum + cgt >= K) break;
        cum += cgt;
      }
      sh_prefix = prefix | ((unsigned)bin << shift);
      sh_K = K - cum;
      sh_cG += cum;
    }
    __syncthreads();
  }
  unsigned T = sh_prefix;
  unsigned Kfill = sh_K;
  unsigned Cgt = sh_cG;

  unsigned* eq = sup;
  __syncthreads();
  for (int k = tid; k < 19200; k += 1024) {
    float4 v4 = p4[k];
    const float* vp = (const float*)&v4;
#pragma unroll
    for (int e = 0; e < 4; e++) {
      unsigned b = __float_as_uint(vp[e]);
      if (b > T) {
        unsigned pos = atomicAdd(&sh_pG, 1u);
        skey[pos] = ((unsigned long long)b << 32) | (unsigned)(~(unsigned)(4 * k + e));
      } else if (b == T) {
        unsigned pos = atomicAdd(&sh_pE, 1u);
        if (pos < 2048u) eq[pos] = (unsigned)(4 * k + e);
      }
    }
  }
  __syncthreads();
  unsigned cE = sh_pE;
  for (int k = tid; k < 2048; k += 1024)
    if ((unsigned)k >= cE) eq[k] = 0xFFFFFFFFu;
  __syncthreads();
  for (int k = 2; k <= 2048; k <<= 1) {
    for (int j = k >> 1; j > 0; j >>= 1) {
      int t = tid;
      int i = ((t & ~(j - 1)) << 1) | (t & (j - 1));
      int l = i | j;
      bool up = ((i & k) == 0);
      unsigned a = eq[i], b2 = eq[l];
      if (up ? (a > b2) : (a < b2)) { eq[i] = b2; eq[l] = a; }
      __syncthreads();
    }
  }
  for (int m2 = tid; m2 < (int)Kfill; m2 += 1024)
    skey[Cgt + m2] = ((unsigned long long)T << 32) | (unsigned)(~eq[m2]);
  __syncthreads();

  for (int k = 2; k <= MAXC; k <<= 1) {
    for (int j = k >> 1; j > 0; j >>= 1) {
      int i = tid;
      int l = i ^ j;
      if (l > i) {
        unsigned long long a = skey[i], b2 = skey[l];
        bool up = ((i & k) == 0);
        if (up ? (a < b2) : (a > b2)) { skey[i] = b2; skey[l] = a; }
      }
      __syncthreads();
    }
  }

  if (tid < 32) vword[tid] = 0u;
  __syncthreads();
  {
    unsigned long long key = skey[tid];
    unsigned vb = (unsigned)(key >> 32);
    float val = __uint_as_float(vb);
    unsigned id = ~(unsigned)key;
    unsigned y = id / 320u, xx = id - 320u * y;
    syx[tid] = (y << 16) | xx;
    if (val > DET_THRESH) atomicOr(&vword[tid >> 5], 1u << (tid & 31));
  }
  __syncthreads();

  {
    unsigned myyx = syx[tid];
    int ty = (int)(myyx >> 16), tx = (int)(myyx & 0xFFFFu);
    for (int w = 0; w < 32; ++w) {
      unsigned bits = 0u;
#pragma unroll 8
      for (int b2 = 0; b2 < 32; ++b2) {
        int j = w * 32 + b2;
        if (j > tid) {
          unsigned o = syx[j];
          int dy = ty - (int)(o >> 16); dy = dy < 0 ? -dy : dy;
          int dx = tx - (int)(o & 0xFFFFu); dx = dx < 0 ? -dx : dx;
          if (((dy | dx) < 4) && (dy + dx) <= 4) bits |= 1u << b2;
        }
      }
      sup[tid * 32 + w] = bits;
    }
  }
  __syncthreads();

  if (tid < 64) {
    int lw = tid;
    unsigned keepw = (lw < 32) ? vword[lw] : 0u;
    for (int i = 0; i < MAXC; ++i) {
      unsigned kword = __shfl(keepw, i >> 5, 64);
      if ((kword >> (i & 31)) & 1u) {
        if (lw < 32) keepw &= ~sup[i * 32 + lw];
      }
    }
    unsigned pc = (lw < 32) ? (unsigned)__builtin_popcount(keepw) : 0u;
    unsigned incl = pc;
    for (int d = 1; d < 32; d <<= 1) {
      unsigned t2 = __shfl_up(incl, d, 64);
      if (lw >= d) incl += t2;
    }
    unsigned excl = incl - pc;
    if (lw < 32) {
      int quota = 300 - (int)excl;
      if (quota <= 0) keepw = 0u;
      else if ((int)pc > quota) {
        while (__builtin_popcount(keepw) > quota)
          keepw &= ~(1u << (31 - __builtin_clz(keepw)));
      }
      unsigned kw = keepw;
      while (kw) {
        int b2 = __builtin_ffs((int)kw) - 1;
        kw &= kw - 1u;
        int i = lw * 32 + b2;
        unsigned long long key = skey[i];
        float v = __uint_as_float((unsigned)(key >> 32));
        unsigned id = ~(unsigned)key;
        on[id] = v;
        op[id] = v;
      }
    }
  }
}

// =====================================================================
extern "C" void kernel_launch(void* const* d_in, const int* in_sizes, int n_in,
                              void* d_out, int out_size, void* d_ws, size_t ws_size,
                              hipStream_t stream) {
  const float* x = (const float*)d_in[0];
  const float* w[10];
  const float* b[10];
  for (int i = 0; i < 10; ++i) {
    w[i] = (const float*)d_in[1 + 2 * i];
    b[i] = (const float*)d_in[2 + 2 * i];
  }
  float* A = (float*)d_ws;
  float* B = A + 9830400;        // 64*120*160*8
  float* prob  = (float*)d_out;
  float* onms  = prob + 614400;  // 8*240*320
  float* opred = onms + 614400;

  // Transposed weights live in the onms/opred region (dead until k_head
  // zeroes it; k_nms then scatters). Total 921600 floats <= 1228800.
  float* wT1 = onms;
  float* wT2 = wT1 + 36864;
  float* wT3 = wT2 + 36864;
  float* wT4 = wT3 + 36864;
  float* wT5 = wT4 + 73728;
  float* wT6 = wT5 + 147456;
  float* wT7 = wT6 + 147456;
  float* wT8 = wT7 + 147456;

  TP tp;
  tp.src[0] = w[1]; tp.dst[0] = wT1; tp.cin[0] = 64;  tp.cout[0] = 64;
  tp.src[1] = w[2]; tp.dst[1] = wT2; tp.cin[1] = 64;  tp.cout[1] = 64;
  tp.src[2] = w[3]; tp.dst[2] = wT3; tp.cin[2] = 64;  tp.cout[2] = 64;
  tp.src[3] = w[4]; tp.dst[3] = wT4; tp.cin[3] = 64;  tp.cout[3] = 128;
  tp.src[4] = w[5]; tp.dst[4] = wT5; tp.cin[4] = 128; tp.cout[4] = 128;
  tp.src[5] = w[6]; tp.dst[5] = wT6; tp.cin[5] = 128; tp.cout[5] = 128;
  tp.src[6] = w[7]; tp.dst[6] = wT7; tp.cin[6] = 128; tp.cout[6] = 128;
  tp.src[7] = w[8]; tp.dst[7] = wT8; tp.cin[7] = 128; tp.cout[7] = 256;
  k_wT<<<dim3(1152, 8), 256, 0, stream>>>(tp);

  // conv0+conv1+pool -> A (8,64,120,160). 32x8 tiles 10x30, 2 co-blocks (32co).
  k_f01<<<dim3(300, 2, 8), 256, 0, stream>>>(x, w[0], b[0], wT1, b[1], A);
  // conv2 -> B (8,64,120,160)
  kc2<<<dim3(75, 4, 8), 256, 0, stream>>>(A, wT2, b[2], B, 64, 64, 120, 160, 5);
  // conv3+pool -> A (8,64,60,80)
  kc3<<<dim3(75, 4, 8), 256, 0, stream>>>(B, wT3, b[3], A, 64, 64, 120, 160, 5);
  // conv4 -> B (8,128,60,80)
  kc4<<<dim3(20, 8, 8), 256, 0, stream>>>(A, wT4, b[4], B, 64, 128, 60, 80, 2);
  // conv5+pool -> A (8,128,30,40)
  kc5<<<dim3(24, 8, 8), 256, 0, stream>>>(B, wT5, b[5], A, 128, 128, 60, 80, 3);

  // 30x40 layers: ci-split x4.
  float* C6 = B + 4915200;  // conv6 output (1.2M floats)
  float* C7 = A + 4915200;  // conv7 output
  k_convp<<<dim3(5, 8, 32), 256, 0, stream>>>(A, wT6, B, 128);
  k_fuse<<<1200, 256, 0, stream>>>(B, b[6], C6, 128);
  k_convp<<<dim3(5, 8, 32), 256, 0, stream>>>(C6, wT7, A, 128);
  k_fuse<<<1200, 256, 0, stream>>>(A, b[7], C7, 128);
  k_convp<<<dim3(5, 16, 32), 256, 0, stream>>>(C7, wT8, B, 256);
  k_fuse<<<2400, 256, 0, stream>>>(B, b[8], A, 256);

  // convPb + softmax + shuffle -> prob; also zeroes onms/opred.
  k_head<<<dim3(10, 8), 256, 0, stream>>>(A, w[9], b[9], prob, onms);
  // NMS + top-300 -> prob_nms, pred
  k_nms<<<dim3(8), 1024, 0, stream>>>(prob, onms, opred);
}

// Round 17
// 1787.156 us; speedup vs baseline: 1.7023x; 1.0269x over previous
//
#include <hip/hip_runtime.h>
#include <stdint.h>

#define DET_THRESH 0.015f

#define FMA16(ACC, AV) do { \
  ACC[0]  = fmaf(AV, q0.x, ACC[0]);  ACC[1]  = fmaf(AV, q0.y, ACC[1]);  \
  ACC[2]  = fmaf(AV, q0.z, ACC[2]);  ACC[3]  = fmaf(AV, q0.w, ACC[3]);  \
  ACC[4]  = fmaf(AV, q1.x, ACC[4]);  ACC[5]  = fmaf(AV, q1.y, ACC[5]);  \
  ACC[6]  = fmaf(AV, q1.z, ACC[6]);  ACC[7]  = fmaf(AV, q1.w, ACC[7]);  \
  ACC[8]  = fmaf(AV, q2.x, ACC[8]);  ACC[9]  = fmaf(AV, q2.y, ACC[9]);  \
  ACC[10] = fmaf(AV, q2.z, ACC[10]); ACC[11] = fmaf(AV, q2.w, ACC[11]); \
  ACC[12] = fmaf(AV, q3.x, ACC[12]); ACC[13] = fmaf(AV, q3.y, ACC[13]); \
  ACC[14] = fmaf(AV, q3.z, ACC[14]); ACC[15] = fmaf(AV, q3.w, ACC[15]); } while (0)

#define FMA32(ACC, AV) do { \
  FMA16(ACC, AV); \
  ACC[16] = fmaf(AV, q4.x, ACC[16]); ACC[17] = fmaf(AV, q4.y, ACC[17]); \
  ACC[18] = fmaf(AV, q4.z, ACC[18]); ACC[19] = fmaf(AV, q4.w, ACC[19]); \
  ACC[20] = fmaf(AV, q5.x, ACC[20]); ACC[21] = fmaf(AV, q5.y, ACC[21]); \
  ACC[22] = fmaf(AV, q5.z, ACC[22]); ACC[23] = fmaf(AV, q5.w, ACC[23]); \
  ACC[24] = fmaf(AV, q6.x, ACC[24]); ACC[25] = fmaf(AV, q6.y, ACC[25]); \
  ACC[26] = fmaf(AV, q6.z, ACC[26]); ACC[27] = fmaf(AV, q6.w, ACC[27]); \
  ACC[28] = fmaf(AV, q7.x, ACC[28]); ACC[29] = fmaf(AV, q7.y, ACC[29]); \
  ACC[30] = fmaf(AV, q7.z, ACC[30]); ACC[31] = fmaf(AV, q7.w, ACC[31]); } while (0)

// =====================================================================
// Weight pre-transpose: w[co][ci][tap] -> wT[ci*9+tap][co]  (per layer)
// =====================================================================
struct TP {
  const float* src[8];
  float* dst[8];
  int cin[8];
  int cout[8];
};

__global__ __launch_bounds__(256) void k_wT(TP tp) {
  int l = blockIdx.y;
  int n = tp.cin[l] * tp.cout[l] * 9;
  int k = blockIdx.x * 256 + threadIdx.x;
  if (k >= n) return;
  int ci9 = tp.cin[l] * 9;
  int co = k / ci9;
  int r = k - co * ci9;             // r = ci*9 + tap
  tp.dst[l][(size_t)r * tp.cout[l] + co] = tp.src[l][k];
}

// =====================================================================
// Generic 3x3 conv body, 16 co/thread (r10 geometry). kc2..kc5 wrappers.
// =====================================================================
template <int TW, int TH, bool POOL>
__device__ __forceinline__ void conv_body(
    const float* __restrict__ in, const float* __restrict__ wT, const float* __restrict__ bias,
    float* __restrict__ out, int CIN, int COUT, int H, int W, int tilesX)
{
  constexpr int SR = TH + 2;
  constexpr int SC = TW + 2;
  constexpr int LC = TW + 4;
  constexpr int TOTAL = 4 * SR * SC;
  __shared__ float ain[4][SR][LC];

  int tile = blockIdx.x;
  int tx = tile % tilesX, ty = tile / tilesX;
  int x0 = tx * TW, y0 = ty * TH;
  int cob = blockIdx.y * 16;
  int n = blockIdx.z;

  int tid = threadIdx.x;
  int r, c;
  if (TW == 32) { r = tid >> 5; c = tid & 31; }
  else          { r = tid / TW; c = tid - r * TW; }
  bool live = (TW * TH >= 256) || (tid < TW * TH);
  int rE = live ? r : 0;

  bool full = (y0 >= 1) && (y0 + TH + 1 <= H) && (x0 >= 1) && (x0 + TW + 1 <= W);
  size_t imgBase = (size_t)n * CIN * H * W;

  float acc[16];
#pragma unroll
  for (int j = 0; j < 16; j++) acc[j] = 0.f;

  int nch = CIN >> 2;
  for (int cc = 0; cc < nch; ++cc) {
    __syncthreads();
    if (full) {
      const float* src = in + imgBase + (size_t)(cc * 4) * H * W + (y0 - 1) * W + (x0 - 1);
      for (int m = tid; m < TOTAL; m += 256) {
        int ci = m / (SR * SC);
        int rem = m - ci * (SR * SC);
        int rr = rem / SC;
        int col = rem - rr * SC;
        ain[ci][rr][col] = src[(size_t)ci * H * W + rr * W + col];
      }
    } else {
      for (int m = tid; m < TOTAL; m += 256) {
        int ci = m / (SR * SC);
        int rem = m - ci * (SR * SC);
        int rr = rem / SC;
        int col = rem - rr * SC;
        int gy = y0 - 1 + rr, gx = x0 - 1 + col;
        float v = 0.f;
        if (gy >= 0 && gy < H && gx >= 0 && gx < W)
          v = in[imgBase + ((size_t)(cc * 4 + ci) * H + gy) * W + gx];
        ain[ci][rr][col] = v;
      }
    }
    __syncthreads();
#pragma unroll
    for (int ci = 0; ci < 4; ++ci) {
      float win[3][3];
#pragma unroll
      for (int dy = 0; dy < 3; dy++) {
        win[dy][0] = ain[ci][rE + dy][c];
        win[dy][1] = ain[ci][rE + dy][c + 1];
        win[dy][2] = ain[ci][rE + dy][c + 2];
      }
      const float* wp = wT + (size_t)((cc * 4 + ci) * 9) * COUT + cob;
#pragma unroll
      for (int tap = 0; tap < 9; tap++) {
        float4 q0 = *(const float4*)(wp + tap * COUT);
        float4 q1 = *(const float4*)(wp + tap * COUT + 4);
        float4 q2 = *(const float4*)(wp + tap * COUT + 8);
        float4 q3 = *(const float4*)(wp + tap * COUT + 12);
        float av = win[tap / 3][tap % 3];
        FMA16(acc, av);
      }
    }
  }

  float bvv[16];
  {
    const float4* bp = (const float4*)(bias + cob);
    *(float4*)&bvv[0] = bp[0]; *(float4*)&bvv[4] = bp[1];
    *(float4*)&bvv[8] = bp[2]; *(float4*)&bvv[12] = bp[3];
  }
  int x = x0 + c;
  int y = y0 + r;
  if (!POOL) {
    if (live && y < H && x < W) {
#pragma unroll
      for (int j = 0; j < 16; j++)
        out[(((size_t)n * COUT + cob + j) * H + y) * W + x] = fmaxf(acc[j] + bvv[j], 0.f);
    }
  } else {
    // TW==32 only
    int Hp = H >> 1, Wp = W >> 1;
    int py = y >> 1, pxp = x >> 1;
    bool ok = ((r & 1) == 0) && ((c & 1) == 0) && (py < Hp) && (pxp < Wp);
#pragma unroll
    for (int j = 0; j < 16; j++) {
      float h = fmaxf(acc[j] + bvv[j], 0.f);
      float hc = fmaxf(h, __shfl_xor(h, 1, 64));    // col pair
      float hv = fmaxf(hc, __shfl_xor(hc, 32, 64)); // row pair
      if (ok)
        out[(((size_t)n * COUT + cob + j) * Hp + py) * Wp + pxp] = hv;
    }
  }
}

__global__ __launch_bounds__(256) void kc2(const float* in, const float* wT, const float* bias,
                                           float* out, int CIN, int COUT, int H, int W, int tX)
{ conv_body<32, 8, false>(in, wT, bias, out, CIN, COUT, H, W, tX); }
__global__ __launch_bounds__(256) void kc3(const float* in, const float* wT, const float* bias,
                                           float* out, int CIN, int COUT, int H, int W, int tX)
{ conv_body<32, 8, true>(in, wT, bias, out, CIN, COUT, H, W, tX); }
__global__ __launch_bounds__(256) void kc4(const float* in, const float* wT, const float* bias,
                                           float* out, int CIN, int COUT, int H, int W, int tX)
{ conv_body<40, 6, false>(in, wT, bias, out, CIN, COUT, H, W, tX); }
__global__ __launch_bounds__(256) void kc5(const float* in, const float* wT, const float* bias,
                                           float* out, int CIN, int COUT, int H, int W, int tX)
{ conv_body<32, 8, true>(in, wT, bias, out, CIN, COUT, H, W, tX); }

// =====================================================================
// ci-split partial conv for the 30x40 layers (CIN=128). split = z&3.
// =====================================================================
__global__ __launch_bounds__(256) void k_convp(
    const float* __restrict__ in, const float* __restrict__ wT,
    float* __restrict__ pout, int COUT)
{
  const int H = 30, W = 40;
  constexpr int SR = 8, SC = 42, LC = 44;
  constexpr int TOTAL = 4 * SR * SC;   // 1344
  __shared__ float ain[4][SR][LC];

  int y0 = blockIdx.x * 6;             // 0..4
  int cob = blockIdx.y * 16;
  int z = blockIdx.z;
  int n = z >> 2, split = z & 3;

  int tid = threadIdx.x;
  int r = tid / 40, c = tid - r * 40;
  bool live = tid < 240;
  int rE = live ? r : 0;

  size_t imgBase = (size_t)n * 128 * 1200;

  float acc[16];
#pragma unroll
  for (int j = 0; j < 16; j++) acc[j] = 0.f;

  int cc0 = split * 8;
  for (int cc = cc0; cc < cc0 + 8; ++cc) {
    __syncthreads();
    for (int m = tid; m < TOTAL; m += 256) {
      int ci = m / (SR * SC);
      int rem = m - ci * (SR * SC);
      int rr = rem / SC;
      int col = rem - rr * SC;
      int gy = y0 - 1 + rr, gx = col - 1;
      float v = 0.f;
      if (gy >= 0 && gy < H && gx >= 0 && gx < W)
        v = in[imgBase + ((size_t)(cc * 4 + ci) * H + gy) * W + gx];
      ain[ci][rr][col] = v;
    }
    __syncthreads();
#pragma unroll
    for (int ci = 0; ci < 4; ++ci) {
      float win[3][3];
#pragma unroll
      for (int dy = 0; dy < 3; dy++) {
        win[dy][0] = ain[ci][rE + dy][c];
        win[dy][1] = ain[ci][rE + dy][c + 1];
        win[dy][2] = ain[ci][rE + dy][c + 2];
      }
      const float* wp = wT + (size_t)((cc * 4 + ci) * 9) * COUT + cob;
#pragma unroll
      for (int tap = 0; tap < 9; tap++) {
        float4 q0 = *(const float4*)(wp + tap * COUT);
        float4 q1 = *(const float4*)(wp + tap * COUT + 4);
        float4 q2 = *(const float4*)(wp + tap * COUT + 8);
        float4 q3 = *(const float4*)(wp + tap * COUT + 12);
        float av = win[tap / 3][tap % 3];
        FMA16(acc, av);
      }
    }
  }

  int y = y0 + r;
  if (live && y < H) {
    float* po = pout + (size_t)split * (8 * (size_t)COUT * 1200)
              + ((size_t)n * COUT + cob) * 1200 + y * 40 + c;
#pragma unroll
    for (int j = 0; j < 16; j++)
      po[(size_t)j * 1200] = acc[j];
  }
}

// sum 4 partial slabs + bias + relu (float4)
__global__ __launch_bounds__(256) void k_fuse(
    const float* __restrict__ pin, const float* __restrict__ bias,
    float* __restrict__ out, int COUT)
{
  int idx = blockIdx.x * 256 + threadIdx.x;       // float4 index
  int total4 = 2 * COUT * 1200;                   // (8*COUT*1200)/4
  if (idx >= total4) return;
  int co = ((idx * 4) / 1200) % COUT;
  size_t slab4 = (size_t)2 * COUT * 1200;
  const float4* p4 = (const float4*)pin;
  float4 a = p4[idx], b2 = p4[idx + slab4], c2 = p4[idx + 2 * slab4], d = p4[idx + 3 * slab4];
  float bb = bias[co];
  float4 o;
  o.x = fmaxf(a.x + b2.x + c2.x + d.x + bb, 0.f);
  o.y = fmaxf(a.y + b2.y + c2.y + d.y + bb, 0.f);
  o.z = fmaxf(a.z + b2.z + c2.z + d.z + bb, 0.f);
  o.w = fmaxf(a.w + b2.w + c2.w + d.w + bb, 0.f);
  ((float4*)out)[idx] = o;
}

// =====================================================================
// Fused conv0(1->64)+relu -> conv1(64->64)+relu -> 2x2 maxpool.
// 32x8 tile, 1 row x 32 co (584us = 98% of the scalar-FMA issue floor).
// =====================================================================
__global__ __launch_bounds__(256) void k_f01(
    const float* __restrict__ x, const float* __restrict__ w0g, const float* __restrict__ b0g,
    const float* __restrict__ wT1, const float* __restrict__ b1g, float* __restrict__ out)
{
  const int H = 240, W = 320;
  __shared__ float in_raw[12][36];
  __shared__ float a0[4][10][36];
  __shared__ float w0l[576];
  __shared__ float b0l[64];

  int tile = blockIdx.x;              // tilesX=10, tilesY=30
  int tx = tile % 10, ty = tile / 10;
  int x0 = tx * 32, y0 = ty * 8;
  int cob = blockIdx.y * 32;          // 0..1
  int n = blockIdx.z;

  int tid = threadIdx.x;
  int r = tid >> 5;
  int c = tid & 31;

  bool fullT = (y0 >= 1) && (y0 + 9 <= H) && (x0 >= 1) && (x0 + 33 <= W);

  for (int k = tid; k < 576; k += 256) w0l[k] = w0g[k];
  if (tid < 64) b0l[tid] = b0g[tid];
  for (int m = tid; m < 432; m += 256) {
    int rr = m / 36, col = m - rr * 36;
    int gy = y0 - 2 + rr, gx = x0 - 2 + col;
    in_raw[rr][col] = (gy >= 0 && gy < H && gx >= 0 && gx < W)
                          ? x[(size_t)n * (H * W) + gy * W + gx] : 0.f;
  }

  float acc[32];
#pragma unroll
  for (int j = 0; j < 32; j++) acc[j] = 0.f;

  for (int cc = 0; cc < 16; ++cc) {
    __syncthreads();                  // in_raw/w0l ready; a0 free
    if (fullT) {
      for (int m = tid; m < 1360; m += 256) {
        int ch = m / 340;
        int rem = m - ch * 340;
        int rr = rem / 34;
        int col = rem - rr * 34;
        const float* wp = &w0l[(cc * 4 + ch) * 9];
        float s = b0l[cc * 4 + ch];
#pragma unroll
        for (int dy = 0; dy < 3; dy++)
#pragma unroll
          for (int dx = 0; dx < 3; dx++)
            s = fmaf(in_raw[rr + dy][col + dx], wp[dy * 3 + dx], s);
        a0[ch][rr][col] = fmaxf(s, 0.f);
      }
    } else {
      for (int m = tid; m < 1360; m += 256) {
        int ch = m / 340;
        int rem = m - ch * 340;
        int rr = rem / 34;
        int col = rem - rr * 34;
        int gy = y0 - 1 + rr, gx = x0 - 1 + col;
        float v = 0.f;
        if (gy >= 0 && gy < H && gx >= 0 && gx < W) {
          const float* wp = &w0l[(cc * 4 + ch) * 9];
          float s = b0l[cc * 4 + ch];
#pragma unroll
          for (int dy = 0; dy < 3; dy++)
#pragma unroll
            for (int dx = 0; dx < 3; dx++)
              s = fmaf(in_raw[rr + dy][col + dx], wp[dy * 3 + dx], s);
          v = fmaxf(s, 0.f);
        }
        a0[ch][rr][col] = v;
      }
    }
    __syncthreads();
#pragma unroll
    for (int ci = 0; ci < 4; ++ci) {
      float win[3][3];
#pragma unroll
      for (int dy = 0; dy < 3; dy++) {
        win[dy][0] = a0[ci][r + dy][c];
        win[dy][1] = a0[ci][r + dy][c + 1];
        win[dy][2] = a0[ci][r + dy][c + 2];
      }
      const float* wp = wT1 + (size_t)((cc * 4 + ci) * 9) * 64 + cob;
#pragma unroll
      for (int tap = 0; tap < 9; tap++) {
        float4 q0 = *(const float4*)(wp + tap * 64);
        float4 q1 = *(const float4*)(wp + tap * 64 + 4);
        float4 q2 = *(const float4*)(wp + tap * 64 + 8);
        float4 q3 = *(const float4*)(wp + tap * 64 + 12);
        float4 q4 = *(const float4*)(wp + tap * 64 + 16);
        float4 q5 = *(const float4*)(wp + tap * 64 + 20);
        float4 q6 = *(const float4*)(wp + tap * 64 + 24);
        float4 q7 = *(const float4*)(wp + tap * 64 + 28);
        float av = win[tap / 3][tap % 3];
        FMA32(acc, av);
      }
    }
  }

  float bvv[32];
  {
    const float4* bp = (const float4*)(b1g + cob);
#pragma unroll
    for (int g = 0; g < 8; g++) *(float4*)&bvv[4 * g] = bp[g];
  }
  int Hp = 120, Wp = 160;
  int py = (y0 + r) >> 1, pxp = (x0 + c) >> 1;
  bool ok = ((r & 1) == 0) && ((c & 1) == 0);
#pragma unroll
  for (int j = 0; j < 32; j++) {
    float h = fmaxf(acc[j] + bvv[j], 0.f);
    float hv = fmaxf(h, __shfl_xor(h, 32, 64));
    float hh = fmaxf(hv, __shfl_xor(hv, 1, 64));
    if (ok)
      out[(((size_t)n * 64 + cob + j) * Hp + py) * Wp + pxp] = hh;
  }
}

// =====================================================================
// Head: conv9 (1x1, 256->65) + bias + softmax(65) + dustbin drop + shuffle.
// 2-lane teams. Also zeroes the prob_nms/pred output region.
// =====================================================================
__global__ __launch_bounds__(256) void k_head(
    const float* __restrict__ act, const float* __restrict__ w9, const float* __restrict__ b9,
    float* __restrict__ prob, float* __restrict__ zbase)
{
  __shared__ float wl[256 * 68];
  int n = blockIdx.y;
  int tid = threadIdx.x;

  // zero onms+opred (2*614400 floats) across all 80 blocks
  {
    float4* z = (float4*)zbase;
    int gid = (blockIdx.y * gridDim.x + blockIdx.x) * 256 + tid;
    for (int k = gid; k < 307200; k += 20480)
      z[k] = make_float4(0.f, 0.f, 0.f, 0.f);
  }

  for (int k = tid; k < 65 * 256; k += 256) {
    int co = k / 256, ci = k % 256;
    wl[ci * 68 + co] = w9[k];
  }
  for (int ci = tid; ci < 256; ci += 256) {
    wl[ci * 68 + 65] = 0.f; wl[ci * 68 + 66] = 0.f; wl[ci * 68 + 67] = 0.f;
  }
  __syncthreads();
  int px = blockIdx.x * 128 + (tid >> 1);
  int half = tid & 1;
  bool live = (px < 1200);
  int cbase = half * 34;
  int nreal = half ? 31 : 34;    // real co count (incl. dustbin 64 on odd)

  float accv[34];
#pragma unroll
  for (int i = 0; i < 34; i++) accv[i] = 0.f;

  if (live) {
    for (int ci = 0; ci < 256; ++ci) {
      float a = act[((size_t)n * 256 + ci) * 1200 + px];
      const float2* wp = (const float2*)&wl[ci * 68 + cbase];
#pragma unroll
      for (int g = 0; g < 17; g++) {
        float2 wv = wp[g];
        accv[g * 2 + 0] = fmaf(a, wv.x, accv[g * 2 + 0]);
        accv[g * 2 + 1] = fmaf(a, wv.y, accv[g * 2 + 1]);
      }
    }
  }
  for (int i = 0; i < 34; i++)
    if (i < nreal) accv[i] += b9[cbase + i];
  float m = -1e30f;
  for (int i = 0; i < 34; i++)
    if (i < nreal) m = fmaxf(m, accv[i]);
  m = fmaxf(m, __shfl_xor(m, 1, 64));
  float s = 0.f;
  for (int i = 0; i < 34; i++)
    if (i < nreal) { accv[i] = __expf(accv[i] - m); s += accv[i]; }
  s += __shfl_xor(s, 1, 64);
  float inv = 1.f / s;

  if (live) {
    int hc = px / 40, wc = px % 40;
    float* pb = prob + (size_t)n * 76800;
    int nw = half ? 30 : 34;     // write only co < 64
    for (int i = 0; i < nw; i++) {
      int co = cbase + i;
      pb[(hc * 8 + (co >> 3)) * 320 + wc * 8 + (co & 7)] = accv[i] * inv;
    }
  }
}

// =====================================================================
// Exact reference NMS per image. r17: parallel suffix-scan bin select
// (was a 256-iter serial LDS chain x4 on tid 0 ~ 35us of 8-CU idle) and
// the eq-sort runs only when Kfill < cE (equal-T subset selection; the
// main skey sort re-orders equal values by index anyway).
// =====================================================================
#define MAXC 1024
__global__ __launch_bounds__(1024) void k_nms(
    const float* __restrict__ prob, float* __restrict__ onms, float* __restrict__ opred)
{
  __shared__ unsigned sup[MAXC * 32];
  __shared__ unsigned long long skey[MAXC];
  __shared__ unsigned syx[MAXC];
  __shared__ unsigned hist[256];
  __shared__ unsigned vword[32];
  __shared__ unsigned sh_prefix, sh_K, sh_cG, sh_pG, sh_pE;

  int n = blockIdx.x;
  int tid = threadIdx.x;
  const float* p = prob + (size_t)n * 76800;
  const float4* p4 = (const float4*)p;
  float* on = onms + (size_t)n * 76800;
  float* op = opred + (size_t)n * 76800;

  if (tid == 0) { sh_prefix = 0u; sh_K = MAXC; sh_cG = 0u; sh_pG = 0u; sh_pE = 0u; }

  unsigned* h16 = sup;   // 16 waves x 256 bins (sup unused until later)
  int wv = tid >> 6;
  for (int round = 0; round < 4; ++round) {
    for (int k = tid; k < 4096; k += 1024) h16[k] = 0u;
    __syncthreads();
    unsigned prefix = sh_prefix;
    unsigned K = sh_K;
    int shift = 24 - 8 * round;
    unsigned maskHi = (round == 0) ? 0u : (0xFFFFFFFFu << (shift + 8));
    for (int k = tid; k < 19200; k += 1024) {
      float4 v4 = p4[k];
      const float* vp = (const float*)&v4;
#pragma unroll
      for (int e = 0; e < 4; e++) {
        unsigned b = __float_as_uint(vp[e]);
        if ((b & maskHi) == prefix) atomicAdd(&h16[wv * 256 + ((b >> shift) & 255)], 1u);
      }
    }
    __syncthreads();
    if (tid < 256) {
      unsigned s = 0u;
#pragma unroll
      for (int w = 0; w < 16; w++) s += h16[w * 256 + tid];
      hist[tid] = s;
    }
    __syncthreads();
    // parallel suffix sum over 256 bins (8 Hillis-Steele steps)
    for (int off = 1; off < 256; off <<= 1) {
      unsigned v = 0u;
      if (tid < 256) {
        v = hist[tid];
        if (tid + off < 256) v += hist[tid + off];
      }
      __syncthreads();
      if (tid < 256) hist[tid] = v;
      __syncthreads();
    }
    // unique winner: suffix(bin) >= K and suffix(bin+1) < K
    if (tid < 256) {
      unsigned sInc = hist[tid];
      unsigned sExc = (tid < 255) ? hist[tid + 1] : 0u;
      if (sInc >= K && sExc < K) {
        sh_prefix = prefix | ((unsigned)tid << shift);
        sh_K = K - sExc;
        sh_cG += sExc;
      }
    }
    __syncthreads();
  }
  unsigned T = sh_prefix;
  unsigned Kfill = sh_K;
  unsigned Cgt = sh_cG;

  unsigned* eq = sup;
  __syncthreads();
  for (int k = tid; k < 19200; k += 1024) {
    float4 v4 = p4[k];
    const float* vp = (const float*)&v4;
#pragma unroll
    for (int e = 0; e < 4; e++) {
      unsigned b = __float_as_uint(vp[e]);
      if (b > T) {
        unsigned pos = atomicAdd(&sh_pG, 1u);
        skey[pos] = ((unsigned long long)b << 32) | (unsigned)(~(unsigned)(4 * k + e));
      } else if (b == T) {
        unsigned pos = atomicAdd(&sh_pE, 1u);
        if (pos < 2048u) eq[pos] = (unsigned)(4 * k + e);
      }
    }
  }
  __syncthreads();
  unsigned cE = sh_pE;
  if (Kfill < cE) {
    // need the Kfill smallest indices among the ==T set: sort eq asc
    for (int k = tid; k < 2048; k += 1024)
      if ((unsigned)k >= cE) eq[k] = 0xFFFFFFFFu;
    __syncthreads();
    for (int k = 2; k <= 2048; k <<= 1) {
      for (int j = k >> 1; j > 0; j >>= 1) {
        int t = tid;
        int i = ((t & ~(j - 1)) << 1) | (t & (j - 1));
        int l = i | j;
        bool up = ((i & k) == 0);
        unsigned a = eq[i], b2 = eq[l];
        if (up ? (a > b2) : (a < b2)) { eq[i] = b2; eq[l] = a; }
        __syncthreads();
      }
    }
  }
  for (int m2 = tid; m2 < (int)Kfill; m2 += 1024)
    skey[Cgt + m2] = ((unsigned long long)T << 32) | (unsigned)(~eq[m2]);
  __syncthreads();

  for (int k = 2; k <= MAXC; k <<= 1) {
    for (int j = k >> 1; j > 0; j >>= 1) {
      int i = tid;
      int l = i ^ j;
      if (l > i) {
        unsigned long long a = skey[i], b2 = skey[l];
        bool up = ((i & k) == 0);
        if (up ? (a < b2) : (a > b2)) { skey[i] = b2; skey[l] = a; }
      }
      __syncthreads();
    }
  }

  if (tid < 32) vword[tid] = 0u;
  __syncthreads();
  {
    unsigned long long key = skey[tid];
    unsigned vb = (unsigned)(key >> 32);
    float val = __uint_as_float(vb);
    unsigned id = ~(unsigned)key;
    unsigned y = id / 320u, xx = id - 320u * y;
    syx[tid] = (y << 16) | xx;
    if (val > DET_THRESH) atomicOr(&vword[tid >> 5], 1u << (tid & 31));
  }
  __syncthreads();

  {
    unsigned myyx = syx[tid];
    int ty = (int)(myyx >> 16), tx = (int)(myyx & 0xFFFFu);
    for (int w = 0; w < 32; ++w) {
      unsigned bits = 0u;
#pragma unroll 8
      for (int b2 = 0; b2 < 32; ++b2) {
        int j = w * 32 + b2;
        if (j > tid) {
          unsigned o = syx[j];
          int dy = ty - (int)(o >> 16); dy = dy < 0 ? -dy : dy;
          int dx = tx - (int)(o & 0xFFFFu); dx = dx < 0 ? -dx : dx;
          if (((dy | dx) < 4) && (dy + dx) <= 4) bits |= 1u << b2;
        }
      }
      sup[tid * 32 + w] = bits;
    }
  }
  __syncthreads();

  if (tid < 64) {
    int lw = tid;
    unsigned keepw = (lw < 32) ? vword[lw] : 0u;
    for (int i = 0; i < MAXC; ++i) {
      unsigned kword = __shfl(keepw, i >> 5, 64);
      if ((kword >> (i & 31)) & 1u) {
        if (lw < 32) keepw &= ~sup[i * 32 + lw];
      }
    }
    unsigned pc = (lw < 32) ? (unsigned)__builtin_popcount(keepw) : 0u;
    unsigned incl = pc;
    for (int d = 1; d < 32; d <<= 1) {
      unsigned t2 = __shfl_up(incl, d, 64);
      if (lw >= d) incl += t2;
    }
    unsigned excl = incl - pc;
    if (lw < 32) {
      int quota = 300 - (int)excl;
      if (quota <= 0) keepw = 0u;
      else if ((int)pc > quota) {
        while (__builtin_popcount(keepw) > quota)
          keepw &= ~(1u << (31 - __builtin_clz(keepw)));
      }
      unsigned kw = keepw;
      while (kw) {
        int b2 = __builtin_ffs((int)kw) - 1;
        kw &= kw - 1u;
        int i = lw * 32 + b2;
        unsigned long long key = skey[i];
        float v = __uint_as_float((unsigned)(key >> 32));
        unsigned id = ~(unsigned)key;
        on[id] = v;
        op[id] = v;
      }
    }
  }
}

// =====================================================================
extern "C" void kernel_launch(void* const* d_in, const int* in_sizes, int n_in,
                              void* d_out, int out_size, void* d_ws, size_t ws_size,
                              hipStream_t stream) {
  const float* x = (const float*)d_in[0];
  const float* w[10];
  const float* b[10];
  for (int i = 0; i < 10; ++i) {
    w[i] = (const float*)d_in[1 + 2 * i];
    b[i] = (const float*)d_in[2 + 2 * i];
  }
  float* A = (float*)d_ws;
  float* B = A + 9830400;        // 64*120*160*8
  float* prob  = (float*)d_out;
  float* onms  = prob + 614400;  // 8*240*320
  float* opred = onms + 614400;

  // Transposed weights live in the onms/opred region (dead until k_head
  // zeroes it; k_nms then scatters). Total 921600 floats <= 1228800.
  float* wT1 = onms;
  float* wT2 = wT1 + 36864;
  float* wT3 = wT2 + 36864;
  float* wT4 = wT3 + 36864;
  float* wT5 = wT4 + 73728;
  float* wT6 = wT5 + 147456;
  float* wT7 = wT6 + 147456;
  float* wT8 = wT7 + 147456;

  TP tp;
  tp.src[0] = w[1]; tp.dst[0] = wT1; tp.cin[0] = 64;  tp.cout[0] = 64;
  tp.src[1] = w[2]; tp.dst[1] = wT2; tp.cin[1] = 64;  tp.cout[1] = 64;
  tp.src[2] = w[3]; tp.dst[2] = wT3; tp.cin[2] = 64;  tp.cout[2] = 64;
  tp.src[3] = w[4]; tp.dst[3] = wT4; tp.cin[3] = 64;  tp.cout[3] = 128;
  tp.src[4] = w[5]; tp.dst[4] = wT5; tp.cin[4] = 128; tp.cout[4] = 128;
  tp.src[5] = w[6]; tp.dst[5] = wT6; tp.cin[5] = 128; tp.cout[5] = 128;
  tp.src[6] = w[7]; tp.dst[6] = wT7; tp.cin[6] = 128; tp.cout[6] = 128;
  tp.src[7] = w[8]; tp.dst[7] = wT8; tp.cin[7] = 128; tp.cout[7] = 256;
  k_wT<<<dim3(1152, 8), 256, 0, stream>>>(tp);

  // conv0+conv1+pool -> A (8,64,120,160). 32x8 tiles 10x30, 2 co-blocks (32co).
  k_f01<<<dim3(300, 2, 8), 256, 0, stream>>>(x, w[0], b[0], wT1, b[1], A);
  // conv2 -> B (8,64,120,160)
  kc2<<<dim3(75, 4, 8), 256, 0, stream>>>(A, wT2, b[2], B, 64, 64, 120, 160, 5);
  // conv3+pool -> A (8,64,60,80)
  kc3<<<dim3(75, 4, 8), 256, 0, stream>>>(B, wT3, b[3], A, 64, 64, 120, 160, 5);
  // conv4 -> B (8,128,60,80)
  kc4<<<dim3(20, 8, 8), 256, 0, stream>>>(A, wT4, b[4], B, 64, 128, 60, 80, 2);
  // conv5+pool -> A (8,128,30,40)
  kc5<<<dim3(24, 8, 8), 256, 0, stream>>>(B, wT5, b[5], A, 128, 128, 60, 80, 3);

  // 30x40 layers: ci-split x4.
  float* C6 = B + 4915200;  // conv6 output (1.2M floats)
  float* C7 = A + 4915200;  // conv7 output
  k_convp<<<dim3(5, 8, 32), 256, 0, stream>>>(A, wT6, B, 128);
  k_fuse<<<1200, 256, 0, stream>>>(B, b[6], C6, 128);
  k_convp<<<dim3(5, 8, 32), 256, 0, stream>>>(C6, wT7, A, 128);
  k_fuse<<<1200, 256, 0, stream>>>(A, b[7], C7, 128);
  k_convp<<<dim3(5, 16, 32), 256, 0, stream>>>(C7, wT8, B, 256);
  k_fuse<<<2400, 256, 0, stream>>>(B, b[8], A, 256);

  // convPb + softmax + shuffle -> prob; also zeroes onms/opred.
  k_head<<<dim3(10, 8), 256, 0, stream>>>(A, w[9], b[9], prob, onms);
  // NMS + top-300 -> prob_nms, pred
  k_nms<<<dim3(8), 1024, 0, stream>>>(prob, onms, opred);
}

// Round 18
// 1745.124 us; speedup vs baseline: 1.7433x; 1.0241x over previous
//
#include <hip/hip_runtime.h>
#include <stdint.h>

#define DET_THRESH 0.015f

#define FMA16(ACC, AV) do { \
  ACC[0]  = fmaf(AV, q0.x, ACC[0]);  ACC[1]  = fmaf(AV, q0.y, ACC[1]);  \
  ACC[2]  = fmaf(AV, q0.z, ACC[2]);  ACC[3]  = fmaf(AV, q0.w, ACC[3]);  \
  ACC[4]  = fmaf(AV, q1.x, ACC[4]);  ACC[5]  = fmaf(AV, q1.y, ACC[5]);  \
  ACC[6]  = fmaf(AV, q1.z, ACC[6]);  ACC[7]  = fmaf(AV, q1.w, ACC[7]);  \
  ACC[8]  = fmaf(AV, q2.x, ACC[8]);  ACC[9]  = fmaf(AV, q2.y, ACC[9]);  \
  ACC[10] = fmaf(AV, q2.z, ACC[10]); ACC[11] = fmaf(AV, q2.w, ACC[11]); \
  ACC[12] = fmaf(AV, q3.x, ACC[12]); ACC[13] = fmaf(AV, q3.y, ACC[13]); \
  ACC[14] = fmaf(AV, q3.z, ACC[14]); ACC[15] = fmaf(AV, q3.w, ACC[15]); } while (0)

#define FMA32(ACC, AV) do { \
  FMA16(ACC, AV); \
  ACC[16] = fmaf(AV, q4.x, ACC[16]); ACC[17] = fmaf(AV, q4.y, ACC[17]); \
  ACC[18] = fmaf(AV, q4.z, ACC[18]); ACC[19] = fmaf(AV, q4.w, ACC[19]); \
  ACC[20] = fmaf(AV, q5.x, ACC[20]); ACC[21] = fmaf(AV, q5.y, ACC[21]); \
  ACC[22] = fmaf(AV, q5.z, ACC[22]); ACC[23] = fmaf(AV, q5.w, ACC[23]); \
  ACC[24] = fmaf(AV, q6.x, ACC[24]); ACC[25] = fmaf(AV, q6.y, ACC[25]); \
  ACC[26] = fmaf(AV, q6.z, ACC[26]); ACC[27] = fmaf(AV, q6.w, ACC[27]); \
  ACC[28] = fmaf(AV, q7.x, ACC[28]); ACC[29] = fmaf(AV, q7.y, ACC[29]); \
  ACC[30] = fmaf(AV, q7.z, ACC[30]); ACC[31] = fmaf(AV, q7.w, ACC[31]); } while (0)

// =====================================================================
// Weight pre-transpose: w[co][ci][tap] -> wT[ci*9+tap][co]  (per layer)
// =====================================================================
struct TP {
  const float* src[8];
  float* dst[8];
  int cin[8];
  int cout[8];
};

__global__ __launch_bounds__(256) void k_wT(TP tp) {
  int l = blockIdx.y;
  int n = tp.cin[l] * tp.cout[l] * 9;
  int k = blockIdx.x * 256 + threadIdx.x;
  if (k >= n) return;
  int ci9 = tp.cin[l] * 9;
  int co = k / ci9;
  int r = k - co * ci9;             // r = ci*9 + tap
  tp.dst[l][(size_t)r * tp.cout[l] + co] = tp.src[l][k];
}

// =====================================================================
// Generic 3x3 conv body, 16 co/thread (r10 geometry) -- used for conv4/5
// (their 32-co block counts collapse; r13 evidence).
// =====================================================================
template <int TW, int TH, bool POOL>
__device__ __forceinline__ void conv_body(
    const float* __restrict__ in, const float* __restrict__ wT, const float* __restrict__ bias,
    float* __restrict__ out, int CIN, int COUT, int H, int W, int tilesX)
{
  constexpr int SR = TH + 2;
  constexpr int SC = TW + 2;
  constexpr int LC = TW + 4;
  constexpr int TOTAL = 4 * SR * SC;
  __shared__ float ain[4][SR][LC];

  int tile = blockIdx.x;
  int tx = tile % tilesX, ty = tile / tilesX;
  int x0 = tx * TW, y0 = ty * TH;
  int cob = blockIdx.y * 16;
  int n = blockIdx.z;

  int tid = threadIdx.x;
  int r, c;
  if (TW == 32) { r = tid >> 5; c = tid & 31; }
  else          { r = tid / TW; c = tid - r * TW; }
  bool live = (TW * TH >= 256) || (tid < TW * TH);
  int rE = live ? r : 0;

  bool full = (y0 >= 1) && (y0 + TH + 1 <= H) && (x0 >= 1) && (x0 + TW + 1 <= W);
  size_t imgBase = (size_t)n * CIN * H * W;

  float acc[16];
#pragma unroll
  for (int j = 0; j < 16; j++) acc[j] = 0.f;

  int nch = CIN >> 2;
  for (int cc = 0; cc < nch; ++cc) {
    __syncthreads();
    if (full) {
      const float* src = in + imgBase + (size_t)(cc * 4) * H * W + (y0 - 1) * W + (x0 - 1);
      for (int m = tid; m < TOTAL; m += 256) {
        int ci = m / (SR * SC);
        int rem = m - ci * (SR * SC);
        int rr = rem / SC;
        int col = rem - rr * SC;
        ain[ci][rr][col] = src[(size_t)ci * H * W + rr * W + col];
      }
    } else {
      for (int m = tid; m < TOTAL; m += 256) {
        int ci = m / (SR * SC);
        int rem = m - ci * (SR * SC);
        int rr = rem / SC;
        int col = rem - rr * SC;
        int gy = y0 - 1 + rr, gx = x0 - 1 + col;
        float v = 0.f;
        if (gy >= 0 && gy < H && gx >= 0 && gx < W)
          v = in[imgBase + ((size_t)(cc * 4 + ci) * H + gy) * W + gx];
        ain[ci][rr][col] = v;
      }
    }
    __syncthreads();
#pragma unroll
    for (int ci = 0; ci < 4; ++ci) {
      float win[3][3];
#pragma unroll
      for (int dy = 0; dy < 3; dy++) {
        win[dy][0] = ain[ci][rE + dy][c];
        win[dy][1] = ain[ci][rE + dy][c + 1];
        win[dy][2] = ain[ci][rE + dy][c + 2];
      }
      const float* wp = wT + (size_t)((cc * 4 + ci) * 9) * COUT + cob;
#pragma unroll
      for (int tap = 0; tap < 9; tap++) {
        float4 q0 = *(const float4*)(wp + tap * COUT);
        float4 q1 = *(const float4*)(wp + tap * COUT + 4);
        float4 q2 = *(const float4*)(wp + tap * COUT + 8);
        float4 q3 = *(const float4*)(wp + tap * COUT + 12);
        float av = win[tap / 3][tap % 3];
        FMA16(acc, av);
      }
    }
  }

  float bvv[16];
  {
    const float4* bp = (const float4*)(bias + cob);
    *(float4*)&bvv[0] = bp[0]; *(float4*)&bvv[4] = bp[1];
    *(float4*)&bvv[8] = bp[2]; *(float4*)&bvv[12] = bp[3];
  }
  int x = x0 + c;
  int y = y0 + r;
  if (!POOL) {
    if (live && y < H && x < W) {
#pragma unroll
      for (int j = 0; j < 16; j++)
        out[(((size_t)n * COUT + cob + j) * H + y) * W + x] = fmaxf(acc[j] + bvv[j], 0.f);
    }
  } else {
    // TW==32 only
    int Hp = H >> 1, Wp = W >> 1;
    int py = y >> 1, pxp = x >> 1;
    bool ok = ((r & 1) == 0) && ((c & 1) == 0) && (py < Hp) && (pxp < Wp);
#pragma unroll
    for (int j = 0; j < 16; j++) {
      float h = fmaxf(acc[j] + bvv[j], 0.f);
      float hc = fmaxf(h, __shfl_xor(h, 1, 64));    // col pair
      float hv = fmaxf(hc, __shfl_xor(hc, 32, 64)); // row pair
      if (ok)
        out[(((size_t)n * COUT + cob + j) * Hp + py) * Wp + pxp] = hv;
    }
  }
}

// =====================================================================
// 32-co conv body (k_f01's proven 1.18-inst/FMA recipe) for conv2/conv3:
// same shape class as conv1 and still 1200 blocks at 32 co. 32x8 tile.
// =====================================================================
template <bool POOL>
__device__ __forceinline__ void conv_body32(
    const float* __restrict__ in, const float* __restrict__ wT, const float* __restrict__ bias,
    float* __restrict__ out, int CIN, int COUT, int H, int W, int tilesX)
{
  constexpr int SR = 10, SC = 34, LC = 36;
  constexpr int TOTAL = 4 * SR * SC;   // 1360
  __shared__ float ain[4][SR][LC];

  int tile = blockIdx.x;
  int tx = tile % tilesX, ty = tile / tilesX;
  int x0 = tx * 32, y0 = ty * 8;
  int cob = blockIdx.y * 32;
  int n = blockIdx.z;

  int tid = threadIdx.x;
  int r = tid >> 5;
  int c = tid & 31;

  bool full = (y0 >= 1) && (y0 + 9 <= H) && (x0 >= 1) && (x0 + 33 <= W);
  size_t imgBase = (size_t)n * CIN * H * W;

  float acc[32];
#pragma unroll
  for (int j = 0; j < 32; j++) acc[j] = 0.f;

  int nch = CIN >> 2;
  for (int cc = 0; cc < nch; ++cc) {
    __syncthreads();
    if (full) {
      const float* src = in + imgBase + (size_t)(cc * 4) * H * W + (y0 - 1) * W + (x0 - 1);
      for (int m = tid; m < TOTAL; m += 256) {
        int ci = m / (SR * SC);
        int rem = m - ci * (SR * SC);
        int rr = rem / SC;
        int col = rem - rr * SC;
        ain[ci][rr][col] = src[(size_t)ci * H * W + rr * W + col];
      }
    } else {
      for (int m = tid; m < TOTAL; m += 256) {
        int ci = m / (SR * SC);
        int rem = m - ci * (SR * SC);
        int rr = rem / SC;
        int col = rem - rr * SC;
        int gy = y0 - 1 + rr, gx = x0 - 1 + col;
        float v = 0.f;
        if (gy >= 0 && gy < H && gx >= 0 && gx < W)
          v = in[imgBase + ((size_t)(cc * 4 + ci) * H + gy) * W + gx];
        ain[ci][rr][col] = v;
      }
    }
    __syncthreads();
#pragma unroll
    for (int ci = 0; ci < 4; ++ci) {
      float win[3][3];
#pragma unroll
      for (int dy = 0; dy < 3; dy++) {
        win[dy][0] = ain[ci][r + dy][c];
        win[dy][1] = ain[ci][r + dy][c + 1];
        win[dy][2] = ain[ci][r + dy][c + 2];
      }
      const float* wp = wT + (size_t)((cc * 4 + ci) * 9) * COUT + cob;
#pragma unroll
      for (int tap = 0; tap < 9; tap++) {
        float4 q0 = *(const float4*)(wp + tap * COUT);
        float4 q1 = *(const float4*)(wp + tap * COUT + 4);
        float4 q2 = *(const float4*)(wp + tap * COUT + 8);
        float4 q3 = *(const float4*)(wp + tap * COUT + 12);
        float4 q4 = *(const float4*)(wp + tap * COUT + 16);
        float4 q5 = *(const float4*)(wp + tap * COUT + 20);
        float4 q6 = *(const float4*)(wp + tap * COUT + 24);
        float4 q7 = *(const float4*)(wp + tap * COUT + 28);
        float av = win[tap / 3][tap % 3];
        FMA32(acc, av);
      }
    }
  }

  float bvv[32];
  {
    const float4* bp = (const float4*)(bias + cob);
#pragma unroll
    for (int g = 0; g < 8; g++) *(float4*)&bvv[4 * g] = bp[g];
  }
  int x = x0 + c;
  int y = y0 + r;
  if (!POOL) {
    if (y < H && x < W) {
#pragma unroll
      for (int j = 0; j < 32; j++)
        out[(((size_t)n * COUT + cob + j) * H + y) * W + x] = fmaxf(acc[j] + bvv[j], 0.f);
    }
  } else {
    int Hp = H >> 1, Wp = W >> 1;
    int py = y >> 1, pxp = x >> 1;
    bool ok = ((r & 1) == 0) && ((c & 1) == 0) && (py < Hp) && (pxp < Wp);
#pragma unroll
    for (int j = 0; j < 32; j++) {
      float h = fmaxf(acc[j] + bvv[j], 0.f);
      float hv = fmaxf(h, __shfl_xor(h, 32, 64));   // row pair
      float hh = fmaxf(hv, __shfl_xor(hv, 1, 64));  // col pair
      if (ok)
        out[(((size_t)n * COUT + cob + j) * Hp + py) * Wp + pxp] = hh;
    }
  }
}

__global__ __launch_bounds__(256) void kc2(const float* in, const float* wT, const float* bias,
                                           float* out, int CIN, int COUT, int H, int W, int tX)
{ conv_body32<false>(in, wT, bias, out, CIN, COUT, H, W, tX); }
__global__ __launch_bounds__(256) void kc3(const float* in, const float* wT, const float* bias,
                                           float* out, int CIN, int COUT, int H, int W, int tX)
{ conv_body32<true>(in, wT, bias, out, CIN, COUT, H, W, tX); }
__global__ __launch_bounds__(256) void kc4(const float* in, const float* wT, const float* bias,
                                           float* out, int CIN, int COUT, int H, int W, int tX)
{ conv_body<40, 6, false>(in, wT, bias, out, CIN, COUT, H, W, tX); }
__global__ __launch_bounds__(256) void kc5(const float* in, const float* wT, const float* bias,
                                           float* out, int CIN, int COUT, int H, int W, int tX)
{ conv_body<32, 8, true>(in, wT, bias, out, CIN, COUT, H, W, tX); }

// =====================================================================
// ci-split partial conv for the 30x40 layers (CIN=128). split = z&3.
// =====================================================================
__global__ __launch_bounds__(256) void k_convp(
    const float* __restrict__ in, const float* __restrict__ wT,
    float* __restrict__ pout, int COUT)
{
  const int H = 30, W = 40;
  constexpr int SR = 8, SC = 42, LC = 44;
  constexpr int TOTAL = 4 * SR * SC;   // 1344
  __shared__ float ain[4][SR][LC];

  int y0 = blockIdx.x * 6;             // 0..4
  int cob = blockIdx.y * 16;
  int z = blockIdx.z;
  int n = z >> 2, split = z & 3;

  int tid = threadIdx.x;
  int r = tid / 40, c = tid - r * 40;
  bool live = tid < 240;
  int rE = live ? r : 0;

  size_t imgBase = (size_t)n * 128 * 1200;

  float acc[16];
#pragma unroll
  for (int j = 0; j < 16; j++) acc[j] = 0.f;

  int cc0 = split * 8;
  for (int cc = cc0; cc < cc0 + 8; ++cc) {
    __syncthreads();
    for (int m = tid; m < TOTAL; m += 256) {
      int ci = m / (SR * SC);
      int rem = m - ci * (SR * SC);
      int rr = rem / SC;
      int col = rem - rr * SC;
      int gy = y0 - 1 + rr, gx = col - 1;
      float v = 0.f;
      if (gy >= 0 && gy < H && gx >= 0 && gx < W)
        v = in[imgBase + ((size_t)(cc * 4 + ci) * H + gy) * W + gx];
      ain[ci][rr][col] = v;
    }
    __syncthreads();
#pragma unroll
    for (int ci = 0; ci < 4; ++ci) {
      float win[3][3];
#pragma unroll
      for (int dy = 0; dy < 3; dy++) {
        win[dy][0] = ain[ci][rE + dy][c];
        win[dy][1] = ain[ci][rE + dy][c + 1];
        win[dy][2] = ain[ci][rE + dy][c + 2];
      }
      const float* wp = wT + (size_t)((cc * 4 + ci) * 9) * COUT + cob;
#pragma unroll
      for (int tap = 0; tap < 9; tap++) {
        float4 q0 = *(const float4*)(wp + tap * COUT);
        float4 q1 = *(const float4*)(wp + tap * COUT + 4);
        float4 q2 = *(const float4*)(wp + tap * COUT + 8);
        float4 q3 = *(const float4*)(wp + tap * COUT + 12);
        float av = win[tap / 3][tap % 3];
        FMA16(acc, av);
      }
    }
  }

  int y = y0 + r;
  if (live && y < H) {
    float* po = pout + (size_t)split * (8 * (size_t)COUT * 1200)
              + ((size_t)n * COUT + cob) * 1200 + y * 40 + c;
#pragma unroll
    for (int j = 0; j < 16; j++)
      po[(size_t)j * 1200] = acc[j];
  }
}

// sum 4 partial slabs + bias + relu (float4)
__global__ __launch_bounds__(256) void k_fuse(
    const float* __restrict__ pin, const float* __restrict__ bias,
    float* __restrict__ out, int COUT)
{
  int idx = blockIdx.x * 256 + threadIdx.x;       // float4 index
  int total4 = 2 * COUT * 1200;                   // (8*COUT*1200)/4
  if (idx >= total4) return;
  int co = ((idx * 4) / 1200) % COUT;
  size_t slab4 = (size_t)2 * COUT * 1200;
  const float4* p4 = (const float4*)pin;
  float4 a = p4[idx], b2 = p4[idx + slab4], c2 = p4[idx + 2 * slab4], d = p4[idx + 3 * slab4];
  float bb = bias[co];
  float4 o;
  o.x = fmaxf(a.x + b2.x + c2.x + d.x + bb, 0.f);
  o.y = fmaxf(a.y + b2.y + c2.y + d.y + bb, 0.f);
  o.z = fmaxf(a.z + b2.z + c2.z + d.z + bb, 0.f);
  o.w = fmaxf(a.w + b2.w + c2.w + d.w + bb, 0.f);
  ((float4*)out)[idx] = o;
}

// =====================================================================
// Fused conv0(1->64)+relu -> conv1(64->64)+relu -> 2x2 maxpool.
// =====================================================================
__global__ __launch_bounds__(256) void k_f01(
    const float* __restrict__ x, const float* __restrict__ w0g, const float* __restrict__ b0g,
    const float* __restrict__ wT1, const float* __restrict__ b1g, float* __restrict__ out)
{
  const int H = 240, W = 320;
  __shared__ float in_raw[12][36];
  __shared__ float a0[4][10][36];
  __shared__ float w0l[576];
  __shared__ float b0l[64];

  int tile = blockIdx.x;              // tilesX=10, tilesY=30
  int tx = tile % 10, ty = tile / 10;
  int x0 = tx * 32, y0 = ty * 8;
  int cob = blockIdx.y * 32;          // 0..1
  int n = blockIdx.z;

  int tid = threadIdx.x;
  int r = tid >> 5;
  int c = tid & 31;

  bool fullT = (y0 >= 1) && (y0 + 9 <= H) && (x0 >= 1) && (x0 + 33 <= W);

  for (int k = tid; k < 576; k += 256) w0l[k] = w0g[k];
  if (tid < 64) b0l[tid] = b0g[tid];
  for (int m = tid; m < 432; m += 256) {
    int rr = m / 36, col = m - rr * 36;
    int gy = y0 - 2 + rr, gx = x0 - 2 + col;
    in_raw[rr][col] = (gy >= 0 && gy < H && gx >= 0 && gx < W)
                          ? x[(size_t)n * (H * W) + gy * W + gx] : 0.f;
  }

  float acc[32];
#pragma unroll
  for (int j = 0; j < 32; j++) acc[j] = 0.f;

  for (int cc = 0; cc < 16; ++cc) {
    __syncthreads();                  // in_raw/w0l ready; a0 free
    if (fullT) {
      for (int m = tid; m < 1360; m += 256) {
        int ch = m / 340;
        int rem = m - ch * 340;
        int rr = rem / 34;
        int col = rem - rr * 34;
        const float* wp = &w0l[(cc * 4 + ch) * 9];
        float s = b0l[cc * 4 + ch];
#pragma unroll
        for (int dy = 0; dy < 3; dy++)
#pragma unroll
          for (int dx = 0; dx < 3; dx++)
            s = fmaf(in_raw[rr + dy][col + dx], wp[dy * 3 + dx], s);
        a0[ch][rr][col] = fmaxf(s, 0.f);
      }
    } else {
      for (int m = tid; m < 1360; m += 256) {
        int ch = m / 340;
        int rem = m - ch * 340;
        int rr = rem / 34;
        int col = rem - rr * 34;
        int gy = y0 - 1 + rr, gx = x0 - 1 + col;
        float v = 0.f;
        if (gy >= 0 && gy < H && gx >= 0 && gx < W) {
          const float* wp = &w0l[(cc * 4 + ch) * 9];
          float s = b0l[cc * 4 + ch];
#pragma unroll
          for (int dy = 0; dy < 3; dy++)
#pragma unroll
            for (int dx = 0; dx < 3; dx++)
              s = fmaf(in_raw[rr + dy][col + dx], wp[dy * 3 + dx], s);
          v = fmaxf(s, 0.f);
        }
        a0[ch][rr][col] = v;
      }
    }
    __syncthreads();
#pragma unroll
    for (int ci = 0; ci < 4; ++ci) {
      float win[3][3];
#pragma unroll
      for (int dy = 0; dy < 3; dy++) {
        win[dy][0] = a0[ci][r + dy][c];
        win[dy][1] = a0[ci][r + dy][c + 1];
        win[dy][2] = a0[ci][r + dy][c + 2];
      }
      const float* wp = wT1 + (size_t)((cc * 4 + ci) * 9) * 64 + cob;
#pragma unroll
      for (int tap = 0; tap < 9; tap++) {
        float4 q0 = *(const float4*)(wp + tap * 64);
        float4 q1 = *(const float4*)(wp + tap * 64 + 4);
        float4 q2 = *(const float4*)(wp + tap * 64 + 8);
        float4 q3 = *(const float4*)(wp + tap * 64 + 12);
        float4 q4 = *(const float4*)(wp + tap * 64 + 16);
        float4 q5 = *(const float4*)(wp + tap * 64 + 20);
        float4 q6 = *(const float4*)(wp + tap * 64 + 24);
        float4 q7 = *(const float4*)(wp + tap * 64 + 28);
        float av = win[tap / 3][tap % 3];
        FMA32(acc, av);
      }
    }
  }

  float bvv[32];
  {
    const float4* bp = (const float4*)(b1g + cob);
#pragma unroll
    for (int g = 0; g < 8; g++) *(float4*)&bvv[4 * g] = bp[g];
  }
  int Hp = 120, Wp = 160;
  int py = (y0 + r) >> 1, pxp = (x0 + c) >> 1;
  bool ok = ((r & 1) == 0) && ((c & 1) == 0);
#pragma unroll
  for (int j = 0; j < 32; j++) {
    float h = fmaxf(acc[j] + bvv[j], 0.f);
    float hv = fmaxf(h, __shfl_xor(h, 32, 64));
    float hh = fmaxf(hv, __shfl_xor(hv, 1, 64));
    if (ok)
      out[(((size_t)n * 64 + cob + j) * Hp + py) * Wp + pxp] = hh;
  }
}

// =====================================================================
// Head: conv9 (1x1, 256->65) + bias + softmax(65) + dustbin drop + shuffle.
// 2-lane teams. Also zeroes the prob_nms/pred output region.
// =====================================================================
__global__ __launch_bounds__(256) void k_head(
    const float* __restrict__ act, const float* __restrict__ w9, const float* __restrict__ b9,
    float* __restrict__ prob, float* __restrict__ zbase)
{
  __shared__ float wl[256 * 68];
  int n = blockIdx.y;
  int tid = threadIdx.x;

  // zero onms+opred (2*614400 floats) across all 80 blocks
  {
    float4* z = (float4*)zbase;
    int gid = (blockIdx.y * gridDim.x + blockIdx.x) * 256 + tid;
    for (int k = gid; k < 307200; k += 20480)
      z[k] = make_float4(0.f, 0.f, 0.f, 0.f);
  }

  for (int k = tid; k < 65 * 256; k += 256) {
    int co = k / 256, ci = k % 256;
    wl[ci * 68 + co] = w9[k];
  }
  for (int ci = tid; ci < 256; ci += 256) {
    wl[ci * 68 + 65] = 0.f; wl[ci * 68 + 66] = 0.f; wl[ci * 68 + 67] = 0.f;
  }
  __syncthreads();
  int px = blockIdx.x * 128 + (tid >> 1);
  int half = tid & 1;
  bool live = (px < 1200);
  int cbase = half * 34;
  int nreal = half ? 31 : 34;    // real co count (incl. dustbin 64 on odd)

  float accv[34];
#pragma unroll
  for (int i = 0; i < 34; i++) accv[i] = 0.f;

  if (live) {
    for (int ci = 0; ci < 256; ++ci) {
      float a = act[((size_t)n * 256 + ci) * 1200 + px];
      const float2* wp = (const float2*)&wl[ci * 68 + cbase];
#pragma unroll
      for (int g = 0; g < 17; g++) {
        float2 wv = wp[g];
        accv[g * 2 + 0] = fmaf(a, wv.x, accv[g * 2 + 0]);
        accv[g * 2 + 1] = fmaf(a, wv.y, accv[g * 2 + 1]);
      }
    }
  }
  for (int i = 0; i < 34; i++)
    if (i < nreal) accv[i] += b9[cbase + i];
  float m = -1e30f;
  for (int i = 0; i < 34; i++)
    if (i < nreal) m = fmaxf(m, accv[i]);
  m = fmaxf(m, __shfl_xor(m, 1, 64));
  float s = 0.f;
  for (int i = 0; i < 34; i++)
    if (i < nreal) { accv[i] = __expf(accv[i] - m); s += accv[i]; }
  s += __shfl_xor(s, 1, 64);
  float inv = 1.f / s;

  if (live) {
    int hc = px / 40, wc = px % 40;
    float* pb = prob + (size_t)n * 76800;
    int nw = half ? 30 : 34;     // write only co < 64
    for (int i = 0; i < nw; i++) {
      int co = cbase + i;
      pb[(hc * 8 + (co >> 3)) * 320 + wc * 8 + (co & 7)] = accv[i] * inv;
    }
  }
}

// =====================================================================
// Exact reference NMS per image (parallel suffix-scan bin select;
// eq-sort only when Kfill < cE).
// =====================================================================
#define MAXC 1024
__global__ __launch_bounds__(1024) void k_nms(
    const float* __restrict__ prob, float* __restrict__ onms, float* __restrict__ opred)
{
  __shared__ unsigned sup[MAXC * 32];
  __shared__ unsigned long long skey[MAXC];
  __shared__ unsigned syx[MAXC];
  __shared__ unsigned hist[256];
  __shared__ unsigned vword[32];
  __shared__ unsigned sh_prefix, sh_K, sh_cG, sh_pG, sh_pE;

  int n = blockIdx.x;
  int tid = threadIdx.x;
  const float* p = prob + (size_t)n * 76800;
  const float4* p4 = (const float4*)p;
  float* on = onms + (size_t)n * 76800;
  float* op = opred + (size_t)n * 76800;

  if (tid == 0) { sh_prefix = 0u; sh_K = MAXC; sh_cG = 0u; sh_pG = 0u; sh_pE = 0u; }

  unsigned* h16 = sup;   // 16 waves x 256 bins (sup unused until later)
  int wv = tid >> 6;
  for (int round = 0; round < 4; ++round) {
    for (int k = tid; k < 4096; k += 1024) h16[k] = 0u;
    __syncthreads();
    unsigned prefix = sh_prefix;
    unsigned K = sh_K;
    int shift = 24 - 8 * round;
    unsigned maskHi = (round == 0) ? 0u : (0xFFFFFFFFu << (shift + 8));
    for (int k = tid; k < 19200; k += 1024) {
      float4 v4 = p4[k];
      const float* vp = (const float*)&v4;
#pragma unroll
      for (int e = 0; e < 4; e++) {
        unsigned b = __float_as_uint(vp[e]);
        if ((b & maskHi) == prefix) atomicAdd(&h16[wv * 256 + ((b >> shift) & 255)], 1u);
      }
    }
    __syncthreads();
    if (tid < 256) {
      unsigned s = 0u;
#pragma unroll
      for (int w = 0; w < 16; w++) s += h16[w * 256 + tid];
      hist[tid] = s;
    }
    __syncthreads();
    // parallel suffix sum over 256 bins (8 Hillis-Steele steps)
    for (int off = 1; off < 256; off <<= 1) {
      unsigned v = 0u;
      if (tid < 256) {
        v = hist[tid];
        if (tid + off < 256) v += hist[tid + off];
      }
      __syncthreads();
      if (tid < 256) hist[tid] = v;
      __syncthreads();
    }
    if (tid < 256) {
      unsigned sInc = hist[tid];
      unsigned sExc = (tid < 255) ? hist[tid + 1] : 0u;
      if (sInc >= K && sExc < K) {
        sh_prefix = prefix | ((unsigned)tid << shift);
        sh_K = K - sExc;
        sh_cG += sExc;
      }
    }
    __syncthreads();
  }
  unsigned T = sh_prefix;
  unsigned Kfill = sh_K;
  unsigned Cgt = sh_cG;

  unsigned* eq = sup;
  __syncthreads();
  for (int k = tid; k < 19200; k += 1024) {
    float4 v4 = p4[k];
    const float* vp = (const float*)&v4;
#pragma unroll
    for (int e = 0; e < 4; e++) {
      unsigned b = __float_as_uint(vp[e]);
      if (b > T) {
        unsigned pos = atomicAdd(&sh_pG, 1u);
        skey[pos] = ((unsigned long long)b << 32) | (unsigned)(~(unsigned)(4 * k + e));
      } else if (b == T) {
        unsigned pos = atomicAdd(&sh_pE, 1u);
        if (pos < 2048u) eq[pos] = (unsigned)(4 * k + e);
      }
    }
  }
  __syncthreads();
  unsigned cE = sh_pE;
  if (Kfill < cE) {
    for (int k = tid; k < 2048; k += 1024)
      if ((unsigned)k >= cE) eq[k] = 0xFFFFFFFFu;
    __syncthreads();
    for (int k = 2; k <= 2048; k <<= 1) {
      for (int j = k >> 1; j > 0; j >>= 1) {
        int t = tid;
        int i = ((t & ~(j - 1)) << 1) | (t & (j - 1));
        int l = i | j;
        bool up = ((i & k) == 0);
        unsigned a = eq[i], b2 = eq[l];
        if (up ? (a > b2) : (a < b2)) { eq[i] = b2; eq[l] = a; }
        __syncthreads();
      }
    }
  }
  for (int m2 = tid; m2 < (int)Kfill; m2 += 1024)
    skey[Cgt + m2] = ((unsigned long long)T << 32) | (unsigned)(~eq[m2]);
  __syncthreads();

  for (int k = 2; k <= MAXC; k <<= 1) {
    for (int j = k >> 1; j > 0; j >>= 1) {
      int i = tid;
      int l = i ^ j;
      if (l > i) {
        unsigned long long a = skey[i], b2 = skey[l];
        bool up = ((i & k) == 0);
        if (up ? (a < b2) : (a > b2)) { skey[i] = b2; skey[l] = a; }
      }
      __syncthreads();
    }
  }

  if (tid < 32) vword[tid] = 0u;
  __syncthreads();
  {
    unsigned long long key = skey[tid];
    unsigned vb = (unsigned)(key >> 32);
    float val = __uint_as_float(vb);
    unsigned id = ~(unsigned)key;
    unsigned y = id / 320u, xx = id - 320u * y;
    syx[tid] = (y << 16) | xx;
    if (val > DET_THRESH) atomicOr(&vword[tid >> 5], 1u << (tid & 31));
  }
  __syncthreads();

  {
    unsigned myyx = syx[tid];
    int ty = (int)(myyx >> 16), tx = (int)(myyx & 0xFFFFu);
    for (int w = 0; w < 32; ++w) {
      unsigned bits = 0u;
#pragma unroll 8
      for (int b2 = 0; b2 < 32; ++b2) {
        int j = w * 32 + b2;
        if (j > tid) {
          unsigned o = syx[j];
          int dy = ty - (int)(o >> 16); dy = dy < 0 ? -dy : dy;
          int dx = tx - (int)(o & 0xFFFFu); dx = dx < 0 ? -dx : dx;
          if (((dy | dx) < 4) && (dy + dx) <= 4) bits |= 1u << b2;
        }
      }
      sup[tid * 32 + w] = bits;
    }
  }
  __syncthreads();

  if (tid < 64) {
    int lw = tid;
    unsigned keepw = (lw < 32) ? vword[lw] : 0u;
    for (int i = 0; i < MAXC; ++i) {
      unsigned kword = __shfl(keepw, i >> 5, 64);
      if ((kword >> (i & 31)) & 1u) {
        if (lw < 32) keepw &= ~sup[i * 32 + lw];
      }
    }
    unsigned pc = (lw < 32) ? (unsigned)__builtin_popcount(keepw) : 0u;
    unsigned incl = pc;
    for (int d = 1; d < 32; d <<= 1) {
      unsigned t2 = __shfl_up(incl, d, 64);
      if (lw >= d) incl += t2;
    }
    unsigned excl = incl - pc;
    if (lw < 32) {
      int quota = 300 - (int)excl;
      if (quota <= 0) keepw = 0u;
      else if ((int)pc > quota) {
        while (__builtin_popcount(keepw) > quota)
          keepw &= ~(1u << (31 - __builtin_clz(keepw)));
      }
      unsigned kw = keepw;
      while (kw) {
        int b2 = __builtin_ffs((int)kw) - 1;
        kw &= kw - 1u;
        int i = lw * 32 + b2;
        unsigned long long key = skey[i];
        float v = __uint_as_float((unsigned)(key >> 32));
        unsigned id = ~(unsigned)key;
        on[id] = v;
        op[id] = v;
      }
    }
  }
}

// =====================================================================
extern "C" void kernel_launch(void* const* d_in, const int* in_sizes, int n_in,
                              void* d_out, int out_size, void* d_ws, size_t ws_size,
                              hipStream_t stream) {
  const float* x = (const float*)d_in[0];
  const float* w[10];
  const float* b[10];
  for (int i = 0; i < 10; ++i) {
    w[i] = (const float*)d_in[1 + 2 * i];
    b[i] = (const float*)d_in[2 + 2 * i];
  }
  float* A = (float*)d_ws;
  float* B = A + 9830400;        // 64*120*160*8
  float* prob  = (float*)d_out;
  float* onms  = prob + 614400;  // 8*240*320
  float* opred = onms + 614400;

  // Transposed weights live in the onms/opred region (dead until k_head
  // zeroes it; k_nms then scatters). Total 921600 floats <= 1228800.
  float* wT1 = onms;
  float* wT2 = wT1 + 36864;
  float* wT3 = wT2 + 36864;
  float* wT4 = wT3 + 36864;
  float* wT5 = wT4 + 73728;
  float* wT6 = wT5 + 147456;
  float* wT7 = wT6 + 147456;
  float* wT8 = wT7 + 147456;

  TP tp;
  tp.src[0] = w[1]; tp.dst[0] = wT1; tp.cin[0] = 64;  tp.cout[0] = 64;
  tp.src[1] = w[2]; tp.dst[1] = wT2; tp.cin[1] = 64;  tp.cout[1] = 64;
  tp.src[2] = w[3]; tp.dst[2] = wT3; tp.cin[2] = 64;  tp.cout[2] = 64;
  tp.src[3] = w[4]; tp.dst[3] = wT4; tp.cin[3] = 64;  tp.cout[3] = 128;
  tp.src[4] = w[5]; tp.dst[4] = wT5; tp.cin[4] = 128; tp.cout[4] = 128;
  tp.src[5] = w[6]; tp.dst[5] = wT6; tp.cin[5] = 128; tp.cout[5] = 128;
  tp.src[6] = w[7]; tp.dst[6] = wT7; tp.cin[6] = 128; tp.cout[6] = 128;
  tp.src[7] = w[8]; tp.dst[7] = wT8; tp.cin[7] = 128; tp.cout[7] = 256;
  k_wT<<<dim3(1152, 8), 256, 0, stream>>>(tp);

  // conv0+conv1+pool -> A (8,64,120,160). 32x8 tiles 10x30, 2 co-blocks (32co).
  k_f01<<<dim3(300, 2, 8), 256, 0, stream>>>(x, w[0], b[0], wT1, b[1], A);
  // conv2 -> B (8,64,120,160). 32co, 1200 blocks.
  kc2<<<dim3(75, 2, 8), 256, 0, stream>>>(A, wT2, b[2], B, 64, 64, 120, 160, 5);
  // conv3+pool -> A (8,64,60,80). 32co.
  kc3<<<dim3(75, 2, 8), 256, 0, stream>>>(B, wT3, b[3], A, 64, 64, 120, 160, 5);
  // conv4 -> B (8,128,60,80). 16co (r13: 32co collapses block count).
  kc4<<<dim3(20, 8, 8), 256, 0, stream>>>(A, wT4, b[4], B, 64, 128, 60, 80, 2);
  // conv5+pool -> A (8,128,30,40). 16co.
  kc5<<<dim3(24, 8, 8), 256, 0, stream>>>(B, wT5, b[5], A, 128, 128, 60, 80, 3);

  // 30x40 layers: ci-split x4.
  float* C6 = B + 4915200;  // conv6 output (1.2M floats)
  float* C7 = A + 4915200;  // conv7 output
  k_convp<<<dim3(5, 8, 32), 256, 0, stream>>>(A, wT6, B, 128);
  k_fuse<<<1200, 256, 0, stream>>>(B, b[6], C6, 128);
  k_convp<<<dim3(5, 8, 32), 256, 0, stream>>>(C6, wT7, A, 128);
  k_fuse<<<1200, 256, 0, stream>>>(A, b[7], C7, 128);
  k_convp<<<dim3(5, 16, 32), 256, 0, stream>>>(C7, wT8, B, 256);
  k_fuse<<<2400, 256, 0, stream>>>(B, b[8], A, 256);

  // convPb + softmax + shuffle -> prob; also zeroes onms/opred.
  k_head<<<dim3(10, 8), 256, 0, stream>>>(A, w[9], b[9], prob, onms);
  // NMS + top-300 -> prob_nms, pred
  k_nms<<<dim3(8), 1024, 0, stream>>>(prob, onms, opred);
}